// Round 4
// baseline (1279.639 us; speedup 1.0000x reference)
//
#include <hip/hip_runtime.h>
#include <hip/hip_bf16.h>
#include <cstdint>
#include <cstddef>

#define BATCH 8
#define FRAMES 128
#define TOK (BATCH*FRAMES)   // 1024
#define NM 60
#define VF 196
#define DD 256
#define EDIM 512
#define NSTATE 16
#define DTRANK 16
#define NLAYER 4

typedef __attribute__((ext_vector_type(8))) short short8v;
typedef __attribute__((ext_vector_type(4))) float f32x4;

__device__ __forceinline__ unsigned short f2bf(float f) {
  unsigned x = __float_as_uint(f);
  unsigned r = (x + 0x7FFFu + ((x >> 16) & 1u)) >> 16;
  return (unsigned short)r;
}

// ---------------------------------------------------------------------------
// pack_w2: W2 (64,32,3,3) f32 -> Wb[shift(9)][mtile(4)][lane(64)][8] bf16
// ---------------------------------------------------------------------------
__global__ void pack_w2(const float* __restrict__ w2, unsigned short* __restrict__ Wb) {
  int id = blockIdx.x * 256 + threadIdx.x;
  if (id >= 9 * 4 * 64) return;
  int lane = id & 63;
  int mt = (id >> 6) & 3;
  int sh = id >> 8;
  int dy = sh / 3, dx = sh % 3;
  int oc = mt * 16 + (lane & 15);
  int ic0 = (lane >> 4) * 8;
  unsigned u[4];
#pragma unroll
  for (int p = 0; p < 4; ++p) {
    unsigned short lo = f2bf(w2[((oc * 32 + ic0 + 2 * p) * 3 + dy) * 3 + dx]);
    unsigned short hi = f2bf(w2[((oc * 32 + ic0 + 2 * p + 1) * 3 + dy) * 3 + dx]);
    u[p] = (unsigned)lo | ((unsigned)hi << 16);
  }
  uint4 v = {u[0], u[1], u[2], u[3]};
  *(uint4*)(Wb + (size_t)id * 8) = v;
}

// ---------------------------------------------------------------------------
// pack_mamba: in_proj (2dir,4L,1024,256) and out_proj (2dir,4L,256,512) f32 ->
// bf16 MFMA B-fragment order: [dl][ntile][kt][lane][8]
// ---------------------------------------------------------------------------
__global__ void pack_mamba(const float* __restrict__ ipF, const float* __restrict__ ipR,
                           const float* __restrict__ opF, const float* __restrict__ opR,
                           unsigned short* __restrict__ Wip, unsigned short* __restrict__ Wop) {
  int id = blockIdx.x * 256 + threadIdx.x;
  if (id < 262144) {                     // in_proj: 8 dl x (64 nt x 8 kt x 64 lanes)
    int dl = id >> 15, r = id & 32767;
    int ntile = r >> 9, kt = (r >> 6) & 7, lane = r & 63;
    int dir = dl >> 2, layer = dl & 3;
    const float* src = (dir ? ipR : ipF) + (size_t)layer * 1024 * 256
                       + (size_t)(ntile * 16 + (lane & 15)) * 256 + kt * 32 + (lane >> 4) * 8;
    unsigned u[4];
#pragma unroll
    for (int p = 0; p < 4; ++p)
      u[p] = (unsigned)f2bf(src[2 * p]) | ((unsigned)f2bf(src[2 * p + 1]) << 16);
    uint4 v = {u[0], u[1], u[2], u[3]};
    *(uint4*)(Wip + (size_t)id * 8) = v;
  } else if (id < 262144 + 131072) {     // out_proj: 8 dl x (16 nt x 16 kt x 64 lanes)
    int id2 = id - 262144;
    int dl = id2 >> 14, rr = id2 & 16383;
    int ntile = rr >> 10, kt = (rr >> 6) & 15, lane = rr & 63;
    int dir = dl >> 2, layer = dl & 3;
    const float* src = (dir ? opR : opF) + (size_t)layer * 256 * 512
                       + (size_t)(ntile * 16 + (lane & 15)) * 512 + kt * 32 + (lane >> 4) * 8;
    unsigned u[4];
#pragma unroll
    for (int p = 0; p < 4; ++p)
      u[p] = (unsigned)f2bf(src[2 * p]) | ((unsigned)f2bf(src[2 * p + 1]) << 16);
    uint4 v = {u[0], u[1], u[2], u[3]};
    *(uint4*)(Wop + (size_t)id2 * 8) = v;
  }
}

// ---------------------------------------------------------------------------
// conv1_k: unchanged from round 3
// ---------------------------------------------------------------------------
#define C1P 72
__global__ __launch_bounds__(256) void conv1_k(
    const float* __restrict__ video, const float* __restrict__ w1,
    const float* __restrict__ b1, unsigned short* __restrict__ X1)
{
  __shared__ float imgs[3 * 34 * C1P];
  const int img = blockIdx.x, t = threadIdx.x;
  const float* vin = video + (size_t)img * 12288;
  const int px = t & 31, pyl = t >> 5;

#pragma unroll 1
  for (int h = 0; h < 2; ++h) {
    __syncthreads();
    float4 z4 = {0.f, 0.f, 0.f, 0.f};
    for (int i = t; i < (3 * 34 * C1P) / 4; i += 256) ((float4*)imgs)[i] = z4;
    __syncthreads();
    for (int i = t; i < 3 * 33 * 16; i += 256) {
      int ic = i / 528; int rr = (i - ic * 528) >> 4; int c4 = i & 15;
      int r  = rr + (h ? 0 : 1);
      int gr = 32 * h - 1 + r;
      float4 v = *(const float4*)(vin + ic * 4096 + gr * 64 + c4 * 4);
      *(float4*)(imgs + ic * (34 * C1P) + r * C1P + 4 + c4 * 4) = v;
    }
    __syncthreads();
#pragma unroll 1
    for (int s = 0; s < 2; ++s) {
      const int y = pyl + 8 * (2 * h + s);
      const int lr0 = 2 * (pyl + 8 * s);
      float in[3][4][4];
#pragma unroll
      for (int ic = 0; ic < 3; ++ic)
#pragma unroll
        for (int rr = 0; rr < 4; ++rr)
#pragma unroll
          for (int cc = 0; cc < 4; ++cc)
            in[ic][rr][cc] = imgs[ic * (34 * C1P) + (lr0 + rr) * C1P + (2 * px + 3 + cc)];
      unsigned ob[16];
#pragma unroll 1
      for (int ch = 0; ch < 32; ++ch) {
        float wv[27];
#pragma unroll
        for (int j = 0; j < 27; ++j) wv[j] = w1[ch * 27 + j];
        float bb = b1[ch];
        float a0 = bb, a1 = bb, a2 = bb, a3 = bb;
#pragma unroll
        for (int ic = 0; ic < 3; ++ic)
#pragma unroll
          for (int dy = 0; dy < 3; ++dy)
#pragma unroll
            for (int dx = 0; dx < 3; ++dx) {
              float w = wv[ic * 9 + dy * 3 + dx];
              a0 = fmaf(w, in[ic][dy    ][dx    ], a0);
              a1 = fmaf(w, in[ic][dy    ][dx + 1], a1);
              a2 = fmaf(w, in[ic][dy + 1][dx    ], a2);
              a3 = fmaf(w, in[ic][dy + 1][dx + 1], a3);
            }
        a0 = fmaxf(a0, 0.f); a1 = fmaxf(a1, 0.f);
        a2 = fmaxf(a2, 0.f); a3 = fmaxf(a3, 0.f);
        float pooled = fmaxf(fmaxf(a0, a1), fmaxf(a2, a3));
        unsigned short u = f2bf(pooled);
        if ((ch & 1) == 0) ob[ch >> 1] = (unsigned)u;
        else               ob[ch >> 1] |= ((unsigned)u << 16);
      }
      size_t base = ((size_t)img * 1024 + (size_t)y * 32 + px) * 32;
      uint4* dst = (uint4*)(X1 + base);
      uint4 o0 = {ob[0], ob[1], ob[2], ob[3]};
      uint4 o1 = {ob[4], ob[5], ob[6], ob[7]};
      uint4 o2 = {ob[8], ob[9], ob[10], ob[11]};
      uint4 o3 = {ob[12], ob[13], ob[14], ob[15]};
      dst[0] = o0; dst[1] = o1; dst[2] = o2; dst[3] = o3;
    }
  }
}

// ---------------------------------------------------------------------------
// conv2_k: unchanged from round 3
// ---------------------------------------------------------------------------
#define X_LDS_BYTES (4 * 1156 * 16)
#define OCT_STRIDE  (1156 * 16)
__global__ __launch_bounds__(256) void conv2_k(
    const unsigned short* __restrict__ X1, const unsigned short* __restrict__ Wb,
    const float* __restrict__ b2, float* __restrict__ feat)
{
  extern __shared__ char sm[];
  float* part = (float*)(sm + X_LDS_BYTES);
  const int img = blockIdx.x, t = threadIdx.x;
  const int lane = t & 63, wv = t >> 6;
  const int kg = lane >> 4, l15 = lane & 15;

  for (int j = t; j < 1156; j += 256) {
    int r = j / 34, cc = j - r * 34;
    if (r == 0 || r == 33 || cc == 0 || cc == 33) {
      uint4 z = {0, 0, 0, 0};
#pragma unroll
      for (int oct = 0; oct < 4; ++oct)
        *(uint4*)(sm + oct * OCT_STRIDE + j * 16) = z;
    }
  }
  const uint4* src = (const uint4*)(X1 + (size_t)img * 32768);
#pragma unroll 4
  for (int i = 0; i < 16; ++i) {
    int c = i * 256 + t;
    uint4 v = src[c];
    int oct = c & 3, P = c >> 2;
    int y = P >> 5, x = P & 31;
    *(uint4*)(sm + oct * OCT_STRIDE + ((y + 1) * 34 + (x + 1)) * 16) = v;
  }
  __syncthreads();

  float bia[4][4];
#pragma unroll
  for (int mt = 0; mt < 4; ++mt)
#pragma unroll
    for (int r = 0; r < 4; ++r) bia[mt][r] = b2[mt * 16 + kg * 4 + r];

  float msum[4][4];
#pragma unroll
  for (int mt = 0; mt < 4; ++mt)
#pragma unroll
    for (int r = 0; r < 4; ++r) msum[mt][r] = 0.f;

#pragma unroll 1
  for (int pass = 0; pass < 2; ++pass) {
    f32x4 acc[4][8];
#pragma unroll
    for (int mt = 0; mt < 4; ++mt)
#pragma unroll
      for (int q = 0; q < 8; ++q) acc[mt][q] = (f32x4){0.f, 0.f, 0.f, 0.f};
    int Pq[8];
#pragma unroll
    for (int q = 0; q < 8; ++q) {
      int p = (wv * 16 + pass * 8 + q) * 16 + l15;
      int y = p >> 5, x = p & 31;
      Pq[q] = y * 34 + x;
    }
#pragma unroll
    for (int sh = 0; sh < 9; ++sh) {
      const int dy = sh / 3, dx = sh % 3;
      const int shoff = (dy * 34 + dx) * 16;
      short8v Af[4];
#pragma unroll
      for (int mt = 0; mt < 4; ++mt)
        Af[mt] = *(const short8v*)(Wb + ((size_t)(sh * 4 + mt) * 64 + lane) * 8);
#pragma unroll
      for (int q = 0; q < 8; ++q) {
        short8v Bf = *(const short8v*)(sm + kg * OCT_STRIDE + Pq[q] * 16 + shoff);
#pragma unroll
        for (int mt = 0; mt < 4; ++mt)
          acc[mt][q] = __builtin_amdgcn_mfma_f32_16x16x32_bf16(Af[mt], Bf, acc[mt][q], 0, 0, 0);
      }
    }
#pragma unroll
    for (int mt = 0; mt < 4; ++mt) {
#pragma unroll
      for (int pr = 0; pr < 4; ++pr) {
        int qa = (pr & 1) + (pr >> 1) * 4;
        int qb = qa + 2;
#pragma unroll
        for (int r = 0; r < 4; ++r) {
          float va = fmaxf(acc[mt][qa][r] + bia[mt][r], 0.f);
          float vb = fmaxf(acc[mt][qb][r] + bia[mt][r], 0.f);
          float v = fmaxf(va, vb);
          v = fmaxf(v, __shfl_xor(v, 1, 64));
          msum[mt][r] += v;
        }
      }
    }
  }
#pragma unroll
  for (int mt = 0; mt < 4; ++mt)
#pragma unroll
    for (int r = 0; r < 4; ++r) {
      float v = msum[mt][r];
      v += __shfl_xor(v, 1, 64);
      v += __shfl_xor(v, 2, 64);
      v += __shfl_xor(v, 4, 64);
      v += __shfl_xor(v, 8, 64);
      if (l15 == 0) part[wv * 64 + mt * 16 + kg * 4 + r] = v * 0.5f;
    }
  __syncthreads();
  if (t < 64)
    feat[(size_t)img * 64 + t] =
        (part[t] + part[64 + t] + part[128 + t] + part[192 + t]) * (1.f / 256.f);
}

// ---------------------------------------------------------------------------
// Generic f32 GEMM (used only for the small cnn-fc)
// ---------------------------------------------------------------------------
struct GemmArgs {
  const float* A0; const float* A1;
  const float* B0; const float* B1;
  const float* bias0; const float* bias1;
  float* C0; float* C1;
  int M, N, K, lda, ldb, ldc, act, resid;
};

template <int TM>
__global__ __launch_bounds__(256) void gemm_bt(GemmArgs g) {
  constexpr int RM = TM / 16;
  const int dir = blockIdx.z;
  const float* __restrict__ A = dir ? g.A1 : g.A0;
  const float* __restrict__ B = dir ? g.B1 : g.B0;
  const float* bias = dir ? g.bias1 : g.bias0;
  float* __restrict__ C = dir ? g.C1 : g.C0;
  __shared__ float sA[16][TM + 4];
  __shared__ float sB[16][68];
  const int t = threadIdx.x;
  const int m0 = blockIdx.x * TM;
  const int n0 = blockIdx.y * 64;
  const int tx = t & 15, ty = t >> 4;
  const int lk = t & 15, lr = t >> 4;
  float acc[RM][4] = {};
  for (int k0 = 0; k0 < g.K; k0 += 16) {
    bool kok = (k0 + lk) < g.K;
#pragma unroll
    for (int rr = 0; rr < RM; ++rr) {
      int m = m0 + lr + rr * 16;
      sA[lk][lr + rr * 16] = (kok && m < g.M) ? A[(size_t)m * g.lda + k0 + lk] : 0.f;
    }
#pragma unroll
    for (int rr = 0; rr < 4; ++rr) {
      int n = n0 + lr + rr * 16;
      sB[lk][lr + rr * 16] = (kok && n < g.N) ? B[(size_t)n * g.ldb + k0 + lk] : 0.f;
    }
    __syncthreads();
#pragma unroll
    for (int kk = 0; kk < 16; ++kk) {
      float av[RM];
#pragma unroll
      for (int i = 0; i < RM; ++i) av[i] = sA[kk][ty * RM + i];
      float b0 = sB[kk][tx*4+0], b1 = sB[kk][tx*4+1], b2 = sB[kk][tx*4+2], b3 = sB[kk][tx*4+3];
#pragma unroll
      for (int i = 0; i < RM; ++i) {
        acc[i][0] = fmaf(av[i], b0, acc[i][0]);
        acc[i][1] = fmaf(av[i], b1, acc[i][1]);
        acc[i][2] = fmaf(av[i], b2, acc[i][2]);
        acc[i][3] = fmaf(av[i], b3, acc[i][3]);
      }
    }
    __syncthreads();
  }
#pragma unroll
  for (int i = 0; i < RM; ++i) {
    int m = m0 + ty * RM + i;
    if (m >= g.M) continue;
#pragma unroll
    for (int j = 0; j < 4; ++j) {
      int n = n0 + tx * 4 + j;
      if (n >= g.N) continue;
      float v = acc[i][j];
      if (bias) v += bias[n];
      size_t ci = (size_t)m * g.ldc + n;
      if (g.resid) v += C[ci];
      C[ci] = v;
    }
  }
}

// ---------------------------------------------------------------------------
// prep_k: concat(video-fc output, audio) -> xf and reversed xr
// ---------------------------------------------------------------------------
__global__ void prep_k(const float* __restrict__ xc0, const float* __restrict__ audio,
                       float* __restrict__ xf, float* __restrict__ xr) {
  int i = blockIdx.x * 256 + threadIdx.x;
  if (i >= TOK * DD) return;
  int d = i & 255, tok = i >> 8, b = tok >> 7, l = tok & 127;
  float v = (d < VF) ? xc0[i] : audio[(size_t)b * (FRAMES * NM) + l * NM + (d - VF)];
  xf[i] = v;
  xr[((size_t)(b * FRAMES + (FRAMES - 1 - l)) << 8) + d] = v;
}

// ---------------------------------------------------------------------------
// inproj_mfma: fused rmsnorm + in_proj (bf16 MFMA).
// Tile 64 tokens x 64 out. A staged+normalized into LDS [kt][oct][m][8] bf16.
// B-fragments direct from packed global weights.
// ---------------------------------------------------------------------------
__global__ __launch_bounds__(256) void inproj_mfma(
    const float* __restrict__ xF, const float* __restrict__ xR,
    const float* __restrict__ nwF, const float* __restrict__ nwR,
    const unsigned short* __restrict__ Wip, int layer,
    float* __restrict__ xzF, float* __restrict__ xzR)
{
  const int dir = blockIdx.z;
  const float* x = dir ? xR : xF;
  const float* nw = dir ? nwR : nwF;
  float* xz = dir ? xzR : xzF;
  __shared__ unsigned short sa[8 * 4 * 64 * 8];   // 32KB
  const int t = threadIdx.x;
  const int m0 = blockIdx.x * 64, n0 = blockIdx.y * 64;
  {
    const int m = t >> 2, q = t & 3;
    const float* row = x + (size_t)(m0 + m) * DD + q * 64;
    float v[64];
    float ss = 0.f;
#pragma unroll
    for (int i = 0; i < 16; ++i) {
      float4 f = ((const float4*)row)[i];
      v[4*i] = f.x; v[4*i+1] = f.y; v[4*i+2] = f.z; v[4*i+3] = f.w;
      ss += f.x*f.x + f.y*f.y + f.z*f.z + f.w*f.w;
    }
    ss += __shfl_xor(ss, 1, 4);
    ss += __shfl_xor(ss, 2, 4);
    float scale = rsqrtf(ss * (1.f / DD) + 1e-5f);
    const float* nwq = nw + q * 64;
#pragma unroll
    for (int o = 0; o < 8; ++o) {
      unsigned ub[4];
#pragma unroll
      for (int p = 0; p < 4; ++p) {
        unsigned short lo = f2bf(v[o*8 + 2*p]     * scale * nwq[o*8 + 2*p]);
        unsigned short hi = f2bf(v[o*8 + 2*p + 1] * scale * nwq[o*8 + 2*p + 1]);
        ub[p] = (unsigned)lo | ((unsigned)hi << 16);
      }
      int k = q * 64 + o * 8;
      int kt = k >> 5, oct = (k >> 3) & 3;
      uint4 w4 = {ub[0], ub[1], ub[2], ub[3]};
      *(uint4*)(sa + ((size_t)(kt * 4 + oct) * 64 + m) * 8) = w4;
    }
  }
  __syncthreads();
  const int lane = t & 63, w = t >> 6;
  const int ntile = blockIdx.y * 4 + w;
  const unsigned short* wb = Wip + (((size_t)(dir * 4 + layer) * 512 + ntile * 8) * 64 + lane) * 8;
  f32x4 acc[4];
#pragma unroll
  for (int mt = 0; mt < 4; ++mt) acc[mt] = (f32x4){0.f, 0.f, 0.f, 0.f};
#pragma unroll
  for (int kt = 0; kt < 8; ++kt) {
    short8v bf = *(const short8v*)(wb + (size_t)kt * 64 * 8);
#pragma unroll
    for (int mt = 0; mt < 4; ++mt) {
      short8v af = *(const short8v*)(sa + ((size_t)(kt * 4 + (lane >> 4)) * 64 + mt * 16 + (lane & 15)) * 8);
      acc[mt] = __builtin_amdgcn_mfma_f32_16x16x32_bf16(af, bf, acc[mt], 0, 0, 0);
    }
  }
#pragma unroll
  for (int mt = 0; mt < 4; ++mt)
#pragma unroll
    for (int r = 0; r < 4; ++r)
      xz[(size_t)(m0 + mt * 16 + (lane >> 4) * 4 + r) * 1024 + n0 + w * 16 + (lane & 15)] = acc[mt][r];
}

// ---------------------------------------------------------------------------
// xproj_k: fused causal-conv4+silu (A-staging) + x_proj GEMM (f32 VALU).
// Tile 64 tokens x 48 out, K=512 in 8 chunks. Writes xc (f32) and dbc.
// ---------------------------------------------------------------------------
__global__ __launch_bounds__(256) void xproj_k(
    const float* __restrict__ xzF, const float* __restrict__ xzR,
    const float* __restrict__ cwF, const float* __restrict__ cwR,
    const float* __restrict__ cbF, const float* __restrict__ cbR,
    const float* __restrict__ xpF, const float* __restrict__ xpR,
    float* __restrict__ xcF, float* __restrict__ xcR,
    float* __restrict__ dbF, float* __restrict__ dbR)
{
  const int dir = blockIdx.z;
  const float* xz = dir ? xzR : xzF;
  const float* cw = dir ? cwR : cwF;
  const float* cb = dir ? cbR : cbF;
  const float* xp = dir ? xpR : xpF;
  float* xc = dir ? xcR : xcF;
  float* db = dir ? dbR : dbF;
  __shared__ float sA[64][68];
  __shared__ float sB[64][49];
  const int t = threadIdx.x;
  const int m0 = blockIdx.x * 64;
  const int tn = t & 15, tm = t >> 4;
  float acc[4][3] = {};
#pragma unroll 1
  for (int kt = 0; kt < 8; ++kt) {
    __syncthreads();
#pragma unroll
    for (int ii = 0; ii < 16; ++ii) {
      int i = ii * 256 + t;
      int mm = i >> 6, e = i & 63;
      int eg = kt * 64 + e;
      int tok = m0 + mm, l = tok & 127;
      float4 cv = ((const float4*)cw)[eg];
      float a = cb[eg];
      const float* col = xz + (size_t)tok * 1024 + eg;
      if (l >= 3) a = fmaf(col[-3 * 1024], cv.x, a);
      if (l >= 2) a = fmaf(col[-2 * 1024], cv.y, a);
      if (l >= 1) a = fmaf(col[-1 * 1024], cv.z, a);
      a = fmaf(col[0], cv.w, a);
      a = a / (1.f + __expf(-a));
      sA[e][mm] = a;
      xc[(size_t)tok * EDIM + eg] = a;
    }
#pragma unroll
    for (int ii = 0; ii < 12; ++ii) {
      int i = ii * 256 + t;
      int n = i >> 6, k = i & 63;
      sB[k][n] = xp[(size_t)n * EDIM + kt * 64 + k];
    }
    __syncthreads();
#pragma unroll 4
    for (int kk = 0; kk < 64; ++kk) {
      float a4[4];
      *(float4*)a4 = *(const float4*)&sA[kk][tm * 4];
      float b0 = sB[kk][tn * 3], b1 = sB[kk][tn * 3 + 1], b2 = sB[kk][tn * 3 + 2];
#pragma unroll
      for (int i = 0; i < 4; ++i) {
        acc[i][0] = fmaf(a4[i], b0, acc[i][0]);
        acc[i][1] = fmaf(a4[i], b1, acc[i][1]);
        acc[i][2] = fmaf(a4[i], b2, acc[i][2]);
      }
    }
  }
#pragma unroll
  for (int i = 0; i < 4; ++i)
#pragma unroll
    for (int j = 0; j < 3; ++j)
      db[(size_t)(m0 + tm * 4 + i) * 48 + tn * 3 + j] = acc[i][j];
}

// ---------------------------------------------------------------------------
// scan3_k: fused dt-proj+softplus + selective scan + gating. 16 lanes/(b,e).
// All per-step inputs LDS-resident. Writes y bf16 in out_proj fragment order.
// ---------------------------------------------------------------------------
__global__ __launch_bounds__(256) void scan3_k(
    const float* __restrict__ xzF, const float* __restrict__ xzR,
    const float* __restrict__ xcF, const float* __restrict__ xcR,
    const float* __restrict__ dbF, const float* __restrict__ dbR,
    const float* __restrict__ dwF, const float* __restrict__ dwR,
    const float* __restrict__ dtbF, const float* __restrict__ dtbR,
    const float* __restrict__ AlF, const float* __restrict__ AlR,
    const float* __restrict__ DpF, const float* __restrict__ DpR,
    unsigned short* __restrict__ yoF, unsigned short* __restrict__ yoR)
{
  const int dir = blockIdx.z;
  const float* xz = dir ? xzR : xzF;
  const float* xc = dir ? xcR : xcF;
  const float* db = dir ? dbR : dbF;
  const float* dw = dir ? dwR : dwF;
  const float* dtbv = dir ? dtbR : dtbF;
  const float* Al = dir ? AlR : AlF;
  const float* Dp = dir ? DpR : DpF;
  unsigned short* yo = dir ? yoR : yoF;

  __shared__ float sdb[FRAMES * 48];   // 24KB
  __shared__ float sxc[FRAMES * 16];   // 8KB
  __shared__ float sz[FRAMES * 16];    // 8KB
  const int b = blockIdx.x >> 5;
  const int e0 = (blockIdx.x & 31) << 4;
  const int t = threadIdx.x, g = t >> 4, n = t & 15;
  const int e = e0 + g;

  const float* dbp = db + (size_t)b * FRAMES * 48;
  for (int i = t; i < FRAMES * 48 / 4; i += 256)
    ((float4*)sdb)[i] = ((const float4*)dbp)[i];
  for (int i = t; i < FRAMES * 16; i += 256) {
    int l = i >> 4, c = i & 15;
    sxc[i] = xc[(size_t)(b * FRAMES + l) * EDIM + e0 + c];
    sz[i]  = xz[(size_t)(b * FRAMES + l) * 1024 + 512 + e0 + c];
  }
  float An = -expf(Al[e * NSTATE + n]);
  float dwn = dw[e * DTRANK + n];
  float dtb = dtbv[e];
  float Dv = Dp[e];
  float h = 0.f;
  unsigned short* yp = yo + ((size_t)((e >> 5) * 4 + ((e >> 3) & 3)) * 1024 + b * FRAMES) * 8 + (e & 7);
  __syncthreads();

#pragma unroll 1
  for (int l = 0; l < FRAMES; ++l) {
    float p = sdb[l * 48 + n] * dwn;
    p += __shfl_xor(p, 1, 16);
    p += __shfl_xor(p, 2, 16);
    p += __shfl_xor(p, 4, 16);
    p += __shfl_xor(p, 8, 16);
    float lin = p + dtb;
    float dlt = (lin > 20.f) ? lin : log1pf(expf(lin));
    float xcv = sxc[l * 16 + g];
    float Bn = sdb[l * 48 + 16 + n];
    float Cn = sdb[l * 48 + 32 + n];
    float dA = __expf(dlt * An);
    h = fmaf(dA, h, dlt * xcv * Bn);
    float part = h * Cn;
    part += __shfl_xor(part, 1, 16);
    part += __shfl_xor(part, 2, 16);
    part += __shfl_xor(part, 4, 16);
    part += __shfl_xor(part, 8, 16);
    if (n == 0) {
      float zz = sz[l * 16 + g];
      float a2 = fmaf(Dv, xcv, part);
      float sv = zz / (1.f + __expf(-zz));
      yp[(size_t)l * 8] = f2bf(a2 * sv);
    }
  }
}

// ---------------------------------------------------------------------------
// outproj_mfma: zero-LDS bf16 MFMA GEMM. A from y_oct (fragment-ordered),
// B from packed weights. Epilogue: residual += into xf/xr.
// ---------------------------------------------------------------------------
__global__ __launch_bounds__(256) void outproj_mfma(
    const unsigned short* __restrict__ yoF, const unsigned short* __restrict__ yoR,
    const unsigned short* __restrict__ Wop, int layer,
    float* __restrict__ xF, float* __restrict__ xR)
{
  const int dir = blockIdx.z;
  const unsigned short* yo = dir ? yoR : yoF;
  float* xx = dir ? xR : xF;
  const int t = threadIdx.x, lane = t & 63, w = t >> 6;
  const int m0 = blockIdx.x * 32, n0 = blockIdx.y * 64;
  const int ntile = blockIdx.y * 4 + w;
  const unsigned short* wb = Wop + (((size_t)(dir * 4 + layer) * 256 + ntile * 16) * 64 + lane) * 8;
  f32x4 acc[2];
  acc[0] = (f32x4){0.f, 0.f, 0.f, 0.f};
  acc[1] = (f32x4){0.f, 0.f, 0.f, 0.f};
#pragma unroll
  for (int kt = 0; kt < 16; ++kt) {
    short8v bf = *(const short8v*)(wb + (size_t)kt * 64 * 8);
#pragma unroll
    for (int mt = 0; mt < 2; ++mt) {
      short8v af = *(const short8v*)(yo + ((size_t)(kt * 4 + (lane >> 4)) * 1024 + m0 + mt * 16 + (lane & 15)) * 8);
      acc[mt] = __builtin_amdgcn_mfma_f32_16x16x32_bf16(af, bf, acc[mt], 0, 0, 0);
    }
  }
#pragma unroll
  for (int mt = 0; mt < 2; ++mt)
#pragma unroll
    for (int r = 0; r < 4; ++r) {
      size_t ci = (size_t)(m0 + mt * 16 + (lane >> 4) * 4 + r) * DD + n0 + w * 16 + (lane & 15);
      xx[ci] += acc[mt][r];
    }
}

__global__ __launch_bounds__(256) void head_k(
    const float* __restrict__ xf, const float* __restrict__ xr,
    const float* __restrict__ fcw, const float* __restrict__ fcb,
    const float* __restrict__ fc2w, const float* __restrict__ fc2b,
    float* __restrict__ out)
{
  int b = blockIdx.x;
  __shared__ float xl[2 * DD];
  __shared__ float h[DD];
  int t = threadIdx.x;
  xl[t]      = xf[(size_t)(b * FRAMES + FRAMES - 1) * DD + t];
  xl[DD + t] = xr[(size_t)(b * FRAMES + 0) * DD + t];
  __syncthreads();
  float acc = fcb[t];
  for (int k = 0; k < 2 * DD; ++k) acc = fmaf(xl[k], fcw[(size_t)t * 2 * DD + k], acc);
  h[t] = acc;
  __syncthreads();
  if (t < 2) {
    float a = fc2b[t];
    for (int k = 0; k < DD; ++k) a = fmaf(h[k], fc2w[(size_t)t * DD + k], a);
    out[b * 2 + t] = a;
  }
}

// ---------------------------------------------------------------------------
extern "C" void kernel_launch(void* const* d_in, const int* in_sizes, int n_in,
                              void* d_out, int out_size, void* d_ws, size_t ws_size,
                              hipStream_t stream) {
  const float* video = (const float*)d_in[0];
  const float* audio = (const float*)d_in[1];
  const float* c1w = (const float*)d_in[2];
  const float* c1b = (const float*)d_in[3];
  const float* c2w = (const float*)d_in[4];
  const float* c2b = (const float*)d_in[5];
  const float* fcw = (const float*)d_in[6];
  const float* fcb = (const float*)d_in[7];
  const float* Wf[10]; const float* Wb_[10];
  for (int i = 0; i < 10; ++i) { Wf[i] = (const float*)d_in[8+i]; Wb_[i] = (const float*)d_in[18+i]; }
  const float* fc_w  = (const float*)d_in[28];
  const float* fc_b  = (const float*)d_in[29];
  const float* fc2_w = (const float*)d_in[30];
  const float* fc2_b = (const float*)d_in[31];
  float* out = (float*)d_out;

  // workspace (float slots)
  float* ws   = (float*)d_ws;
  float* feat = ws;                       // 65536
  float* xc0  = feat + 65536;             // 262144
  float* xf   = xc0  + 262144;            // 262144
  float* xr   = xf   + 262144;            // 262144
  float* xzF  = xr   + 262144;            // 1048576
  float* xzR  = xzF  + 1048576;           // 1048576
  float* xcF  = xzR  + 1048576;           // 524288
  float* xcR  = xcF  + 524288;            // 524288
  float* dbF  = xcR  + 524288;            // 49152
  float* dbR  = dbF  + 49152;             // 49152
  unsigned short* yoF = (unsigned short*)(dbR + 49152);     // 524288 shorts = 262144 fl
  unsigned short* yoR = yoF + 524288;                        // 262144 fl
  unsigned short* X1  = yoR + 524288;                        // 33554432 shorts
  unsigned short* Wbp = X1 + 33554432;                       // 18432 shorts
  unsigned short* Wip = Wbp + 18432;                         // 2097152 shorts
  unsigned short* Wop = Wip + 2097152;                       // 1048576 shorts

  // 1. packs + CNN
  pack_w2<<<dim3(9), 256, 0, stream>>>(c2w, Wbp);
  pack_mamba<<<dim3(1536), 256, 0, stream>>>(Wf[1], Wb_[1], Wf[9], Wb_[9], Wip, Wop);
  conv1_k<<<dim3(TOK), 256, 0, stream>>>(video, c1w, c1b, X1);
  conv2_k<<<dim3(TOK), 256, (size_t)(X_LDS_BYTES + 1024), stream>>>(X1, Wbp, c2b, feat);

  // 2. cnn fc + prep
  { GemmArgs g{feat, feat, fcw, fcw, fcb, fcb, xc0, xc0, TOK, VF, 64, 64, 64, DD, 0, 0};
    gemm_bt<64><<<dim3(16, 4, 1), 256, 0, stream>>>(g); }
  prep_k<<<dim3(TOK * DD / 256), 256, 0, stream>>>(xc0, audio, xf, xr);

  // 3. bi-Mamba (4 kernels per layer)
  for (int l = 0; l < NLAYER; ++l) {
    const float* nwF  = Wf[0] + l*DD;              const float* nwR  = Wb_[0] + l*DD;
    const float* cwF_ = Wf[2] + l*EDIM*4;          const float* cwR_ = Wb_[2] + l*EDIM*4;
    const float* cbF_ = Wf[3] + l*EDIM;            const float* cbR_ = Wb_[3] + l*EDIM;
    const float* xpF  = Wf[4] + l*48*EDIM;         const float* xpR  = Wb_[4] + l*48*EDIM;
    const float* dwF  = Wf[5] + l*EDIM*DTRANK;     const float* dwR  = Wb_[5] + l*EDIM*DTRANK;
    const float* dtbF = Wf[6] + l*EDIM;            const float* dtbR = Wb_[6] + l*EDIM;
    const float* AlF  = Wf[7] + l*EDIM*NSTATE;     const float* AlR  = Wb_[7] + l*EDIM*NSTATE;
    const float* DpF  = Wf[8] + l*EDIM;            const float* DpR  = Wb_[8] + l*EDIM;

    inproj_mfma<<<dim3(16, 16, 2), 256, 0, stream>>>(xf, xr, nwF, nwR, Wip, l, xzF, xzR);
    xproj_k<<<dim3(16, 1, 2), 256, 0, stream>>>(xzF, xzR, cwF_, cwR_, cbF_, cbR_, xpF, xpR,
                                                xcF, xcR, dbF, dbR);
    scan3_k<<<dim3(256, 1, 2), 256, 0, stream>>>(xzF, xzR, xcF, xcR, dbF, dbR, dwF, dwR,
                                                 dtbF, dtbR, AlF, AlR, DpF, DpR, yoF, yoR);
    outproj_mfma<<<dim3(32, 4, 2), 256, 0, stream>>>(yoF, yoR, Wop, l, xf, xr);
  }

  // 4. head
  head_k<<<dim3(BATCH), 256, 0, stream>>>(xf, xr, fc_w, fc_b, fc2_w, fc2_b, out);
}

// Round 5
// 774.016 us; speedup vs baseline: 1.6532x; 1.6532x over previous
//
#include <hip/hip_runtime.h>
#include <hip/hip_bf16.h>
#include <cstdint>
#include <cstddef>

#define BATCH 8
#define FRAMES 128
#define TOK (BATCH*FRAMES)   // 1024
#define NM 60
#define VF 196
#define DD 256
#define EDIM 512
#define NSTATE 16
#define DTRANK 16
#define NLAYER 4

typedef __attribute__((ext_vector_type(8))) short short8v;
typedef __attribute__((ext_vector_type(4))) float f32x4;

__device__ __forceinline__ unsigned short f2bf(float f) {
  unsigned x = __float_as_uint(f);
  unsigned r = (x + 0x7FFFu + ((x >> 16) & 1u)) >> 16;
  return (unsigned short)r;
}

// ---------------------------------------------------------------------------
// pack_w2: W2 (64,32,3,3) f32 -> Wb[shift(9)][mtile(4)][lane(64)][8] bf16
// ---------------------------------------------------------------------------
__global__ void pack_w2(const float* __restrict__ w2, unsigned short* __restrict__ Wb) {
  int id = blockIdx.x * 256 + threadIdx.x;
  if (id >= 9 * 4 * 64) return;
  int lane = id & 63;
  int mt = (id >> 6) & 3;
  int sh = id >> 8;
  int dy = sh / 3, dx = sh % 3;
  int oc = mt * 16 + (lane & 15);
  int ic0 = (lane >> 4) * 8;
  unsigned u[4];
#pragma unroll
  for (int p = 0; p < 4; ++p) {
    unsigned short lo = f2bf(w2[((oc * 32 + ic0 + 2 * p) * 3 + dy) * 3 + dx]);
    unsigned short hi = f2bf(w2[((oc * 32 + ic0 + 2 * p + 1) * 3 + dy) * 3 + dx]);
    u[p] = (unsigned)lo | ((unsigned)hi << 16);
  }
  uint4 v = {u[0], u[1], u[2], u[3]};
  *(uint4*)(Wb + (size_t)id * 8) = v;
}

// ---------------------------------------------------------------------------
// pack_mamba: in_proj / out_proj / x_proj weights -> bf16 MFMA B-fragment order
//   Wip: [dl(8)][ntile(64)][kt(8)][lane(64)][8]
//   Wop: [dl(8)][ntile(16)][kt(16)][lane(64)][8]
//   Wxp: [dl(8)][ntile(3)][kt(16)][lane(64)][8]
// ---------------------------------------------------------------------------
__global__ void pack_mamba(const float* __restrict__ ipF, const float* __restrict__ ipR,
                           const float* __restrict__ opF, const float* __restrict__ opR,
                           const float* __restrict__ xpF, const float* __restrict__ xpR,
                           unsigned short* __restrict__ Wip, unsigned short* __restrict__ Wop,
                           unsigned short* __restrict__ Wxp) {
  int id = blockIdx.x * 256 + threadIdx.x;
  if (id < 262144) {                     // in_proj
    int dl = id >> 15, r = id & 32767;
    int ntile = r >> 9, kt = (r >> 6) & 7, lane = r & 63;
    int dir = dl >> 2, layer = dl & 3;
    const float* src = (dir ? ipR : ipF) + (size_t)layer * 1024 * 256
                       + (size_t)(ntile * 16 + (lane & 15)) * 256 + kt * 32 + (lane >> 4) * 8;
    unsigned u[4];
#pragma unroll
    for (int p = 0; p < 4; ++p)
      u[p] = (unsigned)f2bf(src[2 * p]) | ((unsigned)f2bf(src[2 * p + 1]) << 16);
    uint4 v = {u[0], u[1], u[2], u[3]};
    *(uint4*)(Wip + (size_t)id * 8) = v;
  } else if (id < 262144 + 131072) {     // out_proj
    int id2 = id - 262144;
    int dl = id2 >> 14, rr = id2 & 16383;
    int ntile = rr >> 10, kt = (rr >> 6) & 15, lane = rr & 63;
    int dir = dl >> 2, layer = dl & 3;
    const float* src = (dir ? opR : opF) + (size_t)layer * 256 * 512
                       + (size_t)(ntile * 16 + (lane & 15)) * 512 + kt * 32 + (lane >> 4) * 8;
    unsigned u[4];
#pragma unroll
    for (int p = 0; p < 4; ++p)
      u[p] = (unsigned)f2bf(src[2 * p]) | ((unsigned)f2bf(src[2 * p + 1]) << 16);
    uint4 v = {u[0], u[1], u[2], u[3]};
    *(uint4*)(Wop + (size_t)id2 * 8) = v;
  } else if (id < 262144 + 131072 + 24576) {  // x_proj (48 x 512)
    int id3 = id - 262144 - 131072;
    int dl = id3 / 3072, rr = id3 % 3072;
    int ntile = rr >> 10, kt = (rr >> 6) & 15, lane = rr & 63;
    int dir = dl >> 2, layer = dl & 3;
    const float* src = (dir ? xpR : xpF) + (size_t)layer * 48 * 512
                       + (size_t)(ntile * 16 + (lane & 15)) * 512 + kt * 32 + (lane >> 4) * 8;
    unsigned u[4];
#pragma unroll
    for (int p = 0; p < 4; ++p)
      u[p] = (unsigned)f2bf(src[2 * p]) | ((unsigned)f2bf(src[2 * p + 1]) << 16);
    uint4 v = {u[0], u[1], u[2], u[3]};
    *(uint4*)(Wxp + (size_t)id3 * 8) = v;
  }
}

// ---------------------------------------------------------------------------
// conv1_k: unchanged (round 3)
// ---------------------------------------------------------------------------
#define C1P 72
__global__ __launch_bounds__(256) void conv1_k(
    const float* __restrict__ video, const float* __restrict__ w1,
    const float* __restrict__ b1, unsigned short* __restrict__ X1)
{
  __shared__ float imgs[3 * 34 * C1P];
  const int img = blockIdx.x, t = threadIdx.x;
  const float* vin = video + (size_t)img * 12288;
  const int px = t & 31, pyl = t >> 5;

#pragma unroll 1
  for (int h = 0; h < 2; ++h) {
    __syncthreads();
    float4 z4 = {0.f, 0.f, 0.f, 0.f};
    for (int i = t; i < (3 * 34 * C1P) / 4; i += 256) ((float4*)imgs)[i] = z4;
    __syncthreads();
    for (int i = t; i < 3 * 33 * 16; i += 256) {
      int ic = i / 528; int rr = (i - ic * 528) >> 4; int c4 = i & 15;
      int r  = rr + (h ? 0 : 1);
      int gr = 32 * h - 1 + r;
      float4 v = *(const float4*)(vin + ic * 4096 + gr * 64 + c4 * 4);
      *(float4*)(imgs + ic * (34 * C1P) + r * C1P + 4 + c4 * 4) = v;
    }
    __syncthreads();
#pragma unroll 1
    for (int s = 0; s < 2; ++s) {
      const int y = pyl + 8 * (2 * h + s);
      const int lr0 = 2 * (pyl + 8 * s);
      float in[3][4][4];
#pragma unroll
      for (int ic = 0; ic < 3; ++ic)
#pragma unroll
        for (int rr = 0; rr < 4; ++rr)
#pragma unroll
          for (int cc = 0; cc < 4; ++cc)
            in[ic][rr][cc] = imgs[ic * (34 * C1P) + (lr0 + rr) * C1P + (2 * px + 3 + cc)];
      unsigned ob[16];
#pragma unroll 1
      for (int ch = 0; ch < 32; ++ch) {
        float wv[27];
#pragma unroll
        for (int j = 0; j < 27; ++j) wv[j] = w1[ch * 27 + j];
        float bb = b1[ch];
        float a0 = bb, a1 = bb, a2 = bb, a3 = bb;
#pragma unroll
        for (int ic = 0; ic < 3; ++ic)
#pragma unroll
          for (int dy = 0; dy < 3; ++dy)
#pragma unroll
            for (int dx = 0; dx < 3; ++dx) {
              float w = wv[ic * 9 + dy * 3 + dx];
              a0 = fmaf(w, in[ic][dy    ][dx    ], a0);
              a1 = fmaf(w, in[ic][dy    ][dx + 1], a1);
              a2 = fmaf(w, in[ic][dy + 1][dx    ], a2);
              a3 = fmaf(w, in[ic][dy + 1][dx + 1], a3);
            }
        a0 = fmaxf(a0, 0.f); a1 = fmaxf(a1, 0.f);
        a2 = fmaxf(a2, 0.f); a3 = fmaxf(a3, 0.f);
        float pooled = fmaxf(fmaxf(a0, a1), fmaxf(a2, a3));
        unsigned short u = f2bf(pooled);
        if ((ch & 1) == 0) ob[ch >> 1] = (unsigned)u;
        else               ob[ch >> 1] |= ((unsigned)u << 16);
      }
      size_t base = ((size_t)img * 1024 + (size_t)y * 32 + px) * 32;
      uint4* dst = (uint4*)(X1 + base);
      uint4 o0 = {ob[0], ob[1], ob[2], ob[3]};
      uint4 o1 = {ob[4], ob[5], ob[6], ob[7]};
      uint4 o2 = {ob[8], ob[9], ob[10], ob[11]};
      uint4 o3 = {ob[12], ob[13], ob[14], ob[15]};
      dst[0] = o0; dst[1] = o1; dst[2] = o2; dst[3] = o3;
    }
  }
}

// ---------------------------------------------------------------------------
// conv2_k: unchanged (round 3)
// ---------------------------------------------------------------------------
#define X_LDS_BYTES (4 * 1156 * 16)
#define OCT_STRIDE  (1156 * 16)
__global__ __launch_bounds__(256) void conv2_k(
    const unsigned short* __restrict__ X1, const unsigned short* __restrict__ Wb,
    const float* __restrict__ b2, float* __restrict__ feat)
{
  extern __shared__ char sm[];
  float* part = (float*)(sm + X_LDS_BYTES);
  const int img = blockIdx.x, t = threadIdx.x;
  const int lane = t & 63, wv = t >> 6;
  const int kg = lane >> 4, l15 = lane & 15;

  for (int j = t; j < 1156; j += 256) {
    int r = j / 34, cc = j - r * 34;
    if (r == 0 || r == 33 || cc == 0 || cc == 33) {
      uint4 z = {0, 0, 0, 0};
#pragma unroll
      for (int oct = 0; oct < 4; ++oct)
        *(uint4*)(sm + oct * OCT_STRIDE + j * 16) = z;
    }
  }
  const uint4* src = (const uint4*)(X1 + (size_t)img * 32768);
#pragma unroll 4
  for (int i = 0; i < 16; ++i) {
    int c = i * 256 + t;
    uint4 v = src[c];
    int oct = c & 3, P = c >> 2;
    int y = P >> 5, x = P & 31;
    *(uint4*)(sm + oct * OCT_STRIDE + ((y + 1) * 34 + (x + 1)) * 16) = v;
  }
  __syncthreads();

  float bia[4][4];
#pragma unroll
  for (int mt = 0; mt < 4; ++mt)
#pragma unroll
    for (int r = 0; r < 4; ++r) bia[mt][r] = b2[mt * 16 + kg * 4 + r];

  float msum[4][4];
#pragma unroll
  for (int mt = 0; mt < 4; ++mt)
#pragma unroll
    for (int r = 0; r < 4; ++r) msum[mt][r] = 0.f;

#pragma unroll 1
  for (int pass = 0; pass < 2; ++pass) {
    f32x4 acc[4][8];
#pragma unroll
    for (int mt = 0; mt < 4; ++mt)
#pragma unroll
      for (int q = 0; q < 8; ++q) acc[mt][q] = (f32x4){0.f, 0.f, 0.f, 0.f};
    int Pq[8];
#pragma unroll
    for (int q = 0; q < 8; ++q) {
      int p = (wv * 16 + pass * 8 + q) * 16 + l15;
      int y = p >> 5, x = p & 31;
      Pq[q] = y * 34 + x;
    }
#pragma unroll
    for (int sh = 0; sh < 9; ++sh) {
      const int dy = sh / 3, dx = sh % 3;
      const int shoff = (dy * 34 + dx) * 16;
      short8v Af[4];
#pragma unroll
      for (int mt = 0; mt < 4; ++mt)
        Af[mt] = *(const short8v*)(Wb + ((size_t)(sh * 4 + mt) * 64 + lane) * 8);
#pragma unroll
      for (int q = 0; q < 8; ++q) {
        short8v Bf = *(const short8v*)(sm + kg * OCT_STRIDE + Pq[q] * 16 + shoff);
#pragma unroll
        for (int mt = 0; mt < 4; ++mt)
          acc[mt][q] = __builtin_amdgcn_mfma_f32_16x16x32_bf16(Af[mt], Bf, acc[mt][q], 0, 0, 0);
      }
    }
#pragma unroll
    for (int mt = 0; mt < 4; ++mt) {
#pragma unroll
      for (int pr = 0; pr < 4; ++pr) {
        int qa = (pr & 1) + (pr >> 1) * 4;
        int qb = qa + 2;
#pragma unroll
        for (int r = 0; r < 4; ++r) {
          float va = fmaxf(acc[mt][qa][r] + bia[mt][r], 0.f);
          float vb = fmaxf(acc[mt][qb][r] + bia[mt][r], 0.f);
          float v = fmaxf(va, vb);
          v = fmaxf(v, __shfl_xor(v, 1, 64));
          msum[mt][r] += v;
        }
      }
    }
  }
#pragma unroll
  for (int mt = 0; mt < 4; ++mt)
#pragma unroll
    for (int r = 0; r < 4; ++r) {
      float v = msum[mt][r];
      v += __shfl_xor(v, 1, 64);
      v += __shfl_xor(v, 2, 64);
      v += __shfl_xor(v, 4, 64);
      v += __shfl_xor(v, 8, 64);
      if (l15 == 0) part[wv * 64 + mt * 16 + kg * 4 + r] = v * 0.5f;
    }
  __syncthreads();
  if (t < 64)
    feat[(size_t)img * 64 + t] =
        (part[t] + part[64 + t] + part[128 + t] + part[192 + t]) * (1.f / 256.f);
}

// ---------------------------------------------------------------------------
// Generic f32 GEMM (used only for the small cnn-fc)
// ---------------------------------------------------------------------------
struct GemmArgs {
  const float* A0; const float* A1;
  const float* B0; const float* B1;
  const float* bias0; const float* bias1;
  float* C0; float* C1;
  int M, N, K, lda, ldb, ldc, act, resid;
};

template <int TM>
__global__ __launch_bounds__(256) void gemm_bt(GemmArgs g) {
  constexpr int RM = TM / 16;
  const int dir = blockIdx.z;
  const float* __restrict__ A = dir ? g.A1 : g.A0;
  const float* __restrict__ B = dir ? g.B1 : g.B0;
  const float* bias = dir ? g.bias1 : g.bias0;
  float* __restrict__ C = dir ? g.C1 : g.C0;
  __shared__ float sA[16][TM + 4];
  __shared__ float sB[16][68];
  const int t = threadIdx.x;
  const int m0 = blockIdx.x * TM;
  const int n0 = blockIdx.y * 64;
  const int tx = t & 15, ty = t >> 4;
  const int lk = t & 15, lr = t >> 4;
  float acc[RM][4] = {};
  for (int k0 = 0; k0 < g.K; k0 += 16) {
    bool kok = (k0 + lk) < g.K;
#pragma unroll
    for (int rr = 0; rr < RM; ++rr) {
      int m = m0 + lr + rr * 16;
      sA[lk][lr + rr * 16] = (kok && m < g.M) ? A[(size_t)m * g.lda + k0 + lk] : 0.f;
    }
#pragma unroll
    for (int rr = 0; rr < 4; ++rr) {
      int n = n0 + lr + rr * 16;
      sB[lk][lr + rr * 16] = (kok && n < g.N) ? B[(size_t)n * g.ldb + k0 + lk] : 0.f;
    }
    __syncthreads();
#pragma unroll
    for (int kk = 0; kk < 16; ++kk) {
      float av[RM];
#pragma unroll
      for (int i = 0; i < RM; ++i) av[i] = sA[kk][ty * RM + i];
      float b0 = sB[kk][tx*4+0], b1 = sB[kk][tx*4+1], b2 = sB[kk][tx*4+2], b3 = sB[kk][tx*4+3];
#pragma unroll
      for (int i = 0; i < RM; ++i) {
        acc[i][0] = fmaf(av[i], b0, acc[i][0]);
        acc[i][1] = fmaf(av[i], b1, acc[i][1]);
        acc[i][2] = fmaf(av[i], b2, acc[i][2]);
        acc[i][3] = fmaf(av[i], b3, acc[i][3]);
      }
    }
    __syncthreads();
  }
#pragma unroll
  for (int i = 0; i < RM; ++i) {
    int m = m0 + ty * RM + i;
    if (m >= g.M) continue;
#pragma unroll
    for (int j = 0; j < 4; ++j) {
      int n = n0 + tx * 4 + j;
      if (n >= g.N) continue;
      float v = acc[i][j];
      if (bias) v += bias[n];
      size_t ci = (size_t)m * g.ldc + n;
      if (g.resid) v += C[ci];
      C[ci] = v;
    }
  }
}

// ---------------------------------------------------------------------------
// prep_k: concat(video-fc output, audio) -> xf and reversed xr
// ---------------------------------------------------------------------------
__global__ void prep_k(const float* __restrict__ xc0, const float* __restrict__ audio,
                       float* __restrict__ xf, float* __restrict__ xr) {
  int i = blockIdx.x * 256 + threadIdx.x;
  if (i >= TOK * DD) return;
  int d = i & 255, tok = i >> 8, b = tok >> 7, l = tok & 127;
  float v = (d < VF) ? xc0[i] : audio[(size_t)b * (FRAMES * NM) + l * NM + (d - VF)];
  xf[i] = v;
  xr[((size_t)(b * FRAMES + (FRAMES - 1 - l)) << 8) + d] = v;
}

// ---------------------------------------------------------------------------
// inproj_mfma: fused rmsnorm + in_proj (bf16 MFMA).
// Block: 64 tokens x 256 out cols (wave loops 4 ntiles). Staging once/block.
// ---------------------------------------------------------------------------
__global__ __launch_bounds__(256) void inproj_mfma(
    const float* __restrict__ xF, const float* __restrict__ xR,
    const float* __restrict__ nwF, const float* __restrict__ nwR,
    const unsigned short* __restrict__ Wip, int layer,
    float* __restrict__ xzF, float* __restrict__ xzR)
{
  const int dir = blockIdx.z;
  const float* x = dir ? xR : xF;
  const float* nw = dir ? nwR : nwF;
  float* xz = dir ? xzR : xzF;
  __shared__ unsigned short sa[8 * 4 * 64 * 8];   // 32KB
  const int t = threadIdx.x;
  const int m0 = blockIdx.x * 64;
  {
    const int m = t >> 2, q = t & 3;
    const float* row = x + (size_t)(m0 + m) * DD + q * 64;
    float v[64];
    float ss = 0.f;
#pragma unroll
    for (int i = 0; i < 16; ++i) {
      float4 f = ((const float4*)row)[i];
      v[4*i] = f.x; v[4*i+1] = f.y; v[4*i+2] = f.z; v[4*i+3] = f.w;
      ss += f.x*f.x + f.y*f.y + f.z*f.z + f.w*f.w;
    }
    ss += __shfl_xor(ss, 1, 4);
    ss += __shfl_xor(ss, 2, 4);
    float scale = rsqrtf(ss * (1.f / DD) + 1e-5f);
    const float* nwq = nw + q * 64;
#pragma unroll
    for (int o = 0; o < 8; ++o) {
      unsigned ub[4];
#pragma unroll
      for (int p = 0; p < 4; ++p) {
        unsigned short lo = f2bf(v[o*8 + 2*p]     * scale * nwq[o*8 + 2*p]);
        unsigned short hi = f2bf(v[o*8 + 2*p + 1] * scale * nwq[o*8 + 2*p + 1]);
        ub[p] = (unsigned)lo | ((unsigned)hi << 16);
      }
      int k = q * 64 + o * 8;
      int kt = k >> 5, oct = (k >> 3) & 3;
      uint4 w4 = {ub[0], ub[1], ub[2], ub[3]};
      *(uint4*)(sa + ((size_t)(kt * 4 + oct) * 64 + m) * 8) = w4;
    }
  }
  __syncthreads();
  const int lane = t & 63, w = t >> 6;
#pragma unroll 1
  for (int ns = 0; ns < 4; ++ns) {
    const int ntile = blockIdx.y * 16 + w * 4 + ns;
    const unsigned short* wb = Wip + (((size_t)(dir * 4 + layer) * 512 + ntile * 8) * 64 + lane) * 8;
    f32x4 acc[4];
#pragma unroll
    for (int mt = 0; mt < 4; ++mt) acc[mt] = (f32x4){0.f, 0.f, 0.f, 0.f};
#pragma unroll
    for (int kt = 0; kt < 8; ++kt) {
      short8v bf = *(const short8v*)(wb + (size_t)kt * 64 * 8);
#pragma unroll
      for (int mt = 0; mt < 4; ++mt) {
        short8v af = *(const short8v*)(sa + ((size_t)(kt * 4 + (lane >> 4)) * 64 + mt * 16 + (lane & 15)) * 8);
        acc[mt] = __builtin_amdgcn_mfma_f32_16x16x32_bf16(af, bf, acc[mt], 0, 0, 0);
      }
    }
#pragma unroll
    for (int mt = 0; mt < 4; ++mt)
#pragma unroll
      for (int r = 0; r < 4; ++r)
        xz[(size_t)(m0 + mt * 16 + (lane >> 4) * 4 + r) * 1024 + ntile * 16 + (lane & 15)] = acc[mt][r];
  }
}

// ---------------------------------------------------------------------------
// convsilu2_k: mass-parallel causal-conv4 + silu. No LDS, no barriers.
// Writes xc f32 [tok][512] and xcb bf16 in MFMA A-fragment order
// [kt(16)*4+oct][tok(1024)][8].
// ---------------------------------------------------------------------------
__global__ __launch_bounds__(256) void convsilu2_k(
    const float* __restrict__ xzF, const float* __restrict__ xzR,
    const float* __restrict__ cwF, const float* __restrict__ cwR,
    const float* __restrict__ cbF, const float* __restrict__ cbR,
    float* __restrict__ xcF, float* __restrict__ xcR,
    unsigned short* __restrict__ xcbF, unsigned short* __restrict__ xcbR)
{
  const int dir = blockIdx.z;
  const float* xz = dir ? xzR : xzF;
  const float* cw = dir ? cwR : cwF;
  const float* cb = dir ? cbR : cbF;
  float* xc = dir ? xcR : xcF;
  unsigned short* xcb = dir ? xcbR : xcbF;

  int i = blockIdx.x * 256 + threadIdx.x;   // 0..65535
  int tok = i >> 6;
  int e0 = (i & 63) << 3;
  int l = tok & 127;
  const float* col = xz + (size_t)tok * 1024 + e0;

  float v3[8] = {}, v2[8] = {}, v1[8] = {}, v0[8];
  if (l >= 3) { *(float4*)v3 = *(const float4*)(col - 3072); *(float4*)(v3+4) = *(const float4*)(col - 3068); }
  if (l >= 2) { *(float4*)v2 = *(const float4*)(col - 2048); *(float4*)(v2+4) = *(const float4*)(col - 2044); }
  if (l >= 1) { *(float4*)v1 = *(const float4*)(col - 1024); *(float4*)(v1+4) = *(const float4*)(col - 1020); }
  *(float4*)v0 = *(const float4*)col; *(float4*)(v0+4) = *(const float4*)(col + 4);

  float cbv[8];
  *(float4*)cbv = *(const float4*)(cb + e0); *(float4*)(cbv+4) = *(const float4*)(cb + e0 + 4);

  float res[8];
#pragma unroll
  for (int j = 0; j < 8; ++j) {
    float4 cv = ((const float4*)cw)[e0 + j];
    float a = cbv[j];
    a = fmaf(cv.x, v3[j], a);
    a = fmaf(cv.y, v2[j], a);
    a = fmaf(cv.z, v1[j], a);
    a = fmaf(cv.w, v0[j], a);
    res[j] = a / (1.f + __expf(-a));
  }
  float4 r0 = {res[0], res[1], res[2], res[3]};
  float4 r1 = {res[4], res[5], res[6], res[7]};
  float* xcp = xc + (size_t)tok * EDIM + e0;
  *(float4*)xcp = r0; *(float4*)(xcp + 4) = r1;

  unsigned ub[4];
#pragma unroll
  for (int p = 0; p < 4; ++p)
    ub[p] = (unsigned)f2bf(res[2*p]) | ((unsigned)f2bf(res[2*p+1]) << 16);
  int kt = e0 >> 5, oct = (e0 >> 3) & 3;
  uint4 w4 = {ub[0], ub[1], ub[2], ub[3]};
  *(uint4*)(xcb + ((size_t)(kt * 4 + oct) * 1024 + tok) * 8) = w4;
}

// ---------------------------------------------------------------------------
// xproj_mfma: pure-register MFMA GEMM. db(1024,48) = xc(1024,512) @ xp^T.
// Block 128 thr (2 waves), each wave: 16 tokens x 48 out, K=512.
// No LDS, no barriers; 64 independent 16B loads per wave pipeline freely.
// ---------------------------------------------------------------------------
__global__ __launch_bounds__(128) void xproj_mfma(
    const unsigned short* __restrict__ xcbF, const unsigned short* __restrict__ xcbR,
    const unsigned short* __restrict__ Wxp, int layer,
    float* __restrict__ dbF, float* __restrict__ dbR)
{
  const int dir = blockIdx.z;
  const unsigned short* xcb = dir ? xcbR : xcbF;
  float* db = dir ? dbR : dbF;
  const int t = threadIdx.x, lane = t & 63, w = t >> 6;
  const int tok0 = blockIdx.x * 32 + w * 16;
  const unsigned short* wbase = Wxp + ((size_t)(dir * 4 + layer) * 3 * 16 * 64) * 8;
  f32x4 acc[3];
#pragma unroll
  for (int nt = 0; nt < 3; ++nt) acc[nt] = (f32x4){0.f, 0.f, 0.f, 0.f};
#pragma unroll
  for (int kt = 0; kt < 16; ++kt) {
    short8v af = *(const short8v*)(xcb + ((size_t)(kt * 4 + (lane >> 4)) * 1024 + tok0 + (lane & 15)) * 8);
#pragma unroll
    for (int nt = 0; nt < 3; ++nt) {
      short8v bf = *(const short8v*)(wbase + ((size_t)(nt * 16 + kt) * 64 + lane) * 8);
      acc[nt] = __builtin_amdgcn_mfma_f32_16x16x32_bf16(af, bf, acc[nt], 0, 0, 0);
    }
  }
#pragma unroll
  for (int nt = 0; nt < 3; ++nt)
#pragma unroll
    for (int r = 0; r < 4; ++r)
      db[(size_t)(tok0 + (lane >> 4) * 4 + r) * 48 + nt * 16 + (lane & 15)] = acc[nt][r];
}

// ---------------------------------------------------------------------------
// scan3_k: fused dt-proj+softplus + selective scan + gating. 16 lanes/(b,e).
// ---------------------------------------------------------------------------
__global__ __launch_bounds__(256) void scan3_k(
    const float* __restrict__ xzF, const float* __restrict__ xzR,
    const float* __restrict__ xcF, const float* __restrict__ xcR,
    const float* __restrict__ dbF, const float* __restrict__ dbR,
    const float* __restrict__ dwF, const float* __restrict__ dwR,
    const float* __restrict__ dtbF, const float* __restrict__ dtbR,
    const float* __restrict__ AlF, const float* __restrict__ AlR,
    const float* __restrict__ DpF, const float* __restrict__ DpR,
    unsigned short* __restrict__ yoF, unsigned short* __restrict__ yoR)
{
  const int dir = blockIdx.z;
  const float* xz = dir ? xzR : xzF;
  const float* xc = dir ? xcR : xcF;
  const float* db = dir ? dbR : dbF;
  const float* dw = dir ? dwR : dwF;
  const float* dtbv = dir ? dtbR : dtbF;
  const float* Al = dir ? AlR : AlF;
  const float* Dp = dir ? DpR : DpF;
  unsigned short* yo = dir ? yoR : yoF;

  __shared__ float sdb[FRAMES * 48];
  __shared__ float sxc[FRAMES * 16];
  __shared__ float sz[FRAMES * 16];
  const int b = blockIdx.x >> 5;
  const int e0 = (blockIdx.x & 31) << 4;
  const int t = threadIdx.x, g = t >> 4, n = t & 15;
  const int e = e0 + g;

  const float* dbp = db + (size_t)b * FRAMES * 48;
  for (int i = t; i < FRAMES * 48 / 4; i += 256)
    ((float4*)sdb)[i] = ((const float4*)dbp)[i];
  for (int i = t; i < FRAMES * 16; i += 256) {
    int l = i >> 4, c = i & 15;
    sxc[i] = xc[(size_t)(b * FRAMES + l) * EDIM + e0 + c];
    sz[i]  = xz[(size_t)(b * FRAMES + l) * 1024 + 512 + e0 + c];
  }
  float An = -expf(Al[e * NSTATE + n]);
  float dwn = dw[e * DTRANK + n];
  float dtb = dtbv[e];
  float Dv = Dp[e];
  float h = 0.f;
  unsigned short* yp = yo + ((size_t)((e >> 5) * 4 + ((e >> 3) & 3)) * 1024 + b * FRAMES) * 8 + (e & 7);
  __syncthreads();

#pragma unroll 1
  for (int l = 0; l < FRAMES; ++l) {
    float p = sdb[l * 48 + n] * dwn;
    p += __shfl_xor(p, 1, 16);
    p += __shfl_xor(p, 2, 16);
    p += __shfl_xor(p, 4, 16);
    p += __shfl_xor(p, 8, 16);
    float lin = p + dtb;
    float dlt = (lin > 20.f) ? lin : log1pf(expf(lin));
    float xcv = sxc[l * 16 + g];
    float Bn = sdb[l * 48 + 16 + n];
    float Cn = sdb[l * 48 + 32 + n];
    float dA = __expf(dlt * An);
    h = fmaf(dA, h, dlt * xcv * Bn);
    float part = h * Cn;
    part += __shfl_xor(part, 1, 16);
    part += __shfl_xor(part, 2, 16);
    part += __shfl_xor(part, 4, 16);
    part += __shfl_xor(part, 8, 16);
    if (n == 0) {
      float zz = sz[l * 16 + g];
      float a2 = fmaf(Dv, xcv, part);
      float sv = zz / (1.f + __expf(-zz));
      yp[(size_t)l * 8] = f2bf(a2 * sv);
    }
  }
}

// ---------------------------------------------------------------------------
// outproj_mfma: zero-LDS bf16 MFMA GEMM + residual add.
// ---------------------------------------------------------------------------
__global__ __launch_bounds__(256) void outproj_mfma(
    const unsigned short* __restrict__ yoF, const unsigned short* __restrict__ yoR,
    const unsigned short* __restrict__ Wop, int layer,
    float* __restrict__ xF, float* __restrict__ xR)
{
  const int dir = blockIdx.z;
  const unsigned short* yo = dir ? yoR : yoF;
  float* xx = dir ? xR : xF;
  const int t = threadIdx.x, lane = t & 63, w = t >> 6;
  const int m0 = blockIdx.x * 32, n0 = blockIdx.y * 64;
  const int ntile = blockIdx.y * 4 + w;
  const unsigned short* wb = Wop + (((size_t)(dir * 4 + layer) * 256 + ntile * 16) * 64 + lane) * 8;
  f32x4 acc[2];
  acc[0] = (f32x4){0.f, 0.f, 0.f, 0.f};
  acc[1] = (f32x4){0.f, 0.f, 0.f, 0.f};
#pragma unroll
  for (int kt = 0; kt < 16; ++kt) {
    short8v bf = *(const short8v*)(wb + (size_t)kt * 64 * 8);
#pragma unroll
    for (int mt = 0; mt < 2; ++mt) {
      short8v af = *(const short8v*)(yo + ((size_t)(kt * 4 + (lane >> 4)) * 1024 + m0 + mt * 16 + (lane & 15)) * 8);
      acc[mt] = __builtin_amdgcn_mfma_f32_16x16x32_bf16(af, bf, acc[mt], 0, 0, 0);
    }
  }
#pragma unroll
  for (int mt = 0; mt < 2; ++mt)
#pragma unroll
    for (int r = 0; r < 4; ++r) {
      size_t ci = (size_t)(m0 + mt * 16 + (lane >> 4) * 4 + r) * DD + n0 + w * 16 + (lane & 15);
      xx[ci] += acc[mt][r];
    }
}

__global__ __launch_bounds__(256) void head_k(
    const float* __restrict__ xf, const float* __restrict__ xr,
    const float* __restrict__ fcw, const float* __restrict__ fcb,
    const float* __restrict__ fc2w, const float* __restrict__ fc2b,
    float* __restrict__ out)
{
  int b = blockIdx.x;
  __shared__ float xl[2 * DD];
  __shared__ float h[DD];
  int t = threadIdx.x;
  xl[t]      = xf[(size_t)(b * FRAMES + FRAMES - 1) * DD + t];
  xl[DD + t] = xr[(size_t)(b * FRAMES + 0) * DD + t];
  __syncthreads();
  float acc = fcb[t];
  for (int k = 0; k < 2 * DD; ++k) acc = fmaf(xl[k], fcw[(size_t)t * 2 * DD + k], acc);
  h[t] = acc;
  __syncthreads();
  if (t < 2) {
    float a = fc2b[t];
    for (int k = 0; k < DD; ++k) a = fmaf(h[k], fc2w[(size_t)t * DD + k], a);
    out[b * 2 + t] = a;
  }
}

// ---------------------------------------------------------------------------
extern "C" void kernel_launch(void* const* d_in, const int* in_sizes, int n_in,
                              void* d_out, int out_size, void* d_ws, size_t ws_size,
                              hipStream_t stream) {
  const float* video = (const float*)d_in[0];
  const float* audio = (const float*)d_in[1];
  const float* c1w = (const float*)d_in[2];
  const float* c1b = (const float*)d_in[3];
  const float* c2w = (const float*)d_in[4];
  const float* c2b = (const float*)d_in[5];
  const float* fcw = (const float*)d_in[6];
  const float* fcb = (const float*)d_in[7];
  const float* Wf[10]; const float* Wb_[10];
  for (int i = 0; i < 10; ++i) { Wf[i] = (const float*)d_in[8+i]; Wb_[i] = (const float*)d_in[18+i]; }
  const float* fc_w  = (const float*)d_in[28];
  const float* fc_b  = (const float*)d_in[29];
  const float* fc2_w = (const float*)d_in[30];
  const float* fc2_b = (const float*)d_in[31];
  float* out = (float*)d_out;

  // workspace (float slots)
  float* ws   = (float*)d_ws;
  float* feat = ws;                       // 65536
  float* xc0  = feat + 65536;             // 262144
  float* xf   = xc0  + 262144;            // 262144
  float* xr   = xf   + 262144;            // 262144
  float* xzF  = xr   + 262144;            // 1048576
  float* xzR  = xzF  + 1048576;           // 1048576
  float* xcF  = xzR  + 1048576;           // 524288
  float* xcR  = xcF  + 524288;            // 524288
  float* dbF  = xcR  + 524288;            // 49152
  float* dbR  = dbF  + 49152;             // 49152
  unsigned short* yoF = (unsigned short*)(dbR + 49152);     // 524288 sh
  unsigned short* yoR = yoF + 524288;
  unsigned short* X1  = yoR + 524288;                        // 33554432 sh
  unsigned short* Wbp = X1 + 33554432;                       // 18432 sh
  unsigned short* Wip = Wbp + 18432;                         // 2097152 sh
  unsigned short* Wop = Wip + 2097152;                       // 1048576 sh
  unsigned short* Wxp = Wop + 1048576;                       // 196608 sh
  unsigned short* xcbF = Wxp + 196608;                       // 524288 sh
  unsigned short* xcbR = xcbF + 524288;                      // 524288 sh

  // 1. packs + CNN
  pack_w2<<<dim3(9), 256, 0, stream>>>(c2w, Wbp);
  pack_mamba<<<dim3(1632), 256, 0, stream>>>(Wf[1], Wb_[1], Wf[9], Wb_[9], Wf[4], Wb_[4],
                                             Wip, Wop, Wxp);
  conv1_k<<<dim3(TOK), 256, 0, stream>>>(video, c1w, c1b, X1);
  conv2_k<<<dim3(TOK), 256, (size_t)(X_LDS_BYTES + 1024), stream>>>(X1, Wbp, c2b, feat);

  // 2. cnn fc + prep
  { GemmArgs g{feat, feat, fcw, fcw, fcb, fcb, xc0, xc0, TOK, VF, 64, 64, 64, DD, 0, 0};
    gemm_bt<64><<<dim3(16, 4, 1), 256, 0, stream>>>(g); }
  prep_k<<<dim3(TOK * DD / 256), 256, 0, stream>>>(xc0, audio, xf, xr);

  // 3. bi-Mamba (5 kernels per layer)
  for (int l = 0; l < NLAYER; ++l) {
    const float* nwF  = Wf[0] + l*DD;              const float* nwR  = Wb_[0] + l*DD;
    const float* cwF_ = Wf[2] + l*EDIM*4;          const float* cwR_ = Wb_[2] + l*EDIM*4;
    const float* cbF_ = Wf[3] + l*EDIM;            const float* cbR_ = Wb_[3] + l*EDIM;
    const float* dwF  = Wf[5] + l*EDIM*DTRANK;     const float* dwR  = Wb_[5] + l*EDIM*DTRANK;
    const float* dtbF = Wf[6] + l*EDIM;            const float* dtbR = Wb_[6] + l*EDIM;
    const float* AlF  = Wf[7] + l*EDIM*NSTATE;     const float* AlR  = Wb_[7] + l*EDIM*NSTATE;
    const float* DpF  = Wf[8] + l*EDIM;            const float* DpR  = Wb_[8] + l*EDIM;

    inproj_mfma<<<dim3(16, 4, 2), 256, 0, stream>>>(xf, xr, nwF, nwR, Wip, l, xzF, xzR);
    convsilu2_k<<<dim3(256, 1, 2), 256, 0, stream>>>(xzF, xzR, cwF_, cwR_, cbF_, cbR_,
                                                     xcF, xcR, xcbF, xcbR);
    xproj_mfma<<<dim3(32, 1, 2), 128, 0, stream>>>(xcbF, xcbR, Wxp, l, dbF, dbR);
    scan3_k<<<dim3(256, 1, 2), 256, 0, stream>>>(xzF, xzR, xcF, xcR, dbF, dbR, dwF, dwR,
                                                 dtbF, dtbR, AlF, AlR, DpF, DpR, yoF, yoR);
    outproj_mfma<<<dim3(32, 4, 2), 256, 0, stream>>>(yoF, yoR, Wop, l, xf, xr);
  }

  // 4. head
  head_k<<<dim3(BATCH), 256, 0, stream>>>(xf, xr, fc_w, fc_b, fc2_w, fc2_b, out);
}

// Round 6
// 525.331 us; speedup vs baseline: 2.4359x; 1.4734x over previous
//
#include <hip/hip_runtime.h>
#include <hip/hip_bf16.h>
#include <cstdint>
#include <cstddef>

#define BATCH 8
#define FRAMES 128
#define TOK (BATCH*FRAMES)   // 1024
#define NM 60
#define VF 196
#define DD 256
#define EDIM 512
#define NSTATE 16
#define DTRANK 16
#define NLAYER 4

typedef __attribute__((ext_vector_type(8))) short short8v;
typedef __attribute__((ext_vector_type(4))) float f32x4;

__device__ __forceinline__ unsigned short f2bf(float f) {
  unsigned x = __float_as_uint(f);
  unsigned r = (x + 0x7FFFu + ((x >> 16) & 1u)) >> 16;
  return (unsigned short)r;
}

// ---------------------------------------------------------------------------
// pack_w2: W2 (64,32,3,3) f32 -> Wb[shift(9)][mtile(4)][lane(64)][8] bf16
// ---------------------------------------------------------------------------
__global__ void pack_w2(const float* __restrict__ w2, unsigned short* __restrict__ Wb) {
  int id = blockIdx.x * 256 + threadIdx.x;
  if (id >= 9 * 4 * 64) return;
  int lane = id & 63;
  int mt = (id >> 6) & 3;
  int sh = id >> 8;
  int dy = sh / 3, dx = sh % 3;
  int oc = mt * 16 + (lane & 15);
  int ic0 = (lane >> 4) * 8;
  unsigned u[4];
#pragma unroll
  for (int p = 0; p < 4; ++p) {
    unsigned short lo = f2bf(w2[((oc * 32 + ic0 + 2 * p) * 3 + dy) * 3 + dx]);
    unsigned short hi = f2bf(w2[((oc * 32 + ic0 + 2 * p + 1) * 3 + dy) * 3 + dx]);
    u[p] = (unsigned)lo | ((unsigned)hi << 16);
  }
  uint4 v = {u[0], u[1], u[2], u[3]};
  *(uint4*)(Wb + (size_t)id * 8) = v;
}

// ---------------------------------------------------------------------------
// pack_mamba: in_proj / out_proj / x_proj weights -> bf16 MFMA B-fragment order
// ---------------------------------------------------------------------------
__global__ void pack_mamba(const float* __restrict__ ipF, const float* __restrict__ ipR,
                           const float* __restrict__ opF, const float* __restrict__ opR,
                           const float* __restrict__ xpF, const float* __restrict__ xpR,
                           unsigned short* __restrict__ Wip, unsigned short* __restrict__ Wop,
                           unsigned short* __restrict__ Wxp) {
  int id = blockIdx.x * 256 + threadIdx.x;
  if (id < 262144) {                     // in_proj
    int dl = id >> 15, r = id & 32767;
    int ntile = r >> 9, kt = (r >> 6) & 7, lane = r & 63;
    int dir = dl >> 2, layer = dl & 3;
    const float* src = (dir ? ipR : ipF) + (size_t)layer * 1024 * 256
                       + (size_t)(ntile * 16 + (lane & 15)) * 256 + kt * 32 + (lane >> 4) * 8;
    unsigned u[4];
#pragma unroll
    for (int p = 0; p < 4; ++p)
      u[p] = (unsigned)f2bf(src[2 * p]) | ((unsigned)f2bf(src[2 * p + 1]) << 16);
    uint4 v = {u[0], u[1], u[2], u[3]};
    *(uint4*)(Wip + (size_t)id * 8) = v;
  } else if (id < 262144 + 131072) {     // out_proj
    int id2 = id - 262144;
    int dl = id2 >> 14, rr = id2 & 16383;
    int ntile = rr >> 10, kt = (rr >> 6) & 15, lane = rr & 63;
    int dir = dl >> 2, layer = dl & 3;
    const float* src = (dir ? opR : opF) + (size_t)layer * 256 * 512
                       + (size_t)(ntile * 16 + (lane & 15)) * 512 + kt * 32 + (lane >> 4) * 8;
    unsigned u[4];
#pragma unroll
    for (int p = 0; p < 4; ++p)
      u[p] = (unsigned)f2bf(src[2 * p]) | ((unsigned)f2bf(src[2 * p + 1]) << 16);
    uint4 v = {u[0], u[1], u[2], u[3]};
    *(uint4*)(Wop + (size_t)id2 * 8) = v;
  } else if (id < 262144 + 131072 + 24576) {  // x_proj (48 x 512)
    int id3 = id - 262144 - 131072;
    int dl = id3 / 3072, rr = id3 % 3072;
    int ntile = rr >> 10, kt = (rr >> 6) & 15, lane = rr & 63;
    int dir = dl >> 2, layer = dl & 3;
    const float* src = (dir ? xpR : xpF) + (size_t)layer * 48 * 512
                       + (size_t)(ntile * 16 + (lane & 15)) * 512 + kt * 32 + (lane >> 4) * 8;
    unsigned u[4];
#pragma unroll
    for (int p = 0; p < 4; ++p)
      u[p] = (unsigned)f2bf(src[2 * p]) | ((unsigned)f2bf(src[2 * p + 1]) << 16);
    uint4 v = {u[0], u[1], u[2], u[3]};
    *(uint4*)(Wxp + (size_t)id3 * 8) = v;
  }
}

// ---------------------------------------------------------------------------
// conv1_k: conv(3->32)+relu+pool. __launch_bounds__(256,4) -> VGPR cap 128 so
// the 48-float input window stays register-resident (was 44 VGPR -> LDS remat).
// ---------------------------------------------------------------------------
#define C1P 72
__global__ __launch_bounds__(256, 4) void conv1_k(
    const float* __restrict__ video, const float* __restrict__ w1,
    const float* __restrict__ b1, unsigned short* __restrict__ X1)
{
  __shared__ float imgs[3 * 34 * C1P];
  const int img = blockIdx.x, t = threadIdx.x;
  const float* vin = video + (size_t)img * 12288;
  const int px = t & 31, pyl = t >> 5;

#pragma unroll 1
  for (int h = 0; h < 2; ++h) {
    __syncthreads();
    float4 z4 = {0.f, 0.f, 0.f, 0.f};
    for (int i = t; i < (3 * 34 * C1P) / 4; i += 256) ((float4*)imgs)[i] = z4;
    __syncthreads();
    for (int i = t; i < 3 * 33 * 16; i += 256) {
      int ic = i / 528; int rr = (i - ic * 528) >> 4; int c4 = i & 15;
      int r  = rr + (h ? 0 : 1);
      int gr = 32 * h - 1 + r;
      float4 v = *(const float4*)(vin + ic * 4096 + gr * 64 + c4 * 4);
      *(float4*)(imgs + ic * (34 * C1P) + r * C1P + 4 + c4 * 4) = v;
    }
    __syncthreads();
#pragma unroll 1
    for (int s = 0; s < 2; ++s) {
      const int y = pyl + 8 * (2 * h + s);
      const int lr0 = 2 * (pyl + 8 * s);
      float in[3][4][4];
#pragma unroll
      for (int ic = 0; ic < 3; ++ic)
#pragma unroll
        for (int rr = 0; rr < 4; ++rr)
#pragma unroll
          for (int cc = 0; cc < 4; ++cc)
            in[ic][rr][cc] = imgs[ic * (34 * C1P) + (lr0 + rr) * C1P + (2 * px + 3 + cc)];
      unsigned ob[16];
#pragma unroll 1
      for (int ch = 0; ch < 32; ++ch) {
        float wv[27];
#pragma unroll
        for (int j = 0; j < 27; ++j) wv[j] = w1[ch * 27 + j];
        float bb = b1[ch];
        float a0 = bb, a1 = bb, a2 = bb, a3 = bb;
#pragma unroll
        for (int ic = 0; ic < 3; ++ic)
#pragma unroll
          for (int dy = 0; dy < 3; ++dy)
#pragma unroll
            for (int dx = 0; dx < 3; ++dx) {
              float w = wv[ic * 9 + dy * 3 + dx];
              a0 = fmaf(w, in[ic][dy    ][dx    ], a0);
              a1 = fmaf(w, in[ic][dy    ][dx + 1], a1);
              a2 = fmaf(w, in[ic][dy + 1][dx    ], a2);
              a3 = fmaf(w, in[ic][dy + 1][dx + 1], a3);
            }
        a0 = fmaxf(a0, 0.f); a1 = fmaxf(a1, 0.f);
        a2 = fmaxf(a2, 0.f); a3 = fmaxf(a3, 0.f);
        float pooled = fmaxf(fmaxf(a0, a1), fmaxf(a2, a3));
        unsigned short u = f2bf(pooled);
        if ((ch & 1) == 0) ob[ch >> 1] = (unsigned)u;
        else               ob[ch >> 1] |= ((unsigned)u << 16);
      }
      size_t base = ((size_t)img * 1024 + (size_t)y * 32 + px) * 32;
      uint4* dst = (uint4*)(X1 + base);
      uint4 o0 = {ob[0], ob[1], ob[2], ob[3]};
      uint4 o1 = {ob[4], ob[5], ob[6], ob[7]};
      uint4 o2 = {ob[8], ob[9], ob[10], ob[11]};
      uint4 o3 = {ob[12], ob[13], ob[14], ob[15]};
      dst[0] = o0; dst[1] = o1; dst[2] = o2; dst[3] = o3;
    }
  }
}

// ---------------------------------------------------------------------------
// conv2_k: unchanged
// ---------------------------------------------------------------------------
#define X_LDS_BYTES (4 * 1156 * 16)
#define OCT_STRIDE  (1156 * 16)
__global__ __launch_bounds__(256) void conv2_k(
    const unsigned short* __restrict__ X1, const unsigned short* __restrict__ Wb,
    const float* __restrict__ b2, float* __restrict__ feat)
{
  extern __shared__ char sm[];
  float* part = (float*)(sm + X_LDS_BYTES);
  const int img = blockIdx.x, t = threadIdx.x;
  const int lane = t & 63, wv = t >> 6;
  const int kg = lane >> 4, l15 = lane & 15;

  for (int j = t; j < 1156; j += 256) {
    int r = j / 34, cc = j - r * 34;
    if (r == 0 || r == 33 || cc == 0 || cc == 33) {
      uint4 z = {0, 0, 0, 0};
#pragma unroll
      for (int oct = 0; oct < 4; ++oct)
        *(uint4*)(sm + oct * OCT_STRIDE + j * 16) = z;
    }
  }
  const uint4* src = (const uint4*)(X1 + (size_t)img * 32768);
#pragma unroll 4
  for (int i = 0; i < 16; ++i) {
    int c = i * 256 + t;
    uint4 v = src[c];
    int oct = c & 3, P = c >> 2;
    int y = P >> 5, x = P & 31;
    *(uint4*)(sm + oct * OCT_STRIDE + ((y + 1) * 34 + (x + 1)) * 16) = v;
  }
  __syncthreads();

  float bia[4][4];
#pragma unroll
  for (int mt = 0; mt < 4; ++mt)
#pragma unroll
    for (int r = 0; r < 4; ++r) bia[mt][r] = b2[mt * 16 + kg * 4 + r];

  float msum[4][4];
#pragma unroll
  for (int mt = 0; mt < 4; ++mt)
#pragma unroll
    for (int r = 0; r < 4; ++r) msum[mt][r] = 0.f;

#pragma unroll 1
  for (int pass = 0; pass < 2; ++pass) {
    f32x4 acc[4][8];
#pragma unroll
    for (int mt = 0; mt < 4; ++mt)
#pragma unroll
      for (int q = 0; q < 8; ++q) acc[mt][q] = (f32x4){0.f, 0.f, 0.f, 0.f};
    int Pq[8];
#pragma unroll
    for (int q = 0; q < 8; ++q) {
      int p = (wv * 16 + pass * 8 + q) * 16 + l15;
      int y = p >> 5, x = p & 31;
      Pq[q] = y * 34 + x;
    }
#pragma unroll
    for (int sh = 0; sh < 9; ++sh) {
      const int dy = sh / 3, dx = sh % 3;
      const int shoff = (dy * 34 + dx) * 16;
      short8v Af[4];
#pragma unroll
      for (int mt = 0; mt < 4; ++mt)
        Af[mt] = *(const short8v*)(Wb + ((size_t)(sh * 4 + mt) * 64 + lane) * 8);
#pragma unroll
      for (int q = 0; q < 8; ++q) {
        short8v Bf = *(const short8v*)(sm + kg * OCT_STRIDE + Pq[q] * 16 + shoff);
#pragma unroll
        for (int mt = 0; mt < 4; ++mt)
          acc[mt][q] = __builtin_amdgcn_mfma_f32_16x16x32_bf16(Af[mt], Bf, acc[mt][q], 0, 0, 0);
      }
    }
#pragma unroll
    for (int mt = 0; mt < 4; ++mt) {
#pragma unroll
      for (int pr = 0; pr < 4; ++pr) {
        int qa = (pr & 1) + (pr >> 1) * 4;
        int qb = qa + 2;
#pragma unroll
        for (int r = 0; r < 4; ++r) {
          float va = fmaxf(acc[mt][qa][r] + bia[mt][r], 0.f);
          float vb = fmaxf(acc[mt][qb][r] + bia[mt][r], 0.f);
          float v = fmaxf(va, vb);
          v = fmaxf(v, __shfl_xor(v, 1, 64));
          msum[mt][r] += v;
        }
      }
    }
  }
#pragma unroll
  for (int mt = 0; mt < 4; ++mt)
#pragma unroll
    for (int r = 0; r < 4; ++r) {
      float v = msum[mt][r];
      v += __shfl_xor(v, 1, 64);
      v += __shfl_xor(v, 2, 64);
      v += __shfl_xor(v, 4, 64);
      v += __shfl_xor(v, 8, 64);
      if (l15 == 0) part[wv * 64 + mt * 16 + kg * 4 + r] = v * 0.5f;
    }
  __syncthreads();
  if (t < 64)
    feat[(size_t)img * 64 + t] =
        (part[t] + part[64 + t] + part[128 + t] + part[192 + t]) * (1.f / 256.f);
}

// ---------------------------------------------------------------------------
// fcgemm_k: feat(1024,64) @ fcw(196,64)^T + fcb -> writes xf AND reversed xr
// ---------------------------------------------------------------------------
__global__ __launch_bounds__(256) void fcgemm_k(
    const float* __restrict__ A, const float* __restrict__ B,
    const float* __restrict__ bias, float* __restrict__ xf, float* __restrict__ xr)
{
  __shared__ float sA[16][68];
  __shared__ float sB[16][68];
  const int t = threadIdx.x;
  const int m0 = blockIdx.x * 64;
  const int n0 = blockIdx.y * 64;
  const int tx = t & 15, ty = t >> 4;
  const int lk = t & 15, lr = t >> 4;
  float acc[4][4] = {};
  for (int k0 = 0; k0 < 64; k0 += 16) {
#pragma unroll
    for (int rr = 0; rr < 4; ++rr) {
      int m = m0 + lr + rr * 16;
      sA[lk][lr + rr * 16] = A[(size_t)m * 64 + k0 + lk];
      int n = n0 + lr + rr * 16;
      sB[lk][lr + rr * 16] = (n < VF) ? B[(size_t)n * 64 + k0 + lk] : 0.f;
    }
    __syncthreads();
#pragma unroll
    for (int kk = 0; kk < 16; ++kk) {
      float a0 = sA[kk][ty*4+0], a1 = sA[kk][ty*4+1], a2 = sA[kk][ty*4+2], a3 = sA[kk][ty*4+3];
      float b0 = sB[kk][tx*4+0], b1 = sB[kk][tx*4+1], b2 = sB[kk][tx*4+2], b3 = sB[kk][tx*4+3];
      acc[0][0]=fmaf(a0,b0,acc[0][0]); acc[0][1]=fmaf(a0,b1,acc[0][1]); acc[0][2]=fmaf(a0,b2,acc[0][2]); acc[0][3]=fmaf(a0,b3,acc[0][3]);
      acc[1][0]=fmaf(a1,b0,acc[1][0]); acc[1][1]=fmaf(a1,b1,acc[1][1]); acc[1][2]=fmaf(a1,b2,acc[1][2]); acc[1][3]=fmaf(a1,b3,acc[1][3]);
      acc[2][0]=fmaf(a2,b0,acc[2][0]); acc[2][1]=fmaf(a2,b1,acc[2][1]); acc[2][2]=fmaf(a2,b2,acc[2][2]); acc[2][3]=fmaf(a2,b3,acc[2][3]);
      acc[3][0]=fmaf(a3,b0,acc[3][0]); acc[3][1]=fmaf(a3,b1,acc[3][1]); acc[3][2]=fmaf(a3,b2,acc[3][2]); acc[3][3]=fmaf(a3,b3,acc[3][3]);
    }
    __syncthreads();
  }
#pragma unroll
  for (int i = 0; i < 4; ++i) {
    int m = m0 + ty * 4 + i;
    int b = m >> 7, l = m & 127;
    int mr = (b << 7) + (127 - l);
#pragma unroll
    for (int j = 0; j < 4; ++j) {
      int n = n0 + tx * 4 + j;
      if (n >= VF) continue;
      float v = acc[i][j] + bias[n];
      xf[(size_t)m * DD + n] = v;
      xr[(size_t)mr * DD + n] = v;
    }
  }
}

// audio_k: audio -> xf/xr cols [196,256)
__global__ void audio_k(const float* __restrict__ audio,
                        float* __restrict__ xf, float* __restrict__ xr) {
  int i = blockIdx.x * 256 + threadIdx.x;
  if (i >= BATCH * FRAMES * NM) return;
  int j = i % NM; int l = (i / NM) % FRAMES; int b = i / (NM * FRAMES);
  float v = audio[i];
  xf[(size_t)(b * FRAMES + l) * DD + VF + j] = v;
  xr[(size_t)(b * FRAMES + (FRAMES - 1 - l)) * DD + VF + j] = v;
}

// ---------------------------------------------------------------------------
// inproj_mfma: fused rmsnorm + in_proj (bf16 MFMA). grid (16,8,2): 256 blocks.
// ---------------------------------------------------------------------------
__global__ __launch_bounds__(256) void inproj_mfma(
    const float* __restrict__ xF, const float* __restrict__ xR,
    const float* __restrict__ nwF, const float* __restrict__ nwR,
    const unsigned short* __restrict__ Wip, int layer,
    float* __restrict__ xzF, float* __restrict__ xzR)
{
  const int dir = blockIdx.z;
  const float* x = dir ? xR : xF;
  const float* nw = dir ? nwR : nwF;
  float* xz = dir ? xzR : xzF;
  __shared__ unsigned short sa[8 * 4 * 64 * 8];   // 32KB
  const int t = threadIdx.x;
  const int m0 = blockIdx.x * 64;
  {
    const int m = t >> 2, q = t & 3;
    const float* row = x + (size_t)(m0 + m) * DD + q * 64;
    float v[64];
    float ss = 0.f;
#pragma unroll
    for (int i = 0; i < 16; ++i) {
      float4 f = ((const float4*)row)[i];
      v[4*i] = f.x; v[4*i+1] = f.y; v[4*i+2] = f.z; v[4*i+3] = f.w;
      ss += f.x*f.x + f.y*f.y + f.z*f.z + f.w*f.w;
    }
    ss += __shfl_xor(ss, 1, 4);
    ss += __shfl_xor(ss, 2, 4);
    float scale = rsqrtf(ss * (1.f / DD) + 1e-5f);
    const float* nwq = nw + q * 64;
#pragma unroll
    for (int o = 0; o < 8; ++o) {
      unsigned ub[4];
#pragma unroll
      for (int p = 0; p < 4; ++p) {
        unsigned short lo = f2bf(v[o*8 + 2*p]     * scale * nwq[o*8 + 2*p]);
        unsigned short hi = f2bf(v[o*8 + 2*p + 1] * scale * nwq[o*8 + 2*p + 1]);
        ub[p] = (unsigned)lo | ((unsigned)hi << 16);
      }
      int k = q * 64 + o * 8;
      int kt = k >> 5, oct = (k >> 3) & 3;
      uint4 w4 = {ub[0], ub[1], ub[2], ub[3]};
      *(uint4*)(sa + ((size_t)(kt * 4 + oct) * 64 + m) * 8) = w4;
    }
  }
  __syncthreads();
  const int lane = t & 63, w = t >> 6;
#pragma unroll 1
  for (int ns = 0; ns < 2; ++ns) {
    const int ntile = blockIdx.y * 8 + w * 2 + ns;
    const unsigned short* wb = Wip + (((size_t)(dir * 4 + layer) * 512 + ntile * 8) * 64 + lane) * 8;
    f32x4 acc[4];
#pragma unroll
    for (int mt = 0; mt < 4; ++mt) acc[mt] = (f32x4){0.f, 0.f, 0.f, 0.f};
#pragma unroll
    for (int kt = 0; kt < 8; ++kt) {
      short8v bf = *(const short8v*)(wb + (size_t)kt * 64 * 8);
#pragma unroll
      for (int mt = 0; mt < 4; ++mt) {
        short8v af = *(const short8v*)(sa + ((size_t)(kt * 4 + (lane >> 4)) * 64 + mt * 16 + (lane & 15)) * 8);
        acc[mt] = __builtin_amdgcn_mfma_f32_16x16x32_bf16(af, bf, acc[mt], 0, 0, 0);
      }
    }
#pragma unroll
    for (int mt = 0; mt < 4; ++mt)
#pragma unroll
      for (int r = 0; r < 4; ++r)
        xz[(size_t)(m0 + mt * 16 + (lane >> 4) * 4 + r) * 1024 + ntile * 16 + (lane & 15)] = acc[mt][r];
  }
}

// ---------------------------------------------------------------------------
// convsilu2_k: mass-parallel causal-conv4 + silu
// ---------------------------------------------------------------------------
__global__ __launch_bounds__(256) void convsilu2_k(
    const float* __restrict__ xzF, const float* __restrict__ xzR,
    const float* __restrict__ cwF, const float* __restrict__ cwR,
    const float* __restrict__ cbF, const float* __restrict__ cbR,
    float* __restrict__ xcF, float* __restrict__ xcR,
    unsigned short* __restrict__ xcbF, unsigned short* __restrict__ xcbR)
{
  const int dir = blockIdx.z;
  const float* xz = dir ? xzR : xzF;
  const float* cw = dir ? cwR : cwF;
  const float* cb = dir ? cbR : cbF;
  float* xc = dir ? xcR : xcF;
  unsigned short* xcb = dir ? xcbR : xcbF;

  int i = blockIdx.x * 256 + threadIdx.x;
  int tok = i >> 6;
  int e0 = (i & 63) << 3;
  int l = tok & 127;
  const float* col = xz + (size_t)tok * 1024 + e0;

  float v3[8] = {}, v2[8] = {}, v1[8] = {}, v0[8];
  if (l >= 3) { *(float4*)v3 = *(const float4*)(col - 3072); *(float4*)(v3+4) = *(const float4*)(col - 3068); }
  if (l >= 2) { *(float4*)v2 = *(const float4*)(col - 2048); *(float4*)(v2+4) = *(const float4*)(col - 2044); }
  if (l >= 1) { *(float4*)v1 = *(const float4*)(col - 1024); *(float4*)(v1+4) = *(const float4*)(col - 1020); }
  *(float4*)v0 = *(const float4*)col; *(float4*)(v0+4) = *(const float4*)(col + 4);

  float cbv[8];
  *(float4*)cbv = *(const float4*)(cb + e0); *(float4*)(cbv+4) = *(const float4*)(cb + e0 + 4);

  float res[8];
#pragma unroll
  for (int j = 0; j < 8; ++j) {
    float4 cv = ((const float4*)cw)[e0 + j];
    float a = cbv[j];
    a = fmaf(cv.x, v3[j], a);
    a = fmaf(cv.y, v2[j], a);
    a = fmaf(cv.z, v1[j], a);
    a = fmaf(cv.w, v0[j], a);
    res[j] = a / (1.f + __expf(-a));
  }
  float4 r0 = {res[0], res[1], res[2], res[3]};
  float4 r1 = {res[4], res[5], res[6], res[7]};
  float* xcp = xc + (size_t)tok * EDIM + e0;
  *(float4*)xcp = r0; *(float4*)(xcp + 4) = r1;

  unsigned ub[4];
#pragma unroll
  for (int p = 0; p < 4; ++p)
    ub[p] = (unsigned)f2bf(res[2*p]) | ((unsigned)f2bf(res[2*p+1]) << 16);
  int kt = e0 >> 5, oct = (e0 >> 3) & 3;
  uint4 w4 = {ub[0], ub[1], ub[2], ub[3]};
  *(uint4*)(xcb + ((size_t)(kt * 4 + oct) * 1024 + tok) * 8) = w4;
}

// ---------------------------------------------------------------------------
// xproj_mfma: pure-register MFMA GEMM. 64-thr blocks, grid (64,1,2).
// ---------------------------------------------------------------------------
__global__ __launch_bounds__(64) void xproj_mfma(
    const unsigned short* __restrict__ xcbF, const unsigned short* __restrict__ xcbR,
    const unsigned short* __restrict__ Wxp, int layer,
    float* __restrict__ dbF, float* __restrict__ dbR)
{
  const int dir = blockIdx.z;
  const unsigned short* xcb = dir ? xcbR : xcbF;
  float* db = dir ? dbR : dbF;
  const int lane = threadIdx.x & 63;
  const int tok0 = blockIdx.x * 16;
  const unsigned short* wbase = Wxp + ((size_t)(dir * 4 + layer) * 3 * 16 * 64) * 8;
  f32x4 acc[3];
#pragma unroll
  for (int nt = 0; nt < 3; ++nt) acc[nt] = (f32x4){0.f, 0.f, 0.f, 0.f};
#pragma unroll
  for (int kt = 0; kt < 16; ++kt) {
    short8v af = *(const short8v*)(xcb + ((size_t)(kt * 4 + (lane >> 4)) * 1024 + tok0 + (lane & 15)) * 8);
#pragma unroll
    for (int nt = 0; nt < 3; ++nt) {
      short8v bf = *(const short8v*)(wbase + ((size_t)(nt * 16 + kt) * 64 + lane) * 8);
      acc[nt] = __builtin_amdgcn_mfma_f32_16x16x32_bf16(af, bf, acc[nt], 0, 0, 0);
    }
  }
#pragma unroll
  for (int nt = 0; nt < 3; ++nt)
#pragma unroll
    for (int r = 0; r < 4; ++r)
      db[(size_t)(tok0 + (lane >> 4) * 4 + r) * 48 + nt * 16 + (lane & 15)] = acc[nt][r];
}

// ---------------------------------------------------------------------------
// dtproj_k: dl[tok][e] = softplus(db[tok][0:16] @ dtw[e][:] + dtb[e])
// mass-parallel, removes softplus+reduce from the scan's serial loop.
// ---------------------------------------------------------------------------
__global__ __launch_bounds__(256) void dtproj_k(
    const float* __restrict__ dbF, const float* __restrict__ dbR,
    const float* __restrict__ dwF, const float* __restrict__ dwR,
    const float* __restrict__ dtbF, const float* __restrict__ dtbR,
    float* __restrict__ dlF, float* __restrict__ dlR)
{
  const int dir = blockIdx.z;
  const float* db = dir ? dbR : dbF;
  const float* dw = dir ? dwR : dwF;
  const float* dtb = dir ? dtbR : dtbF;
  float* dl = dir ? dlR : dlF;
  int i = blockIdx.x * 256 + threadIdx.x;   // 0..524287
  int tok = i >> 9, e = i & 511;
  const float* d = db + (size_t)tok * 48;
  const float* w = dw + (size_t)e * 16;
  float acc = dtb[e];
#pragma unroll
  for (int q = 0; q < 4; ++q) {
    float4 dv = *(const float4*)(d + 4 * q);
    float4 wv = *(const float4*)(w + 4 * q);
    acc = fmaf(dv.x, wv.x, acc);
    acc = fmaf(dv.y, wv.y, acc);
    acc = fmaf(dv.z, wv.z, acc);
    acc = fmaf(dv.w, wv.w, acc);
  }
  dl[i] = (acc > 20.f) ? acc : __logf(1.f + __expf(acc));
}

// ---------------------------------------------------------------------------
// scan3_k: selective scan + gating; delta precomputed. 16 lanes/(b,e).
// ---------------------------------------------------------------------------
__global__ __launch_bounds__(256) void scan3_k(
    const float* __restrict__ xzF, const float* __restrict__ xzR,
    const float* __restrict__ xcF, const float* __restrict__ xcR,
    const float* __restrict__ dbF, const float* __restrict__ dbR,
    const float* __restrict__ dlF, const float* __restrict__ dlR,
    const float* __restrict__ AlF, const float* __restrict__ AlR,
    const float* __restrict__ DpF, const float* __restrict__ DpR,
    unsigned short* __restrict__ yoF, unsigned short* __restrict__ yoR)
{
  const int dir = blockIdx.z;
  const float* xz = dir ? xzR : xzF;
  const float* xc = dir ? xcR : xcF;
  const float* db = dir ? dbR : dbF;
  const float* dl = dir ? dlR : dlF;
  const float* Al = dir ? AlR : AlF;
  const float* Dp = dir ? DpR : DpF;
  unsigned short* yo = dir ? yoR : yoF;

  __shared__ float sdb[FRAMES * 48];   // 24KB
  __shared__ float sxc[FRAMES * 16];
  __shared__ float szz[FRAMES * 16];
  __shared__ float sdl[FRAMES * 16];
  const int b = blockIdx.x >> 5;
  const int e0 = (blockIdx.x & 31) << 4;
  const int t = threadIdx.x, g = t >> 4, n = t & 15;
  const int e = e0 + g;

  const float* dbp = db + (size_t)b * FRAMES * 48;
  for (int i = t; i < FRAMES * 48 / 4; i += 256)
    ((float4*)sdb)[i] = ((const float4*)dbp)[i];
  for (int i = t; i < FRAMES * 16; i += 256) {
    int l = i >> 4, c = i & 15;
    sxc[i] = xc[(size_t)(b * FRAMES + l) * EDIM + e0 + c];
    szz[i] = xz[(size_t)(b * FRAMES + l) * 1024 + 512 + e0 + c];
    sdl[i] = dl[(size_t)(b * FRAMES + l) * EDIM + e0 + c];
  }
  float An = -expf(Al[e * NSTATE + n]);
  float Dv = Dp[e];
  float h = 0.f;
  unsigned short* yp = yo + ((size_t)((e >> 5) * 4 + ((e >> 3) & 3)) * 1024 + b * FRAMES) * 8 + (e & 7);
  __syncthreads();

#pragma unroll 1
  for (int l = 0; l < FRAMES; ++l) {
    float dlt = sdl[l * 16 + g];
    float xcv = sxc[l * 16 + g];
    float Bn = sdb[l * 48 + 16 + n];
    float Cn = sdb[l * 48 + 32 + n];
    float dA = __expf(dlt * An);
    h = fmaf(dA, h, dlt * xcv * Bn);
    float part = h * Cn;
    part += __shfl_xor(part, 1, 16);
    part += __shfl_xor(part, 2, 16);
    part += __shfl_xor(part, 4, 16);
    part += __shfl_xor(part, 8, 16);
    if (n == 0) {
      float zz = szz[l * 16 + g];
      float a2 = fmaf(Dv, xcv, part);
      float sv = zz / (1.f + __expf(-zz));
      yp[(size_t)l * 8] = f2bf(a2 * sv);
    }
  }
}

// ---------------------------------------------------------------------------
// outproj_mfma: zero-LDS bf16 MFMA GEMM + residual add.
// ---------------------------------------------------------------------------
__global__ __launch_bounds__(256) void outproj_mfma(
    const unsigned short* __restrict__ yoF, const unsigned short* __restrict__ yoR,
    const unsigned short* __restrict__ Wop, int layer,
    float* __restrict__ xF, float* __restrict__ xR)
{
  const int dir = blockIdx.z;
  const unsigned short* yo = dir ? yoR : yoF;
  float* xx = dir ? xR : xF;
  const int t = threadIdx.x, lane = t & 63, w = t >> 6;
  const int m0 = blockIdx.x * 32, n0 = blockIdx.y * 64;
  const int ntile = blockIdx.y * 4 + w;
  const unsigned short* wb = Wop + (((size_t)(dir * 4 + layer) * 256 + ntile * 16) * 64 + lane) * 8;
  f32x4 acc[2];
  acc[0] = (f32x4){0.f, 0.f, 0.f, 0.f};
  acc[1] = (f32x4){0.f, 0.f, 0.f, 0.f};
#pragma unroll
  for (int kt = 0; kt < 16; ++kt) {
    short8v bf = *(const short8v*)(wb + (size_t)kt * 64 * 8);
#pragma unroll
    for (int mt = 0; mt < 2; ++mt) {
      short8v af = *(const short8v*)(yo + ((size_t)(kt * 4 + (lane >> 4)) * 1024 + m0 + mt * 16 + (lane & 15)) * 8);
      acc[mt] = __builtin_amdgcn_mfma_f32_16x16x32_bf16(af, bf, acc[mt], 0, 0, 0);
    }
  }
#pragma unroll
  for (int mt = 0; mt < 2; ++mt)
#pragma unroll
    for (int r = 0; r < 4; ++r) {
      size_t ci = (size_t)(m0 + mt * 16 + (lane >> 4) * 4 + r) * DD + n0 + w * 16 + (lane & 15);
      xx[ci] += acc[mt][r];
    }
}

__global__ __launch_bounds__(256) void head_k(
    const float* __restrict__ xf, const float* __restrict__ xr,
    const float* __restrict__ fcw, const float* __restrict__ fcb,
    const float* __restrict__ fc2w, const float* __restrict__ fc2b,
    float* __restrict__ out)
{
  int b = blockIdx.x;
  __shared__ float xl[2 * DD];
  __shared__ float h[DD];
  __shared__ float hp[4];
  int t = threadIdx.x;
  xl[t]      = xf[(size_t)(b * FRAMES + FRAMES - 1) * DD + t];
  xl[DD + t] = xr[(size_t)(b * FRAMES + 0) * DD + t];
  __syncthreads();
  float acc = fcb[t];
  for (int k = 0; k < 2 * DD; ++k) acc = fmaf(xl[k], fcw[(size_t)t * 2 * DD + k], acc);
  h[t] = acc;
  __syncthreads();
  // stage 2: c = t>>7 (waves 0-1 -> c=0, waves 2-3 -> c=1), 128 threads per c
  {
    int c = t >> 7, k = t & 127;
    float p = h[k] * fc2w[c * DD + k] + h[k + 128] * fc2w[c * DD + k + 128];
#pragma unroll
    for (int off = 32; off; off >>= 1) p += __shfl_xor(p, off, 64);
    if ((t & 63) == 0) hp[t >> 6] = p;
  }
  __syncthreads();
  if (t < 2) out[b * 2 + t] = hp[2 * t] + hp[2 * t + 1] + fc2b[t];
}

// ---------------------------------------------------------------------------
extern "C" void kernel_launch(void* const* d_in, const int* in_sizes, int n_in,
                              void* d_out, int out_size, void* d_ws, size_t ws_size,
                              hipStream_t stream) {
  const float* video = (const float*)d_in[0];
  const float* audio = (const float*)d_in[1];
  const float* c1w = (const float*)d_in[2];
  const float* c1b = (const float*)d_in[3];
  const float* c2w = (const float*)d_in[4];
  const float* c2b = (const float*)d_in[5];
  const float* fcw = (const float*)d_in[6];
  const float* fcb = (const float*)d_in[7];
  const float* Wf[10]; const float* Wb_[10];
  for (int i = 0; i < 10; ++i) { Wf[i] = (const float*)d_in[8+i]; Wb_[i] = (const float*)d_in[18+i]; }
  const float* fc_w  = (const float*)d_in[28];
  const float* fc_b  = (const float*)d_in[29];
  const float* fc2_w = (const float*)d_in[30];
  const float* fc2_b = (const float*)d_in[31];
  float* out = (float*)d_out;

  // workspace (float slots)
  float* ws   = (float*)d_ws;
  float* feat = ws;                       // 65536
  float* xf   = feat + 65536;             // 262144
  float* xr   = xf   + 262144;            // 262144
  float* xzF  = xr   + 262144;            // 1048576
  float* xzR  = xzF  + 1048576;           // 1048576
  float* xcF  = xzR  + 1048576;           // 524288
  float* xcR  = xcF  + 524288;            // 524288
  float* dbF  = xcR  + 524288;            // 49152
  float* dbR  = dbF  + 49152;             // 49152
  float* dlF  = dbR  + 49152;             // 524288
  float* dlR  = dlF  + 524288;            // 524288
  unsigned short* yoF = (unsigned short*)(dlR + 524288);    // 524288 sh
  unsigned short* yoR = yoF + 524288;
  unsigned short* X1  = yoR + 524288;                        // 33554432 sh
  unsigned short* Wbp = X1 + 33554432;                       // 18432 sh
  unsigned short* Wip = Wbp + 18432;                         // 2097152 sh
  unsigned short* Wop = Wip + 2097152;                       // 1048576 sh
  unsigned short* Wxp = Wop + 1048576;                       // 196608 sh
  unsigned short* xcbF = Wxp + 196608;                       // 524288 sh
  unsigned short* xcbR = xcbF + 524288;                      // 524288 sh

  // 1. packs + CNN
  pack_w2<<<dim3(9), 256, 0, stream>>>(c2w, Wbp);
  pack_mamba<<<dim3(1632), 256, 0, stream>>>(Wf[1], Wb_[1], Wf[9], Wb_[9], Wf[4], Wb_[4],
                                             Wip, Wop, Wxp);
  conv1_k<<<dim3(TOK), 256, 0, stream>>>(video, c1w, c1b, X1);
  conv2_k<<<dim3(TOK), 256, (size_t)(X_LDS_BYTES + 1024), stream>>>(X1, Wbp, c2b, feat);

  // 2. cnn fc (writes xf+xr directly) + audio fill (independent)
  fcgemm_k<<<dim3(16, 4), 256, 0, stream>>>(feat, fcw, fcb, xf, xr);
  audio_k<<<dim3((BATCH*FRAMES*NM + 255)/256), 256, 0, stream>>>(audio, xf, xr);

  // 3. bi-Mamba (6 kernels per layer)
  for (int l = 0; l < NLAYER; ++l) {
    const float* nwF  = Wf[0] + l*DD;              const float* nwR  = Wb_[0] + l*DD;
    const float* cwF_ = Wf[2] + l*EDIM*4;          const float* cwR_ = Wb_[2] + l*EDIM*4;
    const float* cbF_ = Wf[3] + l*EDIM;            const float* cbR_ = Wb_[3] + l*EDIM;
    const float* dwF  = Wf[5] + l*EDIM*DTRANK;     const float* dwR  = Wb_[5] + l*EDIM*DTRANK;
    const float* dtbF = Wf[6] + l*EDIM;            const float* dtbR = Wb_[6] + l*EDIM;
    const float* AlF  = Wf[7] + l*EDIM*NSTATE;     const float* AlR  = Wb_[7] + l*EDIM*NSTATE;
    const float* DpF  = Wf[8] + l*EDIM;            const float* DpR  = Wb_[8] + l*EDIM;

    inproj_mfma<<<dim3(16, 8, 2), 256, 0, stream>>>(xf, xr, nwF, nwR, Wip, l, xzF, xzR);
    convsilu2_k<<<dim3(256, 1, 2), 256, 0, stream>>>(xzF, xzR, cwF_, cwR_, cbF_, cbR_,
                                                     xcF, xcR, xcbF, xcbR);
    xproj_mfma<<<dim3(64, 1, 2), 64, 0, stream>>>(xcbF, xcbR, Wxp, l, dbF, dbR);
    dtproj_k<<<dim3(2048, 1, 2), 256, 0, stream>>>(dbF, dbR, dwF, dwR, dtbF, dtbR, dlF, dlR);
    scan3_k<<<dim3(256, 1, 2), 256, 0, stream>>>(xzF, xzR, xcF, xcR, dbF, dbR, dlF, dlR,
                                                 AlF, AlR, DpF, DpR, yoF, yoR);
    outproj_mfma<<<dim3(32, 4, 2), 256, 0, stream>>>(yoF, yoR, Wop, l, xf, xr);
  }

  // 4. head
  head_k<<<dim3(BATCH), 256, 0, stream>>>(xf, xr, fc_w, fc_b, fc2_w, fc2_b, out);
}

// Round 7
// 521.413 us; speedup vs baseline: 2.4542x; 1.0075x over previous
//
#include <hip/hip_runtime.h>
#include <hip/hip_bf16.h>
#include <cstdint>
#include <cstddef>

#define BATCH 8
#define FRAMES 128
#define TOK (BATCH*FRAMES)   // 1024
#define NM 60
#define VF 196
#define DD 256
#define EDIM 512
#define NSTATE 16
#define DTRANK 16
#define NLAYER 4

typedef __attribute__((ext_vector_type(8))) short short8v;
typedef __attribute__((ext_vector_type(4))) float f32x4;

__device__ __forceinline__ unsigned short f2bf(float f) {
  unsigned x = __float_as_uint(f);
  unsigned r = (x + 0x7FFFu + ((x >> 16) & 1u)) >> 16;
  return (unsigned short)r;
}

// ---------------------------------------------------------------------------
// pack_w2: W2 (64,32,3,3) f32 -> Wb[shift(9)][mtile(4)][lane(64)][8] bf16
// ---------------------------------------------------------------------------
__global__ void pack_w2(const float* __restrict__ w2, unsigned short* __restrict__ Wb) {
  int id = blockIdx.x * 256 + threadIdx.x;
  if (id >= 9 * 4 * 64) return;
  int lane = id & 63;
  int mt = (id >> 6) & 3;
  int sh = id >> 8;
  int dy = sh / 3, dx = sh % 3;
  int oc = mt * 16 + (lane & 15);
  int ic0 = (lane >> 4) * 8;
  unsigned u[4];
#pragma unroll
  for (int p = 0; p < 4; ++p) {
    unsigned short lo = f2bf(w2[((oc * 32 + ic0 + 2 * p) * 3 + dy) * 3 + dx]);
    unsigned short hi = f2bf(w2[((oc * 32 + ic0 + 2 * p + 1) * 3 + dy) * 3 + dx]);
    u[p] = (unsigned)lo | ((unsigned)hi << 16);
  }
  uint4 v = {u[0], u[1], u[2], u[3]};
  *(uint4*)(Wb + (size_t)id * 8) = v;
}

// ---------------------------------------------------------------------------
// pack_mamba: in_proj / out_proj / x_proj weights -> bf16 MFMA B-fragment order
// ---------------------------------------------------------------------------
__global__ void pack_mamba(const float* __restrict__ ipF, const float* __restrict__ ipR,
                           const float* __restrict__ opF, const float* __restrict__ opR,
                           const float* __restrict__ xpF, const float* __restrict__ xpR,
                           unsigned short* __restrict__ Wip, unsigned short* __restrict__ Wop,
                           unsigned short* __restrict__ Wxp) {
  int id = blockIdx.x * 256 + threadIdx.x;
  if (id < 262144) {                     // in_proj
    int dl = id >> 15, r = id & 32767;
    int ntile = r >> 9, kt = (r >> 6) & 7, lane = r & 63;
    int dir = dl >> 2, layer = dl & 3;
    const float* src = (dir ? ipR : ipF) + (size_t)layer * 1024 * 256
                       + (size_t)(ntile * 16 + (lane & 15)) * 256 + kt * 32 + (lane >> 4) * 8;
    unsigned u[4];
#pragma unroll
    for (int p = 0; p < 4; ++p)
      u[p] = (unsigned)f2bf(src[2 * p]) | ((unsigned)f2bf(src[2 * p + 1]) << 16);
    uint4 v = {u[0], u[1], u[2], u[3]};
    *(uint4*)(Wip + (size_t)id * 8) = v;
  } else if (id < 262144 + 131072) {     // out_proj
    int id2 = id - 262144;
    int dl = id2 >> 14, rr = id2 & 16383;
    int ntile = rr >> 10, kt = (rr >> 6) & 15, lane = rr & 63;
    int dir = dl >> 2, layer = dl & 3;
    const float* src = (dir ? opR : opF) + (size_t)layer * 256 * 512
                       + (size_t)(ntile * 16 + (lane & 15)) * 512 + kt * 32 + (lane >> 4) * 8;
    unsigned u[4];
#pragma unroll
    for (int p = 0; p < 4; ++p)
      u[p] = (unsigned)f2bf(src[2 * p]) | ((unsigned)f2bf(src[2 * p + 1]) << 16);
    uint4 v = {u[0], u[1], u[2], u[3]};
    *(uint4*)(Wop + (size_t)id2 * 8) = v;
  } else if (id < 262144 + 131072 + 24576) {  // x_proj (48 x 512)
    int id3 = id - 262144 - 131072;
    int dl = id3 / 3072, rr = id3 % 3072;
    int ntile = rr >> 10, kt = (rr >> 6) & 15, lane = rr & 63;
    int dir = dl >> 2, layer = dl & 3;
    const float* src = (dir ? xpR : xpF) + (size_t)layer * 48 * 512
                       + (size_t)(ntile * 16 + (lane & 15)) * 512 + kt * 32 + (lane >> 4) * 8;
    unsigned u[4];
#pragma unroll
    for (int p = 0; p < 4; ++p)
      u[p] = (unsigned)f2bf(src[2 * p]) | ((unsigned)f2bf(src[2 * p + 1]) << 16);
    uint4 v = {u[0], u[1], u[2], u[3]};
    *(uint4*)(Wxp + (size_t)id3 * 8) = v;
  }
}

// ---------------------------------------------------------------------------
// conv1_k: conv(3->32)+relu+pool. Window pinned into VGPRs via asm so the
// compiler cannot sink the LDS reads into the 32-channel loop (r6: VGPR=44
// -> per-use remat, 2.3x VALU issue overhead).
// ---------------------------------------------------------------------------
#define C1P 72
__global__ __launch_bounds__(256, 4) void conv1_k(
    const float* __restrict__ video, const float* __restrict__ w1,
    const float* __restrict__ b1, unsigned short* __restrict__ X1)
{
  __shared__ float imgs[3 * 34 * C1P];
  const int img = blockIdx.x, t = threadIdx.x;
  const float* vin = video + (size_t)img * 12288;
  const int px = t & 31, pyl = t >> 5;

#pragma unroll 1
  for (int h = 0; h < 2; ++h) {
    __syncthreads();
    float4 z4 = {0.f, 0.f, 0.f, 0.f};
    for (int i = t; i < (3 * 34 * C1P) / 4; i += 256) ((float4*)imgs)[i] = z4;
    __syncthreads();
    for (int i = t; i < 3 * 33 * 16; i += 256) {
      int ic = i / 528; int rr = (i - ic * 528) >> 4; int c4 = i & 15;
      int r  = rr + (h ? 0 : 1);
      int gr = 32 * h - 1 + r;
      float4 v = *(const float4*)(vin + ic * 4096 + gr * 64 + c4 * 4);
      *(float4*)(imgs + ic * (34 * C1P) + r * C1P + 4 + c4 * 4) = v;
    }
    __syncthreads();
#pragma unroll 1
    for (int s = 0; s < 2; ++s) {
      const int y = pyl + 8 * (2 * h + s);
      const int lr0 = 2 * (pyl + 8 * s);
      float in[3][4][4];
#pragma unroll
      for (int ic = 0; ic < 3; ++ic)
#pragma unroll
        for (int rr = 0; rr < 4; ++rr)
#pragma unroll
          for (int cc = 0; cc < 4; ++cc)
            in[ic][rr][cc] = imgs[ic * (34 * C1P) + (lr0 + rr) * C1P + (2 * px + 3 + cc)];
      // pin the 48-float window into VGPRs: compiler cannot re-read from LDS
#pragma unroll
      for (int ic = 0; ic < 3; ++ic)
#pragma unroll
        for (int rr = 0; rr < 4; ++rr)
#pragma unroll
          for (int cc = 0; cc < 4; ++cc)
            asm volatile("" : "+v"(in[ic][rr][cc]));
      unsigned ob[16];
#pragma unroll 1
      for (int ch = 0; ch < 32; ++ch) {
        float wv[27];
#pragma unroll
        for (int j = 0; j < 27; ++j) wv[j] = w1[ch * 27 + j];
        float bb = b1[ch];
        float a0 = bb, a1 = bb, a2 = bb, a3 = bb;
#pragma unroll
        for (int ic = 0; ic < 3; ++ic)
#pragma unroll
          for (int dy = 0; dy < 3; ++dy)
#pragma unroll
            for (int dx = 0; dx < 3; ++dx) {
              float w = wv[ic * 9 + dy * 3 + dx];
              a0 = fmaf(w, in[ic][dy    ][dx    ], a0);
              a1 = fmaf(w, in[ic][dy    ][dx + 1], a1);
              a2 = fmaf(w, in[ic][dy + 1][dx    ], a2);
              a3 = fmaf(w, in[ic][dy + 1][dx + 1], a3);
            }
        a0 = fmaxf(a0, 0.f); a1 = fmaxf(a1, 0.f);
        a2 = fmaxf(a2, 0.f); a3 = fmaxf(a3, 0.f);
        float pooled = fmaxf(fmaxf(a0, a1), fmaxf(a2, a3));
        unsigned short u = f2bf(pooled);
        if ((ch & 1) == 0) ob[ch >> 1] = (unsigned)u;
        else               ob[ch >> 1] |= ((unsigned)u << 16);
      }
      size_t base = ((size_t)img * 1024 + (size_t)y * 32 + px) * 32;
      uint4* dst = (uint4*)(X1 + base);
      uint4 o0 = {ob[0], ob[1], ob[2], ob[3]};
      uint4 o1 = {ob[4], ob[5], ob[6], ob[7]};
      uint4 o2 = {ob[8], ob[9], ob[10], ob[11]};
      uint4 o3 = {ob[12], ob[13], ob[14], ob[15]};
      dst[0] = o0; dst[1] = o1; dst[2] = o2; dst[3] = o3;
    }
  }
}

// ---------------------------------------------------------------------------
// conv2_k: unchanged
// ---------------------------------------------------------------------------
#define X_LDS_BYTES (4 * 1156 * 16)
#define OCT_STRIDE  (1156 * 16)
__global__ __launch_bounds__(256) void conv2_k(
    const unsigned short* __restrict__ X1, const unsigned short* __restrict__ Wb,
    const float* __restrict__ b2, float* __restrict__ feat)
{
  extern __shared__ char sm[];
  float* part = (float*)(sm + X_LDS_BYTES);
  const int img = blockIdx.x, t = threadIdx.x;
  const int lane = t & 63, wv = t >> 6;
  const int kg = lane >> 4, l15 = lane & 15;

  for (int j = t; j < 1156; j += 256) {
    int r = j / 34, cc = j - r * 34;
    if (r == 0 || r == 33 || cc == 0 || cc == 33) {
      uint4 z = {0, 0, 0, 0};
#pragma unroll
      for (int oct = 0; oct < 4; ++oct)
        *(uint4*)(sm + oct * OCT_STRIDE + j * 16) = z;
    }
  }
  const uint4* src = (const uint4*)(X1 + (size_t)img * 32768);
#pragma unroll 4
  for (int i = 0; i < 16; ++i) {
    int c = i * 256 + t;
    uint4 v = src[c];
    int oct = c & 3, P = c >> 2;
    int y = P >> 5, x = P & 31;
    *(uint4*)(sm + oct * OCT_STRIDE + ((y + 1) * 34 + (x + 1)) * 16) = v;
  }
  __syncthreads();

  float bia[4][4];
#pragma unroll
  for (int mt = 0; mt < 4; ++mt)
#pragma unroll
    for (int r = 0; r < 4; ++r) bia[mt][r] = b2[mt * 16 + kg * 4 + r];

  float msum[4][4];
#pragma unroll
  for (int mt = 0; mt < 4; ++mt)
#pragma unroll
    for (int r = 0; r < 4; ++r) msum[mt][r] = 0.f;

#pragma unroll 1
  for (int pass = 0; pass < 2; ++pass) {
    f32x4 acc[4][8];
#pragma unroll
    for (int mt = 0; mt < 4; ++mt)
#pragma unroll
      for (int q = 0; q < 8; ++q) acc[mt][q] = (f32x4){0.f, 0.f, 0.f, 0.f};
    int Pq[8];
#pragma unroll
    for (int q = 0; q < 8; ++q) {
      int p = (wv * 16 + pass * 8 + q) * 16 + l15;
      int y = p >> 5, x = p & 31;
      Pq[q] = y * 34 + x;
    }
#pragma unroll
    for (int sh = 0; sh < 9; ++sh) {
      const int dy = sh / 3, dx = sh % 3;
      const int shoff = (dy * 34 + dx) * 16;
      short8v Af[4];
#pragma unroll
      for (int mt = 0; mt < 4; ++mt)
        Af[mt] = *(const short8v*)(Wb + ((size_t)(sh * 4 + mt) * 64 + lane) * 8);
#pragma unroll
      for (int q = 0; q < 8; ++q) {
        short8v Bf = *(const short8v*)(sm + kg * OCT_STRIDE + Pq[q] * 16 + shoff);
#pragma unroll
        for (int mt = 0; mt < 4; ++mt)
          acc[mt][q] = __builtin_amdgcn_mfma_f32_16x16x32_bf16(Af[mt], Bf, acc[mt][q], 0, 0, 0);
      }
    }
#pragma unroll
    for (int mt = 0; mt < 4; ++mt) {
#pragma unroll
      for (int pr = 0; pr < 4; ++pr) {
        int qa = (pr & 1) + (pr >> 1) * 4;
        int qb = qa + 2;
#pragma unroll
        for (int r = 0; r < 4; ++r) {
          float va = fmaxf(acc[mt][qa][r] + bia[mt][r], 0.f);
          float vb = fmaxf(acc[mt][qb][r] + bia[mt][r], 0.f);
          float v = fmaxf(va, vb);
          v = fmaxf(v, __shfl_xor(v, 1, 64));
          msum[mt][r] += v;
        }
      }
    }
  }
#pragma unroll
  for (int mt = 0; mt < 4; ++mt)
#pragma unroll
    for (int r = 0; r < 4; ++r) {
      float v = msum[mt][r];
      v += __shfl_xor(v, 1, 64);
      v += __shfl_xor(v, 2, 64);
      v += __shfl_xor(v, 4, 64);
      v += __shfl_xor(v, 8, 64);
      if (l15 == 0) part[wv * 64 + mt * 16 + kg * 4 + r] = v * 0.5f;
    }
  __syncthreads();
  if (t < 64)
    feat[(size_t)img * 64 + t] =
        (part[t] + part[64 + t] + part[128 + t] + part[192 + t]) * (1.f / 256.f);
}

// ---------------------------------------------------------------------------
// fcgemm_k: feat(1024,64) @ fcw(196,64)^T + fcb -> writes xf AND reversed xr
// ---------------------------------------------------------------------------
__global__ __launch_bounds__(256) void fcgemm_k(
    const float* __restrict__ A, const float* __restrict__ B,
    const float* __restrict__ bias, float* __restrict__ xf, float* __restrict__ xr)
{
  __shared__ float sA[16][68];
  __shared__ float sB[16][68];
  const int t = threadIdx.x;
  const int m0 = blockIdx.x * 64;
  const int n0 = blockIdx.y * 64;
  const int tx = t & 15, ty = t >> 4;
  const int lk = t & 15, lr = t >> 4;
  float acc[4][4] = {};
  for (int k0 = 0; k0 < 64; k0 += 16) {
#pragma unroll
    for (int rr = 0; rr < 4; ++rr) {
      int m = m0 + lr + rr * 16;
      sA[lk][lr + rr * 16] = A[(size_t)m * 64 + k0 + lk];
      int n = n0 + lr + rr * 16;
      sB[lk][lr + rr * 16] = (n < VF) ? B[(size_t)n * 64 + k0 + lk] : 0.f;
    }
    __syncthreads();
#pragma unroll
    for (int kk = 0; kk < 16; ++kk) {
      float a0 = sA[kk][ty*4+0], a1 = sA[kk][ty*4+1], a2 = sA[kk][ty*4+2], a3 = sA[kk][ty*4+3];
      float b0 = sB[kk][tx*4+0], b1 = sB[kk][tx*4+1], b2 = sB[kk][tx*4+2], b3 = sB[kk][tx*4+3];
      acc[0][0]=fmaf(a0,b0,acc[0][0]); acc[0][1]=fmaf(a0,b1,acc[0][1]); acc[0][2]=fmaf(a0,b2,acc[0][2]); acc[0][3]=fmaf(a0,b3,acc[0][3]);
      acc[1][0]=fmaf(a1,b0,acc[1][0]); acc[1][1]=fmaf(a1,b1,acc[1][1]); acc[1][2]=fmaf(a1,b2,acc[1][2]); acc[1][3]=fmaf(a1,b3,acc[1][3]);
      acc[2][0]=fmaf(a2,b0,acc[2][0]); acc[2][1]=fmaf(a2,b1,acc[2][1]); acc[2][2]=fmaf(a2,b2,acc[2][2]); acc[2][3]=fmaf(a2,b3,acc[2][3]);
      acc[3][0]=fmaf(a3,b0,acc[3][0]); acc[3][1]=fmaf(a3,b1,acc[3][1]); acc[3][2]=fmaf(a3,b2,acc[3][2]); acc[3][3]=fmaf(a3,b3,acc[3][3]);
    }
    __syncthreads();
  }
#pragma unroll
  for (int i = 0; i < 4; ++i) {
    int m = m0 + ty * 4 + i;
    int b = m >> 7, l = m & 127;
    int mr = (b << 7) + (127 - l);
#pragma unroll
    for (int j = 0; j < 4; ++j) {
      int n = n0 + tx * 4 + j;
      if (n >= VF) continue;
      float v = acc[i][j] + bias[n];
      xf[(size_t)m * DD + n] = v;
      xr[(size_t)mr * DD + n] = v;
    }
  }
}

// audio_k: audio -> xf/xr cols [196,256)
__global__ void audio_k(const float* __restrict__ audio,
                        float* __restrict__ xf, float* __restrict__ xr) {
  int i = blockIdx.x * 256 + threadIdx.x;
  if (i >= BATCH * FRAMES * NM) return;
  int j = i % NM; int l = (i / NM) % FRAMES; int b = i / (NM * FRAMES);
  float v = audio[i];
  xf[(size_t)(b * FRAMES + l) * DD + VF + j] = v;
  xr[(size_t)(b * FRAMES + (FRAMES - 1 - l)) * DD + VF + j] = v;
}

// ---------------------------------------------------------------------------
// rmsnorm_pack: rmsnorm(x)*w -> bf16 in MFMA A-fragment order
// xnb layout: [kt(8)*4+oct][tok(1024)][8].  block 64 thr = 4 tokens.
// ---------------------------------------------------------------------------
__global__ __launch_bounds__(64) void rmsnorm_pack(
    const float* __restrict__ xF, const float* __restrict__ xR,
    const float* __restrict__ nwF, const float* __restrict__ nwR,
    unsigned short* __restrict__ xnbF, unsigned short* __restrict__ xnbR)
{
  const int dir = blockIdx.z;
  const float* x = dir ? xR : xF;
  const float* nw = dir ? nwR : nwF;
  unsigned short* xnb = dir ? xnbR : xnbF;
  const int t = threadIdx.x;
  const int tok = blockIdx.x * 4 + (t >> 4);
  const int l16 = t & 15;
  const float* row = x + (size_t)tok * DD + l16 * 16;
  float v[16];
  float ss = 0.f;
#pragma unroll
  for (int i = 0; i < 4; ++i) {
    float4 f = ((const float4*)row)[i];
    v[4*i] = f.x; v[4*i+1] = f.y; v[4*i+2] = f.z; v[4*i+3] = f.w;
    ss += f.x*f.x + f.y*f.y + f.z*f.z + f.w*f.w;
  }
  ss += __shfl_xor(ss, 1, 16);
  ss += __shfl_xor(ss, 2, 16);
  ss += __shfl_xor(ss, 4, 16);
  ss += __shfl_xor(ss, 8, 16);
  float scale = rsqrtf(ss * (1.f / DD) + 1e-5f);
  const float* nwp = nw + l16 * 16;
#pragma unroll
  for (int hh = 0; hh < 2; ++hh) {
    unsigned ub[4];
#pragma unroll
    for (int p = 0; p < 4; ++p) {
      unsigned short lo = f2bf(v[hh*8 + 2*p]     * scale * nwp[hh*8 + 2*p]);
      unsigned short hi = f2bf(v[hh*8 + 2*p + 1] * scale * nwp[hh*8 + 2*p + 1]);
      ub[p] = (unsigned)lo | ((unsigned)hi << 16);
    }
    int k0 = l16 * 16 + hh * 8;
    int kt = k0 >> 5, oct = (k0 >> 3) & 3;
    uint4 w4 = {ub[0], ub[1], ub[2], ub[3]};
    *(uint4*)(xnb + ((size_t)(kt * 4 + oct) * 1024 + tok) * 8) = w4;
  }
}

// ---------------------------------------------------------------------------
// inproj_mfma2: zero-LDS bf16 MFMA GEMM. A from xnb (fragment-ordered global),
// B from packed weights. Each wave: 16 tokens x 64 outs. grid (64,4,2)x256.
// ---------------------------------------------------------------------------
__global__ __launch_bounds__(256) void inproj_mfma2(
    const unsigned short* __restrict__ xnbF, const unsigned short* __restrict__ xnbR,
    const unsigned short* __restrict__ Wip, int layer,
    float* __restrict__ xzF, float* __restrict__ xzR)
{
  const int dir = blockIdx.z;
  const unsigned short* xnb = dir ? xnbR : xnbF;
  float* xz = dir ? xzR : xzF;
  const int t = threadIdx.x, lane = t & 63, w = t >> 6;
  const int tok0 = blockIdx.x * 16;
  short8v af[8];
#pragma unroll
  for (int kt = 0; kt < 8; ++kt)
    af[kt] = *(const short8v*)(xnb + ((size_t)(kt * 4 + (lane >> 4)) * 1024 + tok0 + (lane & 15)) * 8);
#pragma unroll
  for (int ns = 0; ns < 4; ++ns) {
    const int ntile = blockIdx.y * 16 + w * 4 + ns;
    const unsigned short* wb = Wip + (((size_t)(dir * 4 + layer) * 512 + ntile * 8) * 64 + lane) * 8;
    f32x4 acc = (f32x4){0.f, 0.f, 0.f, 0.f};
#pragma unroll
    for (int kt = 0; kt < 8; ++kt) {
      short8v bf = *(const short8v*)(wb + (size_t)kt * 64 * 8);
      acc = __builtin_amdgcn_mfma_f32_16x16x32_bf16(af[kt], bf, acc, 0, 0, 0);
    }
#pragma unroll
    for (int r = 0; r < 4; ++r)
      xz[(size_t)(tok0 + (lane >> 4) * 4 + r) * 1024 + ntile * 16 + (lane & 15)] = acc[r];
  }
}

// ---------------------------------------------------------------------------
// convsilu2_k: mass-parallel causal-conv4 + silu
// ---------------------------------------------------------------------------
__global__ __launch_bounds__(256) void convsilu2_k(
    const float* __restrict__ xzF, const float* __restrict__ xzR,
    const float* __restrict__ cwF, const float* __restrict__ cwR,
    const float* __restrict__ cbF, const float* __restrict__ cbR,
    float* __restrict__ xcF, float* __restrict__ xcR,
    unsigned short* __restrict__ xcbF, unsigned short* __restrict__ xcbR)
{
  const int dir = blockIdx.z;
  const float* xz = dir ? xzR : xzF;
  const float* cw = dir ? cwR : cwF;
  const float* cb = dir ? cbR : cbF;
  float* xc = dir ? xcR : xcF;
  unsigned short* xcb = dir ? xcbR : xcbF;

  int i = blockIdx.x * 256 + threadIdx.x;
  int tok = i >> 6;
  int e0 = (i & 63) << 3;
  int l = tok & 127;
  const float* col = xz + (size_t)tok * 1024 + e0;

  float v3[8] = {}, v2[8] = {}, v1[8] = {}, v0[8];
  if (l >= 3) { *(float4*)v3 = *(const float4*)(col - 3072); *(float4*)(v3+4) = *(const float4*)(col - 3068); }
  if (l >= 2) { *(float4*)v2 = *(const float4*)(col - 2048); *(float4*)(v2+4) = *(const float4*)(col - 2044); }
  if (l >= 1) { *(float4*)v1 = *(const float4*)(col - 1024); *(float4*)(v1+4) = *(const float4*)(col - 1020); }
  *(float4*)v0 = *(const float4*)col; *(float4*)(v0+4) = *(const float4*)(col + 4);

  float cbv[8];
  *(float4*)cbv = *(const float4*)(cb + e0); *(float4*)(cbv+4) = *(const float4*)(cb + e0 + 4);

  float res[8];
#pragma unroll
  for (int j = 0; j < 8; ++j) {
    float4 cv = ((const float4*)cw)[e0 + j];
    float a = cbv[j];
    a = fmaf(cv.x, v3[j], a);
    a = fmaf(cv.y, v2[j], a);
    a = fmaf(cv.z, v1[j], a);
    a = fmaf(cv.w, v0[j], a);
    res[j] = a / (1.f + __expf(-a));
  }
  float4 r0 = {res[0], res[1], res[2], res[3]};
  float4 r1 = {res[4], res[5], res[6], res[7]};
  float* xcp = xc + (size_t)tok * EDIM + e0;
  *(float4*)xcp = r0; *(float4*)(xcp + 4) = r1;

  unsigned ub[4];
#pragma unroll
  for (int p = 0; p < 4; ++p)
    ub[p] = (unsigned)f2bf(res[2*p]) | ((unsigned)f2bf(res[2*p+1]) << 16);
  int kt = e0 >> 5, oct = (e0 >> 3) & 3;
  uint4 w4 = {ub[0], ub[1], ub[2], ub[3]};
  *(uint4*)(xcb + ((size_t)(kt * 4 + oct) * 1024 + tok) * 8) = w4;
}

// ---------------------------------------------------------------------------
// xproj_mfma: pure-register MFMA GEMM. 64-thr blocks, grid (64,1,2).
// ---------------------------------------------------------------------------
__global__ __launch_bounds__(64) void xproj_mfma(
    const unsigned short* __restrict__ xcbF, const unsigned short* __restrict__ xcbR,
    const unsigned short* __restrict__ Wxp, int layer,
    float* __restrict__ dbF, float* __restrict__ dbR)
{
  const int dir = blockIdx.z;
  const unsigned short* xcb = dir ? xcbR : xcbF;
  float* db = dir ? dbR : dbF;
  const int lane = threadIdx.x & 63;
  const int tok0 = blockIdx.x * 16;
  const unsigned short* wbase = Wxp + ((size_t)(dir * 4 + layer) * 3 * 16 * 64) * 8;
  f32x4 acc[3];
#pragma unroll
  for (int nt = 0; nt < 3; ++nt) acc[nt] = (f32x4){0.f, 0.f, 0.f, 0.f};
#pragma unroll
  for (int kt = 0; kt < 16; ++kt) {
    short8v af = *(const short8v*)(xcb + ((size_t)(kt * 4 + (lane >> 4)) * 1024 + tok0 + (lane & 15)) * 8);
#pragma unroll
    for (int nt = 0; nt < 3; ++nt) {
      short8v bf = *(const short8v*)(wbase + ((size_t)(nt * 16 + kt) * 64 + lane) * 8);
      acc[nt] = __builtin_amdgcn_mfma_f32_16x16x32_bf16(af, bf, acc[nt], 0, 0, 0);
    }
  }
#pragma unroll
  for (int nt = 0; nt < 3; ++nt)
#pragma unroll
    for (int r = 0; r < 4; ++r)
      db[(size_t)(tok0 + (lane >> 4) * 4 + r) * 48 + nt * 16 + (lane & 15)] = acc[nt][r];
}

// ---------------------------------------------------------------------------
// dtproj_k: dl[tok][e] = softplus(db[tok][0:16] @ dtw[e][:] + dtb[e])
// ---------------------------------------------------------------------------
__global__ __launch_bounds__(256) void dtproj_k(
    const float* __restrict__ dbF, const float* __restrict__ dbR,
    const float* __restrict__ dwF, const float* __restrict__ dwR,
    const float* __restrict__ dtbF, const float* __restrict__ dtbR,
    float* __restrict__ dlF, float* __restrict__ dlR)
{
  const int dir = blockIdx.z;
  const float* db = dir ? dbR : dbF;
  const float* dw = dir ? dwR : dwF;
  const float* dtb = dir ? dtbR : dtbF;
  float* dl = dir ? dlR : dlF;
  int i = blockIdx.x * 256 + threadIdx.x;
  int tok = i >> 9, e = i & 511;
  const float* d = db + (size_t)tok * 48;
  const float* w = dw + (size_t)e * 16;
  float acc = dtb[e];
#pragma unroll
  for (int q = 0; q < 4; ++q) {
    float4 dv = *(const float4*)(d + 4 * q);
    float4 wv = *(const float4*)(w + 4 * q);
    acc = fmaf(dv.x, wv.x, acc);
    acc = fmaf(dv.y, wv.y, acc);
    acc = fmaf(dv.z, wv.z, acc);
    acc = fmaf(dv.w, wv.w, acc);
  }
  dl[i] = (acc > 20.f) ? acc : __logf(1.f + __expf(acc));
}

// ---------------------------------------------------------------------------
// scan3_k: selective scan + gating; delta precomputed. 16 lanes/(b,e).
// ---------------------------------------------------------------------------
__global__ __launch_bounds__(256) void scan3_k(
    const float* __restrict__ xzF, const float* __restrict__ xzR,
    const float* __restrict__ xcF, const float* __restrict__ xcR,
    const float* __restrict__ dbF, const float* __restrict__ dbR,
    const float* __restrict__ dlF, const float* __restrict__ dlR,
    const float* __restrict__ AlF, const float* __restrict__ AlR,
    const float* __restrict__ DpF, const float* __restrict__ DpR,
    unsigned short* __restrict__ yoF, unsigned short* __restrict__ yoR)
{
  const int dir = blockIdx.z;
  const float* xz = dir ? xzR : xzF;
  const float* xc = dir ? xcR : xcF;
  const float* db = dir ? dbR : dbF;
  const float* dl = dir ? dlR : dlF;
  const float* Al = dir ? AlR : AlF;
  const float* Dp = dir ? DpR : DpF;
  unsigned short* yo = dir ? yoR : yoF;

  __shared__ float sdb[FRAMES * 48];
  __shared__ float sxc[FRAMES * 16];
  __shared__ float szz[FRAMES * 16];
  __shared__ float sdl[FRAMES * 16];
  const int b = blockIdx.x >> 5;
  const int e0 = (blockIdx.x & 31) << 4;
  const int t = threadIdx.x, g = t >> 4, n = t & 15;
  const int e = e0 + g;

  const float* dbp = db + (size_t)b * FRAMES * 48;
  for (int i = t; i < FRAMES * 48 / 4; i += 256)
    ((float4*)sdb)[i] = ((const float4*)dbp)[i];
  for (int i = t; i < FRAMES * 16; i += 256) {
    int l = i >> 4, c = i & 15;
    sxc[i] = xc[(size_t)(b * FRAMES + l) * EDIM + e0 + c];
    szz[i] = xz[(size_t)(b * FRAMES + l) * 1024 + 512 + e0 + c];
    sdl[i] = dl[(size_t)(b * FRAMES + l) * EDIM + e0 + c];
  }
  float An = -expf(Al[e * NSTATE + n]);
  float Dv = Dp[e];
  float h = 0.f;
  unsigned short* yp = yo + ((size_t)((e >> 5) * 4 + ((e >> 3) & 3)) * 1024 + b * FRAMES) * 8 + (e & 7);
  __syncthreads();

#pragma unroll 1
  for (int l = 0; l < FRAMES; ++l) {
    float dlt = sdl[l * 16 + g];
    float xcv = sxc[l * 16 + g];
    float Bn = sdb[l * 48 + 16 + n];
    float Cn = sdb[l * 48 + 32 + n];
    float dA = __expf(dlt * An);
    h = fmaf(dA, h, dlt * xcv * Bn);
    float part = h * Cn;
    part += __shfl_xor(part, 1, 16);
    part += __shfl_xor(part, 2, 16);
    part += __shfl_xor(part, 4, 16);
    part += __shfl_xor(part, 8, 16);
    if (n == 0) {
      float zz = szz[l * 16 + g];
      float a2 = fmaf(Dv, xcv, part);
      float sv = zz / (1.f + __expf(-zz));
      yp[(size_t)l * 8] = f2bf(a2 * sv);
    }
  }
}

// ---------------------------------------------------------------------------
// outproj_mfma: zero-LDS bf16 MFMA GEMM + residual add.
// ---------------------------------------------------------------------------
__global__ __launch_bounds__(256) void outproj_mfma(
    const unsigned short* __restrict__ yoF, const unsigned short* __restrict__ yoR,
    const unsigned short* __restrict__ Wop, int layer,
    float* __restrict__ xF, float* __restrict__ xR)
{
  const int dir = blockIdx.z;
  const unsigned short* yo = dir ? yoR : yoF;
  float* xx = dir ? xR : xF;
  const int t = threadIdx.x, lane = t & 63, w = t >> 6;
  const int m0 = blockIdx.x * 32, n0 = blockIdx.y * 64;
  const int ntile = blockIdx.y * 4 + w;
  const unsigned short* wb = Wop + (((size_t)(dir * 4 + layer) * 256 + ntile * 16) * 64 + lane) * 8;
  f32x4 acc[2];
  acc[0] = (f32x4){0.f, 0.f, 0.f, 0.f};
  acc[1] = (f32x4){0.f, 0.f, 0.f, 0.f};
#pragma unroll
  for (int kt = 0; kt < 16; ++kt) {
    short8v bf = *(const short8v*)(wb + (size_t)kt * 64 * 8);
#pragma unroll
    for (int mt = 0; mt < 2; ++mt) {
      short8v af = *(const short8v*)(yo + ((size_t)(kt * 4 + (lane >> 4)) * 1024 + m0 + mt * 16 + (lane & 15)) * 8);
      acc[mt] = __builtin_amdgcn_mfma_f32_16x16x32_bf16(af, bf, acc[mt], 0, 0, 0);
    }
  }
#pragma unroll
  for (int mt = 0; mt < 2; ++mt)
#pragma unroll
    for (int r = 0; r < 4; ++r) {
      size_t ci = (size_t)(m0 + mt * 16 + (lane >> 4) * 4 + r) * DD + n0 + w * 16 + (lane & 15);
      xx[ci] += acc[mt][r];
    }
}

__global__ __launch_bounds__(256) void head_k(
    const float* __restrict__ xf, const float* __restrict__ xr,
    const float* __restrict__ fcw, const float* __restrict__ fcb,
    const float* __restrict__ fc2w, const float* __restrict__ fc2b,
    float* __restrict__ out)
{
  int b = blockIdx.x;
  __shared__ float xl[2 * DD];
  __shared__ float h[DD];
  __shared__ float hp[4];
  int t = threadIdx.x;
  xl[t]      = xf[(size_t)(b * FRAMES + FRAMES - 1) * DD + t];
  xl[DD + t] = xr[(size_t)(b * FRAMES + 0) * DD + t];
  __syncthreads();
  float acc = fcb[t];
  for (int k = 0; k < 2 * DD; ++k) acc = fmaf(xl[k], fcw[(size_t)t * 2 * DD + k], acc);
  h[t] = acc;
  __syncthreads();
  {
    int c = t >> 7, k = t & 127;
    float p = h[k] * fc2w[c * DD + k] + h[k + 128] * fc2w[c * DD + k + 128];
#pragma unroll
    for (int off = 32; off; off >>= 1) p += __shfl_xor(p, off, 64);
    if ((t & 63) == 0) hp[t >> 6] = p;
  }
  __syncthreads();
  if (t < 2) out[b * 2 + t] = hp[2 * t] + hp[2 * t + 1] + fc2b[t];
}

// ---------------------------------------------------------------------------
extern "C" void kernel_launch(void* const* d_in, const int* in_sizes, int n_in,
                              void* d_out, int out_size, void* d_ws, size_t ws_size,
                              hipStream_t stream) {
  const float* video = (const float*)d_in[0];
  const float* audio = (const float*)d_in[1];
  const float* c1w = (const float*)d_in[2];
  const float* c1b = (const float*)d_in[3];
  const float* c2w = (const float*)d_in[4];
  const float* c2b = (const float*)d_in[5];
  const float* fcw = (const float*)d_in[6];
  const float* fcb = (const float*)d_in[7];
  const float* Wf[10]; const float* Wb_[10];
  for (int i = 0; i < 10; ++i) { Wf[i] = (const float*)d_in[8+i]; Wb_[i] = (const float*)d_in[18+i]; }
  const float* fc_w  = (const float*)d_in[28];
  const float* fc_b  = (const float*)d_in[29];
  const float* fc2_w = (const float*)d_in[30];
  const float* fc2_b = (const float*)d_in[31];
  float* out = (float*)d_out;

  // workspace (float slots)
  float* ws   = (float*)d_ws;
  float* feat = ws;                       // 65536
  float* xf   = feat + 65536;             // 262144
  float* xr   = xf   + 262144;            // 262144
  float* xzF  = xr   + 262144;            // 1048576
  float* xzR  = xzF  + 1048576;           // 1048576
  float* xcF  = xzR  + 1048576;           // 524288
  float* xcR  = xcF  + 524288;            // 524288
  float* dbF  = xcR  + 524288;            // 49152
  float* dbR  = dbF  + 49152;             // 49152
  float* dlF  = dbR  + 49152;             // 524288
  float* dlR  = dlF  + 524288;            // 524288
  unsigned short* yoF = (unsigned short*)(dlR + 524288);    // 524288 sh
  unsigned short* yoR = yoF + 524288;
  unsigned short* X1  = yoR + 524288;                        // 33554432 sh
  unsigned short* Wbp = X1 + 33554432;                       // 18432 sh
  unsigned short* Wip = Wbp + 18432;                         // 2097152 sh
  unsigned short* Wop = Wip + 2097152;                       // 1048576 sh
  unsigned short* Wxp = Wop + 1048576;                       // 196608 sh
  unsigned short* xcbF = Wxp + 196608;                       // 524288 sh
  unsigned short* xcbR = xcbF + 524288;                      // 524288 sh
  unsigned short* xnbF = xcbR + 524288;                      // 524288 sh
  unsigned short* xnbR = xnbF + 524288;                      // 524288 sh

  // 1. packs + CNN
  pack_w2<<<dim3(9), 256, 0, stream>>>(c2w, Wbp);
  pack_mamba<<<dim3(1632), 256, 0, stream>>>(Wf[1], Wb_[1], Wf[9], Wb_[9], Wf[4], Wb_[4],
                                             Wip, Wop, Wxp);
  conv1_k<<<dim3(TOK), 256, 0, stream>>>(video, c1w, c1b, X1);
  conv2_k<<<dim3(TOK), 256, (size_t)(X_LDS_BYTES + 1024), stream>>>(X1, Wbp, c2b, feat);

  // 2. cnn fc (writes xf+xr directly) + audio fill (independent)
  fcgemm_k<<<dim3(16, 4), 256, 0, stream>>>(feat, fcw, fcb, xf, xr);
  audio_k<<<dim3((BATCH*FRAMES*NM + 255)/256), 256, 0, stream>>>(audio, xf, xr);

  // 3. bi-Mamba (7 kernels per layer, all high-occupancy or zero-LDS MFMA)
  for (int l = 0; l < NLAYER; ++l) {
    const float* nwF  = Wf[0] + l*DD;              const float* nwR  = Wb_[0] + l*DD;
    const float* cwF_ = Wf[2] + l*EDIM*4;          const float* cwR_ = Wb_[2] + l*EDIM*4;
    const float* cbF_ = Wf[3] + l*EDIM;            const float* cbR_ = Wb_[3] + l*EDIM;
    const float* dwF  = Wf[5] + l*EDIM*DTRANK;     const float* dwR  = Wb_[5] + l*EDIM*DTRANK;
    const float* dtbF = Wf[6] + l*EDIM;            const float* dtbR = Wb_[6] + l*EDIM;
    const float* AlF  = Wf[7] + l*EDIM*NSTATE;     const float* AlR  = Wb_[7] + l*EDIM*NSTATE;
    const float* DpF  = Wf[8] + l*EDIM;            const float* DpR  = Wb_[8] + l*EDIM;

    rmsnorm_pack<<<dim3(256, 1, 2), 64, 0, stream>>>(xf, xr, nwF, nwR, xnbF, xnbR);
    inproj_mfma2<<<dim3(64, 4, 2), 256, 0, stream>>>(xnbF, xnbR, Wip, l, xzF, xzR);
    convsilu2_k<<<dim3(256, 1, 2), 256, 0, stream>>>(xzF, xzR, cwF_, cwR_, cbF_, cbR_,
                                                     xcF, xcR, xcbF, xcbR);
    xproj_mfma<<<dim3(64, 1, 2), 64, 0, stream>>>(xcbF, xcbR, Wxp, l, dbF, dbR);
    dtproj_k<<<dim3(2048, 1, 2), 256, 0, stream>>>(dbF, dbR, dwF, dwR, dtbF, dtbR, dlF, dlR);
    scan3_k<<<dim3(256, 1, 2), 256, 0, stream>>>(xzF, xzR, xcF, xcR, dbF, dbR, dlF, dlR,
                                                 AlF, AlR, DpF, DpR, yoF, yoR);
    outproj_mfma<<<dim3(32, 4, 2), 256, 0, stream>>>(yoF, yoR, Wop, l, xf, xr);
  }

  // 4. head
  head_k<<<dim3(BATCH), 256, 0, stream>>>(xf, xr, fc_w, fc_b, fc2_w, fc2_b, out);
}

// Round 8
// 460.898 us; speedup vs baseline: 2.7764x; 1.1313x over previous
//
#include <hip/hip_runtime.h>
#include <hip/hip_bf16.h>
#include <cstdint>
#include <cstddef>

#define BATCH 8
#define FRAMES 128
#define TOK (BATCH*FRAMES)   // 1024
#define NM 60
#define VF 196
#define DD 256
#define EDIM 512
#define NSTATE 16
#define DTRANK 16
#define NLAYER 4

typedef __attribute__((ext_vector_type(8))) short short8v;
typedef __attribute__((ext_vector_type(4))) float f32x4;

__device__ __forceinline__ unsigned short f2bf(float f) {
  unsigned x = __float_as_uint(f);
  unsigned r = (x + 0x7FFFu + ((x >> 16) & 1u)) >> 16;
  return (unsigned short)r;
}

// ---------------------------------------------------------------------------
// pack_w2: W2 (64,32,3,3) f32 -> Wb[shift(9)][mtile(4)][lane(64)][8] bf16
// ---------------------------------------------------------------------------
__global__ void pack_w2(const float* __restrict__ w2, unsigned short* __restrict__ Wb) {
  int id = blockIdx.x * 256 + threadIdx.x;
  if (id >= 9 * 4 * 64) return;
  int lane = id & 63;
  int mt = (id >> 6) & 3;
  int sh = id >> 8;
  int dy = sh / 3, dx = sh % 3;
  int oc = mt * 16 + (lane & 15);
  int ic0 = (lane >> 4) * 8;
  unsigned u[4];
#pragma unroll
  for (int p = 0; p < 4; ++p) {
    unsigned short lo = f2bf(w2[((oc * 32 + ic0 + 2 * p) * 3 + dy) * 3 + dx]);
    unsigned short hi = f2bf(w2[((oc * 32 + ic0 + 2 * p + 1) * 3 + dy) * 3 + dx]);
    u[p] = (unsigned)lo | ((unsigned)hi << 16);
  }
  uint4 v = {u[0], u[1], u[2], u[3]};
  *(uint4*)(Wb + (size_t)id * 8) = v;
}

// ---------------------------------------------------------------------------
// pack_mamba: in_proj / out_proj / x_proj weights -> bf16 MFMA B-fragment order
// ---------------------------------------------------------------------------
__global__ void pack_mamba(const float* __restrict__ ipF, const float* __restrict__ ipR,
                           const float* __restrict__ opF, const float* __restrict__ opR,
                           const float* __restrict__ xpF, const float* __restrict__ xpR,
                           unsigned short* __restrict__ Wip, unsigned short* __restrict__ Wop,
                           unsigned short* __restrict__ Wxp) {
  int id = blockIdx.x * 256 + threadIdx.x;
  if (id < 262144) {                     // in_proj
    int dl = id >> 15, r = id & 32767;
    int ntile = r >> 9, kt = (r >> 6) & 7, lane = r & 63;
    int dir = dl >> 2, layer = dl & 3;
    const float* src = (dir ? ipR : ipF) + (size_t)layer * 1024 * 256
                       + (size_t)(ntile * 16 + (lane & 15)) * 256 + kt * 32 + (lane >> 4) * 8;
    unsigned u[4];
#pragma unroll
    for (int p = 0; p < 4; ++p)
      u[p] = (unsigned)f2bf(src[2 * p]) | ((unsigned)f2bf(src[2 * p + 1]) << 16);
    uint4 v = {u[0], u[1], u[2], u[3]};
    *(uint4*)(Wip + (size_t)id * 8) = v;
  } else if (id < 262144 + 131072) {     // out_proj
    int id2 = id - 262144;
    int dl = id2 >> 14, rr = id2 & 16383;
    int ntile = rr >> 10, kt = (rr >> 6) & 15, lane = rr & 63;
    int dir = dl >> 2, layer = dl & 3;
    const float* src = (dir ? opR : opF) + (size_t)layer * 256 * 512
                       + (size_t)(ntile * 16 + (lane & 15)) * 512 + kt * 32 + (lane >> 4) * 8;
    unsigned u[4];
#pragma unroll
    for (int p = 0; p < 4; ++p)
      u[p] = (unsigned)f2bf(src[2 * p]) | ((unsigned)f2bf(src[2 * p + 1]) << 16);
    uint4 v = {u[0], u[1], u[2], u[3]};
    *(uint4*)(Wop + (size_t)id2 * 8) = v;
  } else if (id < 262144 + 131072 + 24576) {  // x_proj (48 x 512)
    int id3 = id - 262144 - 131072;
    int dl = id3 / 3072, rr = id3 % 3072;
    int ntile = rr >> 10, kt = (rr >> 6) & 15, lane = rr & 63;
    int dir = dl >> 2, layer = dl & 3;
    const float* src = (dir ? xpR : xpF) + (size_t)layer * 48 * 512
                       + (size_t)(ntile * 16 + (lane & 15)) * 512 + kt * 32 + (lane >> 4) * 8;
    unsigned u[4];
#pragma unroll
    for (int p = 0; p < 4; ++p)
      u[p] = (unsigned)f2bf(src[2 * p]) | ((unsigned)f2bf(src[2 * p + 1]) << 16);
    uint4 v = {u[0], u[1], u[2], u[3]};
    *(uint4*)(Wxp + (size_t)id3 * 8) = v;
  }
}

// ---------------------------------------------------------------------------
// conv1_k: conv(3->32)+relu+pool, channel-chunked (8 oc at a time) so the
// live register set is bounded by construction: 32 acc + 16-float window.
// Window reloaded once per (chunk, ic) = 192 LDS reads/strip (vs ~3456 remat).
// ---------------------------------------------------------------------------
#define C1P 72
__global__ __launch_bounds__(256, 2) void conv1_k(
    const float* __restrict__ video, const float* __restrict__ w1,
    const float* __restrict__ b1, unsigned short* __restrict__ X1)
{
  __shared__ float imgs[3 * 34 * C1P];
  const int img = blockIdx.x, t = threadIdx.x;
  const float* vin = video + (size_t)img * 12288;
  const int px = t & 31, pyl = t >> 5;

#pragma unroll 1
  for (int h = 0; h < 2; ++h) {
    __syncthreads();
    float4 z4 = {0.f, 0.f, 0.f, 0.f};
    for (int i = t; i < (3 * 34 * C1P) / 4; i += 256) ((float4*)imgs)[i] = z4;
    __syncthreads();
    for (int i = t; i < 3 * 33 * 16; i += 256) {
      int ic = i / 528; int rr = (i - ic * 528) >> 4; int c4 = i & 15;
      int r  = rr + (h ? 0 : 1);
      int gr = 32 * h - 1 + r;
      float4 v = *(const float4*)(vin + ic * 4096 + gr * 64 + c4 * 4);
      *(float4*)(imgs + ic * (34 * C1P) + r * C1P + 4 + c4 * 4) = v;
    }
    __syncthreads();
#pragma unroll 1
    for (int s = 0; s < 2; ++s) {
      const int y = pyl + 8 * (2 * h + s);
      const int lr0 = 2 * (pyl + 8 * s);
      size_t base = ((size_t)img * 1024 + (size_t)y * 32 + px) * 32;
#pragma unroll 1
      for (int c8 = 0; c8 < 4; ++c8) {
        float acc[8][4];
#pragma unroll
        for (int ch = 0; ch < 8; ++ch) {
          float bb = b1[c8 * 8 + ch];
          acc[ch][0] = bb; acc[ch][1] = bb; acc[ch][2] = bb; acc[ch][3] = bb;
        }
#pragma unroll
        for (int ic = 0; ic < 3; ++ic) {
          float win[4][4];
#pragma unroll
          for (int rr = 0; rr < 4; ++rr)
#pragma unroll
            for (int cc = 0; cc < 4; ++cc)
              win[rr][cc] = imgs[ic * (34 * C1P) + (lr0 + rr) * C1P + (2 * px + 3 + cc)];
#pragma unroll
          for (int rr = 0; rr < 4; ++rr)
#pragma unroll
            for (int cc = 0; cc < 4; ++cc)
              asm volatile("" : "+v"(win[rr][cc]));
#pragma unroll
          for (int ch = 0; ch < 8; ++ch) {
            const float* wp = w1 + (c8 * 8 + ch) * 27 + ic * 9;
            float q0 = wp[0], q1 = wp[1], q2 = wp[2], q3 = wp[3], q4 = wp[4],
                  q5 = wp[5], q6 = wp[6], q7 = wp[7], q8 = wp[8];
            float a0 = acc[ch][0], a1 = acc[ch][1], a2 = acc[ch][2], a3 = acc[ch][3];
            a0 = fmaf(q0, win[0][0], a0); a0 = fmaf(q1, win[0][1], a0); a0 = fmaf(q2, win[0][2], a0);
            a0 = fmaf(q3, win[1][0], a0); a0 = fmaf(q4, win[1][1], a0); a0 = fmaf(q5, win[1][2], a0);
            a0 = fmaf(q6, win[2][0], a0); a0 = fmaf(q7, win[2][1], a0); a0 = fmaf(q8, win[2][2], a0);
            a1 = fmaf(q0, win[0][1], a1); a1 = fmaf(q1, win[0][2], a1); a1 = fmaf(q2, win[0][3], a1);
            a1 = fmaf(q3, win[1][1], a1); a1 = fmaf(q4, win[1][2], a1); a1 = fmaf(q5, win[1][3], a1);
            a1 = fmaf(q6, win[2][1], a1); a1 = fmaf(q7, win[2][2], a1); a1 = fmaf(q8, win[2][3], a1);
            a2 = fmaf(q0, win[1][0], a2); a2 = fmaf(q1, win[1][1], a2); a2 = fmaf(q2, win[1][2], a2);
            a2 = fmaf(q3, win[2][0], a2); a2 = fmaf(q4, win[2][1], a2); a2 = fmaf(q5, win[2][2], a2);
            a2 = fmaf(q6, win[3][0], a2); a2 = fmaf(q7, win[3][1], a2); a2 = fmaf(q8, win[3][2], a2);
            a3 = fmaf(q0, win[1][1], a3); a3 = fmaf(q1, win[1][2], a3); a3 = fmaf(q2, win[1][3], a3);
            a3 = fmaf(q3, win[2][1], a3); a3 = fmaf(q4, win[2][2], a3); a3 = fmaf(q5, win[2][3], a3);
            a3 = fmaf(q6, win[3][1], a3); a3 = fmaf(q7, win[3][2], a3); a3 = fmaf(q8, win[3][3], a3);
            acc[ch][0] = a0; acc[ch][1] = a1; acc[ch][2] = a2; acc[ch][3] = a3;
          }
        }
        unsigned u4[4];
#pragma unroll
        for (int ch = 0; ch < 8; ++ch) {
          float a0 = fmaxf(acc[ch][0], 0.f), a1 = fmaxf(acc[ch][1], 0.f);
          float a2 = fmaxf(acc[ch][2], 0.f), a3 = fmaxf(acc[ch][3], 0.f);
          float pooled = fmaxf(fmaxf(a0, a1), fmaxf(a2, a3));
          unsigned short u = f2bf(pooled);
          if ((ch & 1) == 0) u4[ch >> 1] = (unsigned)u;
          else               u4[ch >> 1] |= ((unsigned)u << 16);
        }
        uint4 o = {u4[0], u4[1], u4[2], u4[3]};
        *(uint4*)(X1 + base + c8 * 8) = o;
      }
    }
  }
}

// ---------------------------------------------------------------------------
// conv2_k: unchanged
// ---------------------------------------------------------------------------
#define X_LDS_BYTES (4 * 1156 * 16)
#define OCT_STRIDE  (1156 * 16)
__global__ __launch_bounds__(256) void conv2_k(
    const unsigned short* __restrict__ X1, const unsigned short* __restrict__ Wb,
    const float* __restrict__ b2, float* __restrict__ feat)
{
  extern __shared__ char sm[];
  float* part = (float*)(sm + X_LDS_BYTES);
  const int img = blockIdx.x, t = threadIdx.x;
  const int lane = t & 63, wv = t >> 6;
  const int kg = lane >> 4, l15 = lane & 15;

  for (int j = t; j < 1156; j += 256) {
    int r = j / 34, cc = j - r * 34;
    if (r == 0 || r == 33 || cc == 0 || cc == 33) {
      uint4 z = {0, 0, 0, 0};
#pragma unroll
      for (int oct = 0; oct < 4; ++oct)
        *(uint4*)(sm + oct * OCT_STRIDE + j * 16) = z;
    }
  }
  const uint4* src = (const uint4*)(X1 + (size_t)img * 32768);
#pragma unroll 4
  for (int i = 0; i < 16; ++i) {
    int c = i * 256 + t;
    uint4 v = src[c];
    int oct = c & 3, P = c >> 2;
    int y = P >> 5, x = P & 31;
    *(uint4*)(sm + oct * OCT_STRIDE + ((y + 1) * 34 + (x + 1)) * 16) = v;
  }
  __syncthreads();

  float bia[4][4];
#pragma unroll
  for (int mt = 0; mt < 4; ++mt)
#pragma unroll
    for (int r = 0; r < 4; ++r) bia[mt][r] = b2[mt * 16 + kg * 4 + r];

  float msum[4][4];
#pragma unroll
  for (int mt = 0; mt < 4; ++mt)
#pragma unroll
    for (int r = 0; r < 4; ++r) msum[mt][r] = 0.f;

#pragma unroll 1
  for (int pass = 0; pass < 2; ++pass) {
    f32x4 acc[4][8];
#pragma unroll
    for (int mt = 0; mt < 4; ++mt)
#pragma unroll
      for (int q = 0; q < 8; ++q) acc[mt][q] = (f32x4){0.f, 0.f, 0.f, 0.f};
    int Pq[8];
#pragma unroll
    for (int q = 0; q < 8; ++q) {
      int p = (wv * 16 + pass * 8 + q) * 16 + l15;
      int y = p >> 5, x = p & 31;
      Pq[q] = y * 34 + x;
    }
#pragma unroll
    for (int sh = 0; sh < 9; ++sh) {
      const int dy = sh / 3, dx = sh % 3;
      const int shoff = (dy * 34 + dx) * 16;
      short8v Af[4];
#pragma unroll
      for (int mt = 0; mt < 4; ++mt)
        Af[mt] = *(const short8v*)(Wb + ((size_t)(sh * 4 + mt) * 64 + lane) * 8);
#pragma unroll
      for (int q = 0; q < 8; ++q) {
        short8v Bf = *(const short8v*)(sm + kg * OCT_STRIDE + Pq[q] * 16 + shoff);
#pragma unroll
        for (int mt = 0; mt < 4; ++mt)
          acc[mt][q] = __builtin_amdgcn_mfma_f32_16x16x32_bf16(Af[mt], Bf, acc[mt][q], 0, 0, 0);
      }
    }
#pragma unroll
    for (int mt = 0; mt < 4; ++mt) {
#pragma unroll
      for (int pr = 0; pr < 4; ++pr) {
        int qa = (pr & 1) + (pr >> 1) * 4;
        int qb = qa + 2;
#pragma unroll
        for (int r = 0; r < 4; ++r) {
          float va = fmaxf(acc[mt][qa][r] + bia[mt][r], 0.f);
          float vb = fmaxf(acc[mt][qb][r] + bia[mt][r], 0.f);
          float v = fmaxf(va, vb);
          v = fmaxf(v, __shfl_xor(v, 1, 64));
          msum[mt][r] += v;
        }
      }
    }
  }
#pragma unroll
  for (int mt = 0; mt < 4; ++mt)
#pragma unroll
    for (int r = 0; r < 4; ++r) {
      float v = msum[mt][r];
      v += __shfl_xor(v, 1, 64);
      v += __shfl_xor(v, 2, 64);
      v += __shfl_xor(v, 4, 64);
      v += __shfl_xor(v, 8, 64);
      if (l15 == 0) part[wv * 64 + mt * 16 + kg * 4 + r] = v * 0.5f;
    }
  __syncthreads();
  if (t < 64)
    feat[(size_t)img * 64 + t] =
        (part[t] + part[64 + t] + part[128 + t] + part[192 + t]) * (1.f / 256.f);
}

// ---------------------------------------------------------------------------
// fcgemm_k: feat(1024,64) @ fcw(196,64)^T + fcb -> writes xf AND reversed xr
// ---------------------------------------------------------------------------
__global__ __launch_bounds__(256) void fcgemm_k(
    const float* __restrict__ A, const float* __restrict__ B,
    const float* __restrict__ bias, float* __restrict__ xf, float* __restrict__ xr)
{
  __shared__ float sA[16][68];
  __shared__ float sB[16][68];
  const int t = threadIdx.x;
  const int m0 = blockIdx.x * 64;
  const int n0 = blockIdx.y * 64;
  const int tx = t & 15, ty = t >> 4;
  const int lk = t & 15, lr = t >> 4;
  float acc[4][4] = {};
  for (int k0 = 0; k0 < 64; k0 += 16) {
#pragma unroll
    for (int rr = 0; rr < 4; ++rr) {
      int m = m0 + lr + rr * 16;
      sA[lk][lr + rr * 16] = A[(size_t)m * 64 + k0 + lk];
      int n = n0 + lr + rr * 16;
      sB[lk][lr + rr * 16] = (n < VF) ? B[(size_t)n * 64 + k0 + lk] : 0.f;
    }
    __syncthreads();
#pragma unroll
    for (int kk = 0; kk < 16; ++kk) {
      float a0 = sA[kk][ty*4+0], a1 = sA[kk][ty*4+1], a2 = sA[kk][ty*4+2], a3 = sA[kk][ty*4+3];
      float b0 = sB[kk][tx*4+0], b1 = sB[kk][tx*4+1], b2 = sB[kk][tx*4+2], b3 = sB[kk][tx*4+3];
      acc[0][0]=fmaf(a0,b0,acc[0][0]); acc[0][1]=fmaf(a0,b1,acc[0][1]); acc[0][2]=fmaf(a0,b2,acc[0][2]); acc[0][3]=fmaf(a0,b3,acc[0][3]);
      acc[1][0]=fmaf(a1,b0,acc[1][0]); acc[1][1]=fmaf(a1,b1,acc[1][1]); acc[1][2]=fmaf(a1,b2,acc[1][2]); acc[1][3]=fmaf(a1,b3,acc[1][3]);
      acc[2][0]=fmaf(a2,b0,acc[2][0]); acc[2][1]=fmaf(a2,b1,acc[2][1]); acc[2][2]=fmaf(a2,b2,acc[2][2]); acc[2][3]=fmaf(a2,b3,acc[2][3]);
      acc[3][0]=fmaf(a3,b0,acc[3][0]); acc[3][1]=fmaf(a3,b1,acc[3][1]); acc[3][2]=fmaf(a3,b2,acc[3][2]); acc[3][3]=fmaf(a3,b3,acc[3][3]);
    }
    __syncthreads();
  }
#pragma unroll
  for (int i = 0; i < 4; ++i) {
    int m = m0 + ty * 4 + i;
    int b = m >> 7, l = m & 127;
    int mr = (b << 7) + (127 - l);
#pragma unroll
    for (int j = 0; j < 4; ++j) {
      int n = n0 + tx * 4 + j;
      if (n >= VF) continue;
      float v = acc[i][j] + bias[n];
      xf[(size_t)m * DD + n] = v;
      xr[(size_t)mr * DD + n] = v;
    }
  }
}

// audio_k: audio -> xf/xr cols [196,256)
__global__ void audio_k(const float* __restrict__ audio,
                        float* __restrict__ xf, float* __restrict__ xr) {
  int i = blockIdx.x * 256 + threadIdx.x;
  if (i >= BATCH * FRAMES * NM) return;
  int j = i % NM; int l = (i / NM) % FRAMES; int b = i / (NM * FRAMES);
  float v = audio[i];
  xf[(size_t)(b * FRAMES + l) * DD + VF + j] = v;
  xr[(size_t)(b * FRAMES + (FRAMES - 1 - l)) * DD + VF + j] = v;
}

// ---------------------------------------------------------------------------
// inproj_mfma3: fused rmsnorm (in-block, 16 tokens) + bf16 MFMA GEMM.
// grid (64, 4, 2) x 256. LDS: sa[32][16][8] bf16 = 8KB.
// ---------------------------------------------------------------------------
__global__ __launch_bounds__(256) void inproj_mfma3(
    const float* __restrict__ xF, const float* __restrict__ xR,
    const float* __restrict__ nwF, const float* __restrict__ nwR,
    const unsigned short* __restrict__ Wip, int layer,
    float* __restrict__ xzF, float* __restrict__ xzR)
{
  const int dir = blockIdx.z;
  const float* x = dir ? xR : xF;
  const float* nw = dir ? nwR : nwF;
  float* xz = dir ? xzR : xzF;
  __shared__ unsigned short sa[32 * 16 * 8];   // 8KB
  const int t = threadIdx.x;
  const int tok0 = blockIdx.x * 16;
  {
    const int tk = t >> 4, l16 = t & 15;
    const float* row = x + (size_t)(tok0 + tk) * DD + l16 * 16;
    float v[16];
    float ss = 0.f;
#pragma unroll
    for (int i = 0; i < 4; ++i) {
      float4 f = ((const float4*)row)[i];
      v[4*i] = f.x; v[4*i+1] = f.y; v[4*i+2] = f.z; v[4*i+3] = f.w;
      ss += f.x*f.x + f.y*f.y + f.z*f.z + f.w*f.w;
    }
    ss += __shfl_xor(ss, 1, 16);
    ss += __shfl_xor(ss, 2, 16);
    ss += __shfl_xor(ss, 4, 16);
    ss += __shfl_xor(ss, 8, 16);
    float scale = rsqrtf(ss * (1.f / DD) + 1e-5f);
    const float* nwp = nw + l16 * 16;
#pragma unroll
    for (int hh = 0; hh < 2; ++hh) {
      unsigned ub[4];
#pragma unroll
      for (int p = 0; p < 4; ++p) {
        unsigned short lo = f2bf(v[hh*8 + 2*p]     * scale * nwp[hh*8 + 2*p]);
        unsigned short hi = f2bf(v[hh*8 + 2*p + 1] * scale * nwp[hh*8 + 2*p + 1]);
        ub[p] = (unsigned)lo | ((unsigned)hi << 16);
      }
      int k0 = l16 * 16 + hh * 8;
      int kt = k0 >> 5, oct = (k0 >> 3) & 3;
      uint4 w4 = {ub[0], ub[1], ub[2], ub[3]};
      *(uint4*)(sa + ((size_t)(kt * 4 + oct) * 16 + tk) * 8) = w4;
    }
  }
  __syncthreads();
  const int lane = t & 63, w = t >> 6;
  short8v af[8];
#pragma unroll
  for (int kt = 0; kt < 8; ++kt)
    af[kt] = *(const short8v*)(sa + ((size_t)(kt * 4 + (lane >> 4)) * 16 + (lane & 15)) * 8);
#pragma unroll
  for (int ns = 0; ns < 4; ++ns) {
    const int ntile = blockIdx.y * 16 + w * 4 + ns;
    const unsigned short* wb = Wip + (((size_t)(dir * 4 + layer) * 512 + ntile * 8) * 64 + lane) * 8;
    f32x4 acc = (f32x4){0.f, 0.f, 0.f, 0.f};
#pragma unroll
    for (int kt = 0; kt < 8; ++kt) {
      short8v bf = *(const short8v*)(wb + (size_t)kt * 64 * 8);
      acc = __builtin_amdgcn_mfma_f32_16x16x32_bf16(af[kt], bf, acc, 0, 0, 0);
    }
#pragma unroll
    for (int r = 0; r < 4; ++r)
      xz[(size_t)(tok0 + (lane >> 4) * 4 + r) * 1024 + ntile * 16 + (lane & 15)] = acc[r];
  }
}

// ---------------------------------------------------------------------------
// convsilu2_k: mass-parallel causal-conv4 + silu
// ---------------------------------------------------------------------------
__global__ __launch_bounds__(256) void convsilu2_k(
    const float* __restrict__ xzF, const float* __restrict__ xzR,
    const float* __restrict__ cwF, const float* __restrict__ cwR,
    const float* __restrict__ cbF, const float* __restrict__ cbR,
    float* __restrict__ xcF, float* __restrict__ xcR,
    unsigned short* __restrict__ xcbF, unsigned short* __restrict__ xcbR)
{
  const int dir = blockIdx.z;
  const float* xz = dir ? xzR : xzF;
  const float* cw = dir ? cwR : cwF;
  const float* cb = dir ? cbR : cbF;
  float* xc = dir ? xcR : xcF;
  unsigned short* xcb = dir ? xcbR : xcbF;

  int i = blockIdx.x * 256 + threadIdx.x;
  int tok = i >> 6;
  int e0 = (i & 63) << 3;
  int l = tok & 127;
  const float* col = xz + (size_t)tok * 1024 + e0;

  float v3[8] = {}, v2[8] = {}, v1[8] = {}, v0[8];
  if (l >= 3) { *(float4*)v3 = *(const float4*)(col - 3072); *(float4*)(v3+4) = *(const float4*)(col - 3068); }
  if (l >= 2) { *(float4*)v2 = *(const float4*)(col - 2048); *(float4*)(v2+4) = *(const float4*)(col - 2044); }
  if (l >= 1) { *(float4*)v1 = *(const float4*)(col - 1024); *(float4*)(v1+4) = *(const float4*)(col - 1020); }
  *(float4*)v0 = *(const float4*)col; *(float4*)(v0+4) = *(const float4*)(col + 4);

  float cbv[8];
  *(float4*)cbv = *(const float4*)(cb + e0); *(float4*)(cbv+4) = *(const float4*)(cb + e0 + 4);

  float res[8];
#pragma unroll
  for (int j = 0; j < 8; ++j) {
    float4 cv = ((const float4*)cw)[e0 + j];
    float a = cbv[j];
    a = fmaf(cv.x, v3[j], a);
    a = fmaf(cv.y, v2[j], a);
    a = fmaf(cv.z, v1[j], a);
    a = fmaf(cv.w, v0[j], a);
    res[j] = a / (1.f + __expf(-a));
  }
  float4 r0 = {res[0], res[1], res[2], res[3]};
  float4 r1 = {res[4], res[5], res[6], res[7]};
  float* xcp = xc + (size_t)tok * EDIM + e0;
  *(float4*)xcp = r0; *(float4*)(xcp + 4) = r1;

  unsigned ub[4];
#pragma unroll
  for (int p = 0; p < 4; ++p)
    ub[p] = (unsigned)f2bf(res[2*p]) | ((unsigned)f2bf(res[2*p+1]) << 16);
  int kt = e0 >> 5, oct = (e0 >> 3) & 3;
  uint4 w4 = {ub[0], ub[1], ub[2], ub[3]};
  *(uint4*)(xcb + ((size_t)(kt * 4 + oct) * 1024 + tok) * 8) = w4;
}

// ---------------------------------------------------------------------------
// xproj_mfma: pure-register MFMA GEMM. 64-thr blocks, grid (64,1,2).
// ---------------------------------------------------------------------------
__global__ __launch_bounds__(64) void xproj_mfma(
    const unsigned short* __restrict__ xcbF, const unsigned short* __restrict__ xcbR,
    const unsigned short* __restrict__ Wxp, int layer,
    float* __restrict__ dbF, float* __restrict__ dbR)
{
  const int dir = blockIdx.z;
  const unsigned short* xcb = dir ? xcbR : xcbF;
  float* db = dir ? dbR : dbF;
  const int lane = threadIdx.x & 63;
  const int tok0 = blockIdx.x * 16;
  const unsigned short* wbase = Wxp + ((size_t)(dir * 4 + layer) * 3 * 16 * 64) * 8;
  f32x4 acc[3];
#pragma unroll
  for (int nt = 0; nt < 3; ++nt) acc[nt] = (f32x4){0.f, 0.f, 0.f, 0.f};
#pragma unroll
  for (int kt = 0; kt < 16; ++kt) {
    short8v af = *(const short8v*)(xcb + ((size_t)(kt * 4 + (lane >> 4)) * 1024 + tok0 + (lane & 15)) * 8);
#pragma unroll
    for (int nt = 0; nt < 3; ++nt) {
      short8v bf = *(const short8v*)(wbase + ((size_t)(nt * 16 + kt) * 64 + lane) * 8);
      acc[nt] = __builtin_amdgcn_mfma_f32_16x16x32_bf16(af, bf, acc[nt], 0, 0, 0);
    }
  }
#pragma unroll
  for (int nt = 0; nt < 3; ++nt)
#pragma unroll
    for (int r = 0; r < 4; ++r)
      db[(size_t)(tok0 + (lane >> 4) * 4 + r) * 48 + nt * 16 + (lane & 15)] = acc[nt][r];
}

// ---------------------------------------------------------------------------
// scan4_k: selective scan + gating. dt-projection+softplus and silu(z)
// computed in the PARALLEL staging phase (dtproj_k deleted). 16 lanes/(b,e).
// ---------------------------------------------------------------------------
__global__ __launch_bounds__(256) void scan4_k(
    const float* __restrict__ xzF, const float* __restrict__ xzR,
    const float* __restrict__ xcF, const float* __restrict__ xcR,
    const float* __restrict__ dbF, const float* __restrict__ dbR,
    const float* __restrict__ dwF, const float* __restrict__ dwR,
    const float* __restrict__ dtbF, const float* __restrict__ dtbR,
    const float* __restrict__ AlF, const float* __restrict__ AlR,
    const float* __restrict__ DpF, const float* __restrict__ DpR,
    unsigned short* __restrict__ yoF, unsigned short* __restrict__ yoR)
{
  const int dir = blockIdx.z;
  const float* xz = dir ? xzR : xzF;
  const float* xc = dir ? xcR : xcF;
  const float* db = dir ? dbR : dbF;
  const float* dw = dir ? dwR : dwF;
  const float* dtbv = dir ? dtbR : dtbF;
  const float* Al = dir ? AlR : AlF;
  const float* Dp = dir ? DpR : DpF;
  unsigned short* yo = dir ? yoR : yoF;

  __shared__ float sdb[FRAMES * 48];   // 24KB
  __shared__ float sxc[FRAMES * 16];
  __shared__ float sgz[FRAMES * 16];   // silu(z) precomputed
  __shared__ float sdl[FRAMES * 16];   // softplus(dt) precomputed
  const int b = blockIdx.x >> 5;
  const int e0 = (blockIdx.x & 31) << 4;
  const int t = threadIdx.x, g = t >> 4, n = t & 15;
  const int e = e0 + g;

  const float* dbp = db + (size_t)b * FRAMES * 48;
  for (int i = t; i < FRAMES * 48 / 4; i += 256)
    ((float4*)sdb)[i] = ((const float4*)dbp)[i];
  for (int i = t; i < FRAMES * 16; i += 256) {
    int l = i >> 4, c = i & 15;
    int ee = e0 + c;
    sxc[i] = xc[(size_t)(b * FRAMES + l) * EDIM + ee];
    float zz = xz[(size_t)(b * FRAMES + l) * 1024 + 512 + ee];
    sgz[i] = zz / (1.f + __expf(-zz));
    // fused dt-projection + softplus (from L2-hot global db row)
    const float* d = db + (size_t)(b * FRAMES + l) * 48;
    const float* w = dw + (size_t)ee * 16;
    float a = dtbv[ee];
#pragma unroll
    for (int q = 0; q < 4; ++q) {
      float4 dv = *(const float4*)(d + 4 * q);
      float4 wv = *(const float4*)(w + 4 * q);
      a = fmaf(dv.x, wv.x, a); a = fmaf(dv.y, wv.y, a);
      a = fmaf(dv.z, wv.z, a); a = fmaf(dv.w, wv.w, a);
    }
    sdl[i] = (a > 20.f) ? a : __logf(1.f + __expf(a));
  }
  float An = -expf(Al[e * NSTATE + n]);
  float Dv = Dp[e];
  float h = 0.f;
  unsigned short* yp = yo + ((size_t)((e >> 5) * 4 + ((e >> 3) & 3)) * 1024 + b * FRAMES) * 8 + (e & 7);
  __syncthreads();

#pragma unroll 1
  for (int l = 0; l < FRAMES; ++l) {
    float dlt = sdl[l * 16 + g];
    float xcv = sxc[l * 16 + g];
    float Bn = sdb[l * 48 + 16 + n];
    float Cn = sdb[l * 48 + 32 + n];
    float dA = __expf(dlt * An);
    h = fmaf(dA, h, dlt * xcv * Bn);
    float part = h * Cn;
    part += __shfl_xor(part, 1, 16);
    part += __shfl_xor(part, 2, 16);
    part += __shfl_xor(part, 4, 16);
    part += __shfl_xor(part, 8, 16);
    if (n == 0) {
      float a2 = fmaf(Dv, xcv, part);
      yp[(size_t)l * 8] = f2bf(a2 * sgz[l * 16 + g]);
    }
  }
}

// ---------------------------------------------------------------------------
// outproj_mfma: zero-LDS bf16 MFMA GEMM + residual add.
// ---------------------------------------------------------------------------
__global__ __launch_bounds__(256) void outproj_mfma(
    const unsigned short* __restrict__ yoF, const unsigned short* __restrict__ yoR,
    const unsigned short* __restrict__ Wop, int layer,
    float* __restrict__ xF, float* __restrict__ xR)
{
  const int dir = blockIdx.z;
  const unsigned short* yo = dir ? yoR : yoF;
  float* xx = dir ? xR : xF;
  const int t = threadIdx.x, lane = t & 63, w = t >> 6;
  const int m0 = blockIdx.x * 32, n0 = blockIdx.y * 64;
  const int ntile = blockIdx.y * 4 + w;
  const unsigned short* wb = Wop + (((size_t)(dir * 4 + layer) * 256 + ntile * 16) * 64 + lane) * 8;
  f32x4 acc[2];
  acc[0] = (f32x4){0.f, 0.f, 0.f, 0.f};
  acc[1] = (f32x4){0.f, 0.f, 0.f, 0.f};
#pragma unroll
  for (int kt = 0; kt < 16; ++kt) {
    short8v bf = *(const short8v*)(wb + (size_t)kt * 64 * 8);
#pragma unroll
    for (int mt = 0; mt < 2; ++mt) {
      short8v af = *(const short8v*)(yo + ((size_t)(kt * 4 + (lane >> 4)) * 1024 + m0 + mt * 16 + (lane & 15)) * 8);
      acc[mt] = __builtin_amdgcn_mfma_f32_16x16x32_bf16(af, bf, acc[mt], 0, 0, 0);
    }
  }
#pragma unroll
  for (int mt = 0; mt < 2; ++mt)
#pragma unroll
    for (int r = 0; r < 4; ++r) {
      size_t ci = (size_t)(m0 + mt * 16 + (lane >> 4) * 4 + r) * DD + n0 + w * 16 + (lane & 15);
      xx[ci] += acc[mt][r];
    }
}

__global__ __launch_bounds__(256) void head_k(
    const float* __restrict__ xf, const float* __restrict__ xr,
    const float* __restrict__ fcw, const float* __restrict__ fcb,
    const float* __restrict__ fc2w, const float* __restrict__ fc2b,
    float* __restrict__ out)
{
  int b = blockIdx.x;
  __shared__ float xl[2 * DD];
  __shared__ float h[DD];
  __shared__ float hp[4];
  int t = threadIdx.x;
  xl[t]      = xf[(size_t)(b * FRAMES + FRAMES - 1) * DD + t];
  xl[DD + t] = xr[(size_t)(b * FRAMES + 0) * DD + t];
  __syncthreads();
  float acc = fcb[t];
  for (int k = 0; k < 2 * DD; ++k) acc = fmaf(xl[k], fcw[(size_t)t * 2 * DD + k], acc);
  h[t] = acc;
  __syncthreads();
  {
    int c = t >> 7, k = t & 127;
    float p = h[k] * fc2w[c * DD + k] + h[k + 128] * fc2w[c * DD + k + 128];
#pragma unroll
    for (int off = 32; off; off >>= 1) p += __shfl_xor(p, off, 64);
    if ((t & 63) == 0) hp[t >> 6] = p;
  }
  __syncthreads();
  if (t < 2) out[b * 2 + t] = hp[2 * t] + hp[2 * t + 1] + fc2b[t];
}

// ---------------------------------------------------------------------------
extern "C" void kernel_launch(void* const* d_in, const int* in_sizes, int n_in,
                              void* d_out, int out_size, void* d_ws, size_t ws_size,
                              hipStream_t stream) {
  const float* video = (const float*)d_in[0];
  const float* audio = (const float*)d_in[1];
  const float* c1w = (const float*)d_in[2];
  const float* c1b = (const float*)d_in[3];
  const float* c2w = (const float*)d_in[4];
  const float* c2b = (const float*)d_in[5];
  const float* fcw = (const float*)d_in[6];
  const float* fcb = (const float*)d_in[7];
  const float* Wf[10]; const float* Wb_[10];
  for (int i = 0; i < 10; ++i) { Wf[i] = (const float*)d_in[8+i]; Wb_[i] = (const float*)d_in[18+i]; }
  const float* fc_w  = (const float*)d_in[28];
  const float* fc_b  = (const float*)d_in[29];
  const float* fc2_w = (const float*)d_in[30];
  const float* fc2_b = (const float*)d_in[31];
  float* out = (float*)d_out;

  // workspace (float slots)
  float* ws   = (float*)d_ws;
  float* feat = ws;                       // 65536
  float* xf   = feat + 65536;             // 262144
  float* xr   = xf   + 262144;            // 262144
  float* xzF  = xr   + 262144;            // 1048576
  float* xzR  = xzF  + 1048576;           // 1048576
  float* xcF  = xzR  + 1048576;           // 524288
  float* xcR  = xcF  + 524288;            // 524288
  float* dbF  = xcR  + 524288;            // 49152
  float* dbR  = dbF  + 49152;             // 49152
  unsigned short* yoF = (unsigned short*)(dbR + 49152);     // 524288 sh
  unsigned short* yoR = yoF + 524288;
  unsigned short* X1  = yoR + 524288;                        // 33554432 sh
  unsigned short* Wbp = X1 + 33554432;                       // 18432 sh
  unsigned short* Wip = Wbp + 18432;                         // 2097152 sh
  unsigned short* Wop = Wip + 2097152;                       // 1048576 sh
  unsigned short* Wxp = Wop + 1048576;                       // 196608 sh
  unsigned short* xcbF = Wxp + 196608;                       // 524288 sh
  unsigned short* xcbR = xcbF + 524288;                      // 524288 sh

  // 1. packs + CNN
  pack_w2<<<dim3(9), 256, 0, stream>>>(c2w, Wbp);
  pack_mamba<<<dim3(1632), 256, 0, stream>>>(Wf[1], Wb_[1], Wf[9], Wb_[9], Wf[4], Wb_[4],
                                             Wip, Wop, Wxp);
  conv1_k<<<dim3(TOK), 256, 0, stream>>>(video, c1w, c1b, X1);
  conv2_k<<<dim3(TOK), 256, (size_t)(X_LDS_BYTES + 1024), stream>>>(X1, Wbp, c2b, feat);

  // 2. cnn fc (writes xf+xr directly) + audio fill (independent)
  fcgemm_k<<<dim3(16, 4), 256, 0, stream>>>(feat, fcw, fcb, xf, xr);
  audio_k<<<dim3((BATCH*FRAMES*NM + 255)/256), 256, 0, stream>>>(audio, xf, xr);

  // 3. bi-Mamba (5 kernels per layer)
  for (int l = 0; l < NLAYER; ++l) {
    const float* nwF  = Wf[0] + l*DD;              const float* nwR  = Wb_[0] + l*DD;
    const float* cwF_ = Wf[2] + l*EDIM*4;          const float* cwR_ = Wb_[2] + l*EDIM*4;
    const float* cbF_ = Wf[3] + l*EDIM;            const float* cbR_ = Wb_[3] + l*EDIM;
    const float* dwF  = Wf[5] + l*EDIM*DTRANK;     const float* dwR  = Wb_[5] + l*EDIM*DTRANK;
    const float* dtbF = Wf[6] + l*EDIM;            const float* dtbR = Wb_[6] + l*EDIM;
    const float* AlF  = Wf[7] + l*EDIM*NSTATE;     const float* AlR  = Wb_[7] + l*EDIM*NSTATE;
    const float* DpF  = Wf[8] + l*EDIM;            const float* DpR  = Wb_[8] + l*EDIM;

    inproj_mfma3<<<dim3(64, 4, 2), 256, 0, stream>>>(xf, xr, nwF, nwR, Wip, l, xzF, xzR);
    convsilu2_k<<<dim3(256, 1, 2), 256, 0, stream>>>(xzF, xzR, cwF_, cwR_, cbF_, cbR_,
                                                     xcF, xcR, xcbF, xcbR);
    xproj_mfma<<<dim3(64, 1, 2), 64, 0, stream>>>(xcbF, xcbR, Wxp, l, dbF, dbR);
    scan4_k<<<dim3(256, 1, 2), 256, 0, stream>>>(xzF, xzR, xcF, xcR, dbF, dbR, dwF, dwR,
                                                 dtbF, dtbR, AlF, AlR, DpF, DpR, yoF, yoR);
    outproj_mfma<<<dim3(32, 4, 2), 256, 0, stream>>>(yoF, yoR, Wop, l, xf, xr);
  }

  // 4. head
  head_k<<<dim3(BATCH), 256, 0, stream>>>(xf, xr, fc_w, fc_b, fc2_w, fc2_b, out);
}

// Round 9
// 385.170 us; speedup vs baseline: 3.3223x; 1.1966x over previous
//
#include <hip/hip_runtime.h>
#include <hip/hip_bf16.h>
#include <cstdint>
#include <cstddef>

#define BATCH 8
#define FRAMES 128
#define TOK (BATCH*FRAMES)   // 1024
#define NM 60
#define VF 196
#define DD 256
#define EDIM 512
#define NSTATE 16
#define DTRANK 16
#define NLAYER 4

typedef __attribute__((ext_vector_type(8))) short short8v;
typedef __attribute__((ext_vector_type(4))) float f32x4;

__device__ __forceinline__ unsigned short f2bf(float f) {
  unsigned x = __float_as_uint(f);
  unsigned r = (x + 0x7FFFu + ((x >> 16) & 1u)) >> 16;
  return (unsigned short)r;
}

// ---------------------------------------------------------------------------
// pack_w2: W2 -> conv2 A-frags; also W1 (32,3,3,3) -> conv1 A-frags (K=32,
// k=ic*9+tap, k>=27 zero) and grid covers both. ids [0,2304): w2; [2304,2432): w1.
// ---------------------------------------------------------------------------
__global__ void pack_w2(const float* __restrict__ w2, unsigned short* __restrict__ Wb,
                        const float* __restrict__ w1, unsigned short* __restrict__ Wb1) {
  int id = blockIdx.x * 256 + threadIdx.x;
  if (id < 9 * 4 * 64) {
    int lane = id & 63;
    int mt = (id >> 6) & 3;
    int sh = id >> 8;
    int dy = sh / 3, dx = sh % 3;
    int oc = mt * 16 + (lane & 15);
    int ic0 = (lane >> 4) * 8;
    unsigned u[4];
#pragma unroll
    for (int p = 0; p < 4; ++p) {
      unsigned short lo = f2bf(w2[((oc * 32 + ic0 + 2 * p) * 3 + dy) * 3 + dx]);
      unsigned short hi = f2bf(w2[((oc * 32 + ic0 + 2 * p + 1) * 3 + dy) * 3 + dx]);
      u[p] = (unsigned)lo | ((unsigned)hi << 16);
    }
    uint4 v = {u[0], u[1], u[2], u[3]};
    *(uint4*)(Wb + (size_t)id * 8) = v;
  } else if (id < 9 * 4 * 64 + 128) {
    int id2 = id - 9 * 4 * 64;        // 0..127
    int mt = id2 >> 6, lane = id2 & 63;
    int oc = mt * 16 + (lane & 15);
    int ko = lane >> 4;
    unsigned u[4];
#pragma unroll
    for (int p = 0; p < 4; ++p) {
      int k0 = ko * 8 + 2 * p, k1 = k0 + 1;
      unsigned short lo = (k0 < 27) ? f2bf(w1[oc * 27 + k0]) : 0;
      unsigned short hi = (k1 < 27) ? f2bf(w1[oc * 27 + k1]) : 0;
      u[p] = (unsigned)lo | ((unsigned)hi << 16);
    }
    uint4 v = {u[0], u[1], u[2], u[3]};
    *(uint4*)(Wb1 + (size_t)id2 * 8) = v;
  }
}

// ---------------------------------------------------------------------------
// pack_mamba: in_proj / out_proj / x_proj weights -> bf16 MFMA B-fragment order
// ---------------------------------------------------------------------------
__global__ void pack_mamba(const float* __restrict__ ipF, const float* __restrict__ ipR,
                           const float* __restrict__ opF, const float* __restrict__ opR,
                           const float* __restrict__ xpF, const float* __restrict__ xpR,
                           unsigned short* __restrict__ Wip, unsigned short* __restrict__ Wop,
                           unsigned short* __restrict__ Wxp) {
  int id = blockIdx.x * 256 + threadIdx.x;
  if (id < 262144) {                     // in_proj
    int dl = id >> 15, r = id & 32767;
    int ntile = r >> 9, kt = (r >> 6) & 7, lane = r & 63;
    int dir = dl >> 2, layer = dl & 3;
    const float* src = (dir ? ipR : ipF) + (size_t)layer * 1024 * 256
                       + (size_t)(ntile * 16 + (lane & 15)) * 256 + kt * 32 + (lane >> 4) * 8;
    unsigned u[4];
#pragma unroll
    for (int p = 0; p < 4; ++p)
      u[p] = (unsigned)f2bf(src[2 * p]) | ((unsigned)f2bf(src[2 * p + 1]) << 16);
    uint4 v = {u[0], u[1], u[2], u[3]};
    *(uint4*)(Wip + (size_t)id * 8) = v;
  } else if (id < 262144 + 131072) {     // out_proj
    int id2 = id - 262144;
    int dl = id2 >> 14, rr = id2 & 16383;
    int ntile = rr >> 10, kt = (rr >> 6) & 15, lane = rr & 63;
    int dir = dl >> 2, layer = dl & 3;
    const float* src = (dir ? opR : opF) + (size_t)layer * 256 * 512
                       + (size_t)(ntile * 16 + (lane & 15)) * 512 + kt * 32 + (lane >> 4) * 8;
    unsigned u[4];
#pragma unroll
    for (int p = 0; p < 4; ++p)
      u[p] = (unsigned)f2bf(src[2 * p]) | ((unsigned)f2bf(src[2 * p + 1]) << 16);
    uint4 v = {u[0], u[1], u[2], u[3]};
    *(uint4*)(Wop + (size_t)id2 * 8) = v;
  } else if (id < 262144 + 131072 + 24576) {  // x_proj (48 x 512)
    int id3 = id - 262144 - 131072;
    int dl = id3 / 3072, rr = id3 % 3072;
    int ntile = rr >> 10, kt = (rr >> 6) & 15, lane = rr & 63;
    int dir = dl >> 2, layer = dl & 3;
    const float* src = (dir ? xpR : xpF) + (size_t)layer * 48 * 512
                       + (size_t)(ntile * 16 + (lane & 15)) * 512 + kt * 32 + (lane >> 4) * 8;
    unsigned u[4];
#pragma unroll
    for (int p = 0; p < 4; ++p)
      u[p] = (unsigned)f2bf(src[2 * p]) | ((unsigned)f2bf(src[2 * p + 1]) << 16);
    uint4 v = {u[0], u[1], u[2], u[3]};
    *(uint4*)(Wxp + (size_t)id3 * 8) = v;
  }
}

// ---------------------------------------------------------------------------
// conv1_mfma: conv(3->32,3x3,SAME)+bias+relu+maxpool2 as ONE K=32 MFMA per
// 16-pixel group (K = 3ic x 9taps, padded; A has zeros for k>=27).
// LDS: image as bf16, zero borders, pitch 68, data cols 4..67, rows 1..64.
// Per wave: 16 rows (8 row-pairs) x 64 cols. Output X1 in conv2's layout.
// ---------------------------------------------------------------------------
#define C1RS 68
#define C1ICS (66*68)      // 4488
__global__ __launch_bounds__(256) void conv1_mfma(
    const float* __restrict__ video, const unsigned short* __restrict__ Wb1,
    const float* __restrict__ b1, unsigned short* __restrict__ X1)
{
  __shared__ unsigned short ldsu[3 * C1ICS + 96];   // 27120 B, tail zeroed
  const int img = blockIdx.x, t = threadIdx.x;
  const float* vin = video + (size_t)img * 12288;
  const int lane = t & 63, wv = t >> 6;
  const int col = lane & 15, ko = lane >> 4;

  // zero all (borders + tail), then stage interior as bf16
  for (int i = t; i < (3 * C1ICS + 96) / 2; i += 256) ((unsigned*)ldsu)[i] = 0;
  __syncthreads();
#pragma unroll
  for (int i = 0; i < 12; ++i) {
    int c = i * 256 + t;               // 3072 float4 chunks
    int ic = c >> 10, rem = c & 1023, gy = rem >> 4, c4 = rem & 15;
    float4 v = *(const float4*)(vin + ic * 4096 + gy * 64 + c4 * 4);
    unsigned lo = (unsigned)f2bf(v.x) | ((unsigned)f2bf(v.y) << 16);
    unsigned hi = (unsigned)f2bf(v.z) | ((unsigned)f2bf(v.w) << 16);
    int di = ic * C1ICS + (gy + 1) * C1RS + 4 + c4 * 4;   // mult of 4 -> 8B aligned
    *(uint2*)(ldsu + di) = (uint2){lo, hi};
  }

  // A-fragments + bias (registers, whole kernel)
  short8v A0 = *(const short8v*)(Wb1 + (size_t)(0 * 64 + lane) * 8);
  short8v A1 = *(const short8v*)(Wb1 + (size_t)(1 * 64 + lane) * 8);
  float bia[2][4];
#pragma unroll
  for (int mt = 0; mt < 2; ++mt)
#pragma unroll
    for (int r = 0; r < 4; ++r) bia[mt][r] = b1[mt * 16 + ko * 4 + r];

  // per-lane tap offsets for the 8 k-values of this lane's octet
  int offs[8];
#pragma unroll
  for (int j = 0; j < 8; ++j) {
    int k = ko * 8 + j;
    int o = 0;
    if (k < 27) {
      int ic = k / 9, tap = k - ic * 9;
      int dy = tap / 3, dx = tap - dy * 3;
      o = ic * C1ICS + dy * C1RS + dx + 3;   // OFF-1 = 3
    }
    offs[j] = o;
  }
  __syncthreads();

  f32x4 z4 = {0.f, 0.f, 0.f, 0.f};
#pragma unroll 1
  for (int rp = 0; rp < 8; ++rp) {
    const int y0 = wv * 16 + rp * 2;
#pragma unroll
    for (int xg = 0; xg < 4; ++xg) {
      const int bse = y0 * C1RS + xg * 16 + col;
      short8v vb0, vb1;
#pragma unroll
      for (int j = 0; j < 8; ++j) {
        vb0[j] = (short)ldsu[bse + offs[j]];
        vb1[j] = (short)ldsu[bse + C1RS + offs[j]];
      }
      f32x4 c00 = __builtin_amdgcn_mfma_f32_16x16x32_bf16(A0, vb0, z4, 0, 0, 0);
      f32x4 c10 = __builtin_amdgcn_mfma_f32_16x16x32_bf16(A1, vb0, z4, 0, 0, 0);
      f32x4 c01 = __builtin_amdgcn_mfma_f32_16x16x32_bf16(A0, vb1, z4, 0, 0, 0);
      f32x4 c11 = __builtin_amdgcn_mfma_f32_16x16x32_bf16(A1, vb1, z4, 0, 0, 0);
      const int py = wv * 8 + rp;
      const int pxp = xg * 8 + (col >> 1);
#pragma unroll
      for (int mt = 0; mt < 2; ++mt) {
        f32x4 ca = mt ? c10 : c00;
        f32x4 cb = mt ? c11 : c01;
        unsigned pk[2];
#pragma unroll
        for (int r = 0; r < 4; ++r) {
          float va = fmaxf(ca[r] + bia[mt][r], 0.f);
          float vb = fmaxf(cb[r] + bia[mt][r], 0.f);
          float v = fmaxf(va, vb);
          v = fmaxf(v, __shfl_xor(v, 1, 64));      // pool across x-pairs
          unsigned short u = f2bf(v);
          if ((r & 1) == 0) pk[r >> 1] = (unsigned)u;
          else              pk[r >> 1] |= ((unsigned)u << 16);
        }
        if ((col & 1) == 0) {
          uint2 o = {pk[0], pk[1]};
          *(uint2*)(X1 + ((size_t)(img * 1024 + py * 32 + pxp) * 32 + mt * 16 + ko * 4)) = o;
        }
      }
    }
  }
}

// ---------------------------------------------------------------------------
// conv2_k: unchanged
// ---------------------------------------------------------------------------
#define X_LDS_BYTES (4 * 1156 * 16)
#define OCT_STRIDE  (1156 * 16)
__global__ __launch_bounds__(256) void conv2_k(
    const unsigned short* __restrict__ X1, const unsigned short* __restrict__ Wb,
    const float* __restrict__ b2, float* __restrict__ feat)
{
  extern __shared__ char sm[];
  float* part = (float*)(sm + X_LDS_BYTES);
  const int img = blockIdx.x, t = threadIdx.x;
  const int lane = t & 63, wv = t >> 6;
  const int kg = lane >> 4, l15 = lane & 15;

  for (int j = t; j < 1156; j += 256) {
    int r = j / 34, cc = j - r * 34;
    if (r == 0 || r == 33 || cc == 0 || cc == 33) {
      uint4 z = {0, 0, 0, 0};
#pragma unroll
      for (int oct = 0; oct < 4; ++oct)
        *(uint4*)(sm + oct * OCT_STRIDE + j * 16) = z;
    }
  }
  const uint4* src = (const uint4*)(X1 + (size_t)img * 32768);
#pragma unroll 4
  for (int i = 0; i < 16; ++i) {
    int c = i * 256 + t;
    uint4 v = src[c];
    int oct = c & 3, P = c >> 2;
    int y = P >> 5, x = P & 31;
    *(uint4*)(sm + oct * OCT_STRIDE + ((y + 1) * 34 + (x + 1)) * 16) = v;
  }
  __syncthreads();

  float bia[4][4];
#pragma unroll
  for (int mt = 0; mt < 4; ++mt)
#pragma unroll
    for (int r = 0; r < 4; ++r) bia[mt][r] = b2[mt * 16 + kg * 4 + r];

  float msum[4][4];
#pragma unroll
  for (int mt = 0; mt < 4; ++mt)
#pragma unroll
    for (int r = 0; r < 4; ++r) msum[mt][r] = 0.f;

#pragma unroll 1
  for (int pass = 0; pass < 2; ++pass) {
    f32x4 acc[4][8];
#pragma unroll
    for (int mt = 0; mt < 4; ++mt)
#pragma unroll
      for (int q = 0; q < 8; ++q) acc[mt][q] = (f32x4){0.f, 0.f, 0.f, 0.f};
    int Pq[8];
#pragma unroll
    for (int q = 0; q < 8; ++q) {
      int p = (wv * 16 + pass * 8 + q) * 16 + l15;
      int y = p >> 5, x = p & 31;
      Pq[q] = y * 34 + x;
    }
#pragma unroll
    for (int sh = 0; sh < 9; ++sh) {
      const int dy = sh / 3, dx = sh % 3;
      const int shoff = (dy * 34 + dx) * 16;
      short8v Af[4];
#pragma unroll
      for (int mt = 0; mt < 4; ++mt)
        Af[mt] = *(const short8v*)(Wb + ((size_t)(sh * 4 + mt) * 64 + lane) * 8);
#pragma unroll
      for (int q = 0; q < 8; ++q) {
        short8v Bf = *(const short8v*)(sm + kg * OCT_STRIDE + Pq[q] * 16 + shoff);
#pragma unroll
        for (int mt = 0; mt < 4; ++mt)
          acc[mt][q] = __builtin_amdgcn_mfma_f32_16x16x32_bf16(Af[mt], Bf, acc[mt][q], 0, 0, 0);
      }
    }
#pragma unroll
    for (int mt = 0; mt < 4; ++mt) {
#pragma unroll
      for (int pr = 0; pr < 4; ++pr) {
        int qa = (pr & 1) + (pr >> 1) * 4;
        int qb = qa + 2;
#pragma unroll
        for (int r = 0; r < 4; ++r) {
          float va = fmaxf(acc[mt][qa][r] + bia[mt][r], 0.f);
          float vb = fmaxf(acc[mt][qb][r] + bia[mt][r], 0.f);
          float v = fmaxf(va, vb);
          v = fmaxf(v, __shfl_xor(v, 1, 64));
          msum[mt][r] += v;
        }
      }
    }
  }
#pragma unroll
  for (int mt = 0; mt < 4; ++mt)
#pragma unroll
    for (int r = 0; r < 4; ++r) {
      float v = msum[mt][r];
      v += __shfl_xor(v, 1, 64);
      v += __shfl_xor(v, 2, 64);
      v += __shfl_xor(v, 4, 64);
      v += __shfl_xor(v, 8, 64);
      if (l15 == 0) part[wv * 64 + mt * 16 + kg * 4 + r] = v * 0.5f;
    }
  __syncthreads();
  if (t < 64)
    feat[(size_t)img * 64 + t] =
        (part[t] + part[64 + t] + part[128 + t] + part[192 + t]) * (1.f / 256.f);
}

// ---------------------------------------------------------------------------
// fcgemm_k: feat(1024,64) @ fcw(196,64)^T + fcb -> writes xf AND reversed xr
// ---------------------------------------------------------------------------
__global__ __launch_bounds__(256) void fcgemm_k(
    const float* __restrict__ A, const float* __restrict__ B,
    const float* __restrict__ bias, float* __restrict__ xf, float* __restrict__ xr)
{
  __shared__ float sA[16][68];
  __shared__ float sB[16][68];
  const int t = threadIdx.x;
  const int m0 = blockIdx.x * 64;
  const int n0 = blockIdx.y * 64;
  const int tx = t & 15, ty = t >> 4;
  const int lk = t & 15, lr = t >> 4;
  float acc[4][4] = {};
  for (int k0 = 0; k0 < 64; k0 += 16) {
#pragma unroll
    for (int rr = 0; rr < 4; ++rr) {
      int m = m0 + lr + rr * 16;
      sA[lk][lr + rr * 16] = A[(size_t)m * 64 + k0 + lk];
      int n = n0 + lr + rr * 16;
      sB[lk][lr + rr * 16] = (n < VF) ? B[(size_t)n * 64 + k0 + lk] : 0.f;
    }
    __syncthreads();
#pragma unroll
    for (int kk = 0; kk < 16; ++kk) {
      float a0 = sA[kk][ty*4+0], a1 = sA[kk][ty*4+1], a2 = sA[kk][ty*4+2], a3 = sA[kk][ty*4+3];
      float b0 = sB[kk][tx*4+0], b1 = sB[kk][tx*4+1], b2 = sB[kk][tx*4+2], b3 = sB[kk][tx*4+3];
      acc[0][0]=fmaf(a0,b0,acc[0][0]); acc[0][1]=fmaf(a0,b1,acc[0][1]); acc[0][2]=fmaf(a0,b2,acc[0][2]); acc[0][3]=fmaf(a0,b3,acc[0][3]);
      acc[1][0]=fmaf(a1,b0,acc[1][0]); acc[1][1]=fmaf(a1,b1,acc[1][1]); acc[1][2]=fmaf(a1,b2,acc[1][2]); acc[1][3]=fmaf(a1,b3,acc[1][3]);
      acc[2][0]=fmaf(a2,b0,acc[2][0]); acc[2][1]=fmaf(a2,b1,acc[2][1]); acc[2][2]=fmaf(a2,b2,acc[2][2]); acc[2][3]=fmaf(a2,b3,acc[2][3]);
      acc[3][0]=fmaf(a3,b0,acc[3][0]); acc[3][1]=fmaf(a3,b1,acc[3][1]); acc[3][2]=fmaf(a3,b2,acc[3][2]); acc[3][3]=fmaf(a3,b3,acc[3][3]);
    }
    __syncthreads();
  }
#pragma unroll
  for (int i = 0; i < 4; ++i) {
    int m = m0 + ty * 4 + i;
    int b = m >> 7, l = m & 127;
    int mr = (b << 7) + (127 - l);
#pragma unroll
    for (int j = 0; j < 4; ++j) {
      int n = n0 + tx * 4 + j;
      if (n >= VF) continue;
      float v = acc[i][j] + bias[n];
      xf[(size_t)m * DD + n] = v;
      xr[(size_t)mr * DD + n] = v;
    }
  }
}

// audio_k: audio -> xf/xr cols [196,256)
__global__ void audio_k(const float* __restrict__ audio,
                        float* __restrict__ xf, float* __restrict__ xr) {
  int i = blockIdx.x * 256 + threadIdx.x;
  if (i >= BATCH * FRAMES * NM) return;
  int j = i % NM; int l = (i / NM) % FRAMES; int b = i / (NM * FRAMES);
  float v = audio[i];
  xf[(size_t)(b * FRAMES + l) * DD + VF + j] = v;
  xr[(size_t)(b * FRAMES + (FRAMES - 1 - l)) * DD + VF + j] = v;
}

// ---------------------------------------------------------------------------
// inproj_mfma3: fused rmsnorm (in-block, 16 tokens) + bf16 MFMA GEMM.
// ---------------------------------------------------------------------------
__global__ __launch_bounds__(256) void inproj_mfma3(
    const float* __restrict__ xF, const float* __restrict__ xR,
    const float* __restrict__ nwF, const float* __restrict__ nwR,
    const unsigned short* __restrict__ Wip, int layer,
    float* __restrict__ xzF, float* __restrict__ xzR)
{
  const int dir = blockIdx.z;
  const float* x = dir ? xR : xF;
  const float* nw = dir ? nwR : nwF;
  float* xz = dir ? xzR : xzF;
  __shared__ unsigned short sa[32 * 16 * 8];   // 8KB
  const int t = threadIdx.x;
  const int tok0 = blockIdx.x * 16;
  {
    const int tk = t >> 4, l16 = t & 15;
    const float* row = x + (size_t)(tok0 + tk) * DD + l16 * 16;
    float v[16];
    float ss = 0.f;
#pragma unroll
    for (int i = 0; i < 4; ++i) {
      float4 f = ((const float4*)row)[i];
      v[4*i] = f.x; v[4*i+1] = f.y; v[4*i+2] = f.z; v[4*i+3] = f.w;
      ss += f.x*f.x + f.y*f.y + f.z*f.z + f.w*f.w;
    }
    ss += __shfl_xor(ss, 1, 16);
    ss += __shfl_xor(ss, 2, 16);
    ss += __shfl_xor(ss, 4, 16);
    ss += __shfl_xor(ss, 8, 16);
    float scale = rsqrtf(ss * (1.f / DD) + 1e-5f);
    const float* nwp = nw + l16 * 16;
#pragma unroll
    for (int hh = 0; hh < 2; ++hh) {
      unsigned ub[4];
#pragma unroll
      for (int p = 0; p < 4; ++p) {
        unsigned short lo = f2bf(v[hh*8 + 2*p]     * scale * nwp[hh*8 + 2*p]);
        unsigned short hi = f2bf(v[hh*8 + 2*p + 1] * scale * nwp[hh*8 + 2*p + 1]);
        ub[p] = (unsigned)lo | ((unsigned)hi << 16);
      }
      int k0 = l16 * 16 + hh * 8;
      int kt = k0 >> 5, oct = (k0 >> 3) & 3;
      uint4 w4 = {ub[0], ub[1], ub[2], ub[3]};
      *(uint4*)(sa + ((size_t)(kt * 4 + oct) * 16 + tk) * 8) = w4;
    }
  }
  __syncthreads();
  const int lane = t & 63, w = t >> 6;
  short8v af[8];
#pragma unroll
  for (int kt = 0; kt < 8; ++kt)
    af[kt] = *(const short8v*)(sa + ((size_t)(kt * 4 + (lane >> 4)) * 16 + (lane & 15)) * 8);
#pragma unroll
  for (int ns = 0; ns < 4; ++ns) {
    const int ntile = blockIdx.y * 16 + w * 4 + ns;
    const unsigned short* wb = Wip + (((size_t)(dir * 4 + layer) * 512 + ntile * 8) * 64 + lane) * 8;
    f32x4 acc = (f32x4){0.f, 0.f, 0.f, 0.f};
#pragma unroll
    for (int kt = 0; kt < 8; ++kt) {
      short8v bf = *(const short8v*)(wb + (size_t)kt * 64 * 8);
      acc = __builtin_amdgcn_mfma_f32_16x16x32_bf16(af[kt], bf, acc, 0, 0, 0);
    }
#pragma unroll
    for (int r = 0; r < 4; ++r)
      xz[(size_t)(tok0 + (lane >> 4) * 4 + r) * 1024 + ntile * 16 + (lane & 15)] = acc[r];
  }
}

// ---------------------------------------------------------------------------
// convsilu2_k: mass-parallel causal-conv4 + silu
// ---------------------------------------------------------------------------
__global__ __launch_bounds__(256) void convsilu2_k(
    const float* __restrict__ xzF, const float* __restrict__ xzR,
    const float* __restrict__ cwF, const float* __restrict__ cwR,
    const float* __restrict__ cbF, const float* __restrict__ cbR,
    float* __restrict__ xcF, float* __restrict__ xcR,
    unsigned short* __restrict__ xcbF, unsigned short* __restrict__ xcbR)
{
  const int dir = blockIdx.z;
  const float* xz = dir ? xzR : xzF;
  const float* cw = dir ? cwR : cwF;
  const float* cb = dir ? cbR : cbF;
  float* xc = dir ? xcR : xcF;
  unsigned short* xcb = dir ? xcbR : xcbF;

  int i = blockIdx.x * 256 + threadIdx.x;
  int tok = i >> 6;
  int e0 = (i & 63) << 3;
  int l = tok & 127;
  const float* col = xz + (size_t)tok * 1024 + e0;

  float v3[8] = {}, v2[8] = {}, v1[8] = {}, v0[8];
  if (l >= 3) { *(float4*)v3 = *(const float4*)(col - 3072); *(float4*)(v3+4) = *(const float4*)(col - 3068); }
  if (l >= 2) { *(float4*)v2 = *(const float4*)(col - 2048); *(float4*)(v2+4) = *(const float4*)(col - 2044); }
  if (l >= 1) { *(float4*)v1 = *(const float4*)(col - 1024); *(float4*)(v1+4) = *(const float4*)(col - 1020); }
  *(float4*)v0 = *(const float4*)col; *(float4*)(v0+4) = *(const float4*)(col + 4);

  float cbv[8];
  *(float4*)cbv = *(const float4*)(cb + e0); *(float4*)(cbv+4) = *(const float4*)(cb + e0 + 4);

  float res[8];
#pragma unroll
  for (int j = 0; j < 8; ++j) {
    float4 cv = ((const float4*)cw)[e0 + j];
    float a = cbv[j];
    a = fmaf(cv.x, v3[j], a);
    a = fmaf(cv.y, v2[j], a);
    a = fmaf(cv.z, v1[j], a);
    a = fmaf(cv.w, v0[j], a);
    res[j] = a / (1.f + __expf(-a));
  }
  float4 r0 = {res[0], res[1], res[2], res[3]};
  float4 r1 = {res[4], res[5], res[6], res[7]};
  float* xcp = xc + (size_t)tok * EDIM + e0;
  *(float4*)xcp = r0; *(float4*)(xcp + 4) = r1;

  unsigned ub[4];
#pragma unroll
  for (int p = 0; p < 4; ++p)
    ub[p] = (unsigned)f2bf(res[2*p]) | ((unsigned)f2bf(res[2*p+1]) << 16);
  int kt = e0 >> 5, oct = (e0 >> 3) & 3;
  uint4 w4 = {ub[0], ub[1], ub[2], ub[3]};
  *(uint4*)(xcb + ((size_t)(kt * 4 + oct) * 1024 + tok) * 8) = w4;
}

// ---------------------------------------------------------------------------
// xproj_mfma: pure-register MFMA GEMM. 64-thr blocks, grid (64,1,2).
// ---------------------------------------------------------------------------
__global__ __launch_bounds__(64) void xproj_mfma(
    const unsigned short* __restrict__ xcbF, const unsigned short* __restrict__ xcbR,
    const unsigned short* __restrict__ Wxp, int layer,
    float* __restrict__ dbF, float* __restrict__ dbR)
{
  const int dir = blockIdx.z;
  const unsigned short* xcb = dir ? xcbR : xcbF;
  float* db = dir ? dbR : dbF;
  const int lane = threadIdx.x & 63;
  const int tok0 = blockIdx.x * 16;
  const unsigned short* wbase = Wxp + ((size_t)(dir * 4 + layer) * 3 * 16 * 64) * 8;
  f32x4 acc[3];
#pragma unroll
  for (int nt = 0; nt < 3; ++nt) acc[nt] = (f32x4){0.f, 0.f, 0.f, 0.f};
#pragma unroll
  for (int kt = 0; kt < 16; ++kt) {
    short8v af = *(const short8v*)(xcb + ((size_t)(kt * 4 + (lane >> 4)) * 1024 + tok0 + (lane & 15)) * 8);
#pragma unroll
    for (int nt = 0; nt < 3; ++nt) {
      short8v bf = *(const short8v*)(wbase + ((size_t)(nt * 16 + kt) * 64 + lane) * 8);
      acc[nt] = __builtin_amdgcn_mfma_f32_16x16x32_bf16(af, bf, acc[nt], 0, 0, 0);
    }
  }
#pragma unroll
  for (int nt = 0; nt < 3; ++nt)
#pragma unroll
    for (int r = 0; r < 4; ++r)
      db[(size_t)(tok0 + (lane >> 4) * 4 + r) * 48 + nt * 16 + (lane & 15)] = acc[nt][r];
}

// ---------------------------------------------------------------------------
// scan4_k: selective scan + gating; dt-proj+softplus+silu(z) in staging phase.
// ---------------------------------------------------------------------------
__global__ __launch_bounds__(256) void scan4_k(
    const float* __restrict__ xzF, const float* __restrict__ xzR,
    const float* __restrict__ xcF, const float* __restrict__ xcR,
    const float* __restrict__ dbF, const float* __restrict__ dbR,
    const float* __restrict__ dwF, const float* __restrict__ dwR,
    const float* __restrict__ dtbF, const float* __restrict__ dtbR,
    const float* __restrict__ AlF, const float* __restrict__ AlR,
    const float* __restrict__ DpF, const float* __restrict__ DpR,
    unsigned short* __restrict__ yoF, unsigned short* __restrict__ yoR)
{
  const int dir = blockIdx.z;
  const float* xz = dir ? xzR : xzF;
  const float* xc = dir ? xcR : xcF;
  const float* db = dir ? dbR : dbF;
  const float* dw = dir ? dwR : dwF;
  const float* dtbv = dir ? dtbR : dtbF;
  const float* Al = dir ? AlR : AlF;
  const float* Dp = dir ? DpR : DpF;
  unsigned short* yo = dir ? yoR : yoF;

  __shared__ float sdb[FRAMES * 48];
  __shared__ float sxc[FRAMES * 16];
  __shared__ float sgz[FRAMES * 16];
  __shared__ float sdl[FRAMES * 16];
  const int b = blockIdx.x >> 5;
  const int e0 = (blockIdx.x & 31) << 4;
  const int t = threadIdx.x, g = t >> 4, n = t & 15;
  const int e = e0 + g;

  const float* dbp = db + (size_t)b * FRAMES * 48;
  for (int i = t; i < FRAMES * 48 / 4; i += 256)
    ((float4*)sdb)[i] = ((const float4*)dbp)[i];
  for (int i = t; i < FRAMES * 16; i += 256) {
    int l = i >> 4, c = i & 15;
    int ee = e0 + c;
    sxc[i] = xc[(size_t)(b * FRAMES + l) * EDIM + ee];
    float zz = xz[(size_t)(b * FRAMES + l) * 1024 + 512 + ee];
    sgz[i] = zz / (1.f + __expf(-zz));
    const float* d = db + (size_t)(b * FRAMES + l) * 48;
    const float* w = dw + (size_t)ee * 16;
    float a = dtbv[ee];
#pragma unroll
    for (int q = 0; q < 4; ++q) {
      float4 dv = *(const float4*)(d + 4 * q);
      float4 wv = *(const float4*)(w + 4 * q);
      a = fmaf(dv.x, wv.x, a); a = fmaf(dv.y, wv.y, a);
      a = fmaf(dv.z, wv.z, a); a = fmaf(dv.w, wv.w, a);
    }
    sdl[i] = (a > 20.f) ? a : __logf(1.f + __expf(a));
  }
  float An = -expf(Al[e * NSTATE + n]);
  float Dv = Dp[e];
  float h = 0.f;
  unsigned short* yp = yo + ((size_t)((e >> 5) * 4 + ((e >> 3) & 3)) * 1024 + b * FRAMES) * 8 + (e & 7);
  __syncthreads();

#pragma unroll 1
  for (int l = 0; l < FRAMES; ++l) {
    float dlt = sdl[l * 16 + g];
    float xcv = sxc[l * 16 + g];
    float Bn = sdb[l * 48 + 16 + n];
    float Cn = sdb[l * 48 + 32 + n];
    float dA = __expf(dlt * An);
    h = fmaf(dA, h, dlt * xcv * Bn);
    float part = h * Cn;
    part += __shfl_xor(part, 1, 16);
    part += __shfl_xor(part, 2, 16);
    part += __shfl_xor(part, 4, 16);
    part += __shfl_xor(part, 8, 16);
    if (n == 0) {
      float a2 = fmaf(Dv, xcv, part);
      yp[(size_t)l * 8] = f2bf(a2 * sgz[l * 16 + g]);
    }
  }
}

// ---------------------------------------------------------------------------
// outproj_mfma: zero-LDS bf16 MFMA GEMM + residual add.
// ---------------------------------------------------------------------------
__global__ __launch_bounds__(256) void outproj_mfma(
    const unsigned short* __restrict__ yoF, const unsigned short* __restrict__ yoR,
    const unsigned short* __restrict__ Wop, int layer,
    float* __restrict__ xF, float* __restrict__ xR)
{
  const int dir = blockIdx.z;
  const unsigned short* yo = dir ? yoR : yoF;
  float* xx = dir ? xR : xF;
  const int t = threadIdx.x, lane = t & 63, w = t >> 6;
  const int m0 = blockIdx.x * 32, n0 = blockIdx.y * 64;
  const int ntile = blockIdx.y * 4 + w;
  const unsigned short* wb = Wop + (((size_t)(dir * 4 + layer) * 256 + ntile * 16) * 64 + lane) * 8;
  f32x4 acc[2];
  acc[0] = (f32x4){0.f, 0.f, 0.f, 0.f};
  acc[1] = (f32x4){0.f, 0.f, 0.f, 0.f};
#pragma unroll
  for (int kt = 0; kt < 16; ++kt) {
    short8v bf = *(const short8v*)(wb + (size_t)kt * 64 * 8);
#pragma unroll
    for (int mt = 0; mt < 2; ++mt) {
      short8v af = *(const short8v*)(yo + ((size_t)(kt * 4 + (lane >> 4)) * 1024 + m0 + mt * 16 + (lane & 15)) * 8);
      acc[mt] = __builtin_amdgcn_mfma_f32_16x16x32_bf16(af, bf, acc[mt], 0, 0, 0);
    }
  }
#pragma unroll
  for (int mt = 0; mt < 2; ++mt)
#pragma unroll
    for (int r = 0; r < 4; ++r) {
      size_t ci = (size_t)(m0 + mt * 16 + (lane >> 4) * 4 + r) * DD + n0 + w * 16 + (lane & 15);
      xx[ci] += acc[mt][r];
    }
}

__global__ __launch_bounds__(256) void head_k(
    const float* __restrict__ xf, const float* __restrict__ xr,
    const float* __restrict__ fcw, const float* __restrict__ fcb,
    const float* __restrict__ fc2w, const float* __restrict__ fc2b,
    float* __restrict__ out)
{
  int b = blockIdx.x;
  __shared__ float xl[2 * DD];
  __shared__ float h[DD];
  __shared__ float hp[4];
  int t = threadIdx.x;
  xl[t]      = xf[(size_t)(b * FRAMES + FRAMES - 1) * DD + t];
  xl[DD + t] = xr[(size_t)(b * FRAMES + 0) * DD + t];
  __syncthreads();
  float acc = fcb[t];
  for (int k = 0; k < 2 * DD; ++k) acc = fmaf(xl[k], fcw[(size_t)t * 2 * DD + k], acc);
  h[t] = acc;
  __syncthreads();
  {
    int c = t >> 7, k = t & 127;
    float p = h[k] * fc2w[c * DD + k] + h[k + 128] * fc2w[c * DD + k + 128];
#pragma unroll
    for (int off = 32; off; off >>= 1) p += __shfl_xor(p, off, 64);
    if ((t & 63) == 0) hp[t >> 6] = p;
  }
  __syncthreads();
  if (t < 2) out[b * 2 + t] = hp[2 * t] + hp[2 * t + 1] + fc2b[t];
}

// ---------------------------------------------------------------------------
extern "C" void kernel_launch(void* const* d_in, const int* in_sizes, int n_in,
                              void* d_out, int out_size, void* d_ws, size_t ws_size,
                              hipStream_t stream) {
  const float* video = (const float*)d_in[0];
  const float* audio = (const float*)d_in[1];
  const float* c1w = (const float*)d_in[2];
  const float* c1b = (const float*)d_in[3];
  const float* c2w = (const float*)d_in[4];
  const float* c2b = (const float*)d_in[5];
  const float* fcw = (const float*)d_in[6];
  const float* fcb = (const float*)d_in[7];
  const float* Wf[10]; const float* Wb_[10];
  for (int i = 0; i < 10; ++i) { Wf[i] = (const float*)d_in[8+i]; Wb_[i] = (const float*)d_in[18+i]; }
  const float* fc_w  = (const float*)d_in[28];
  const float* fc_b  = (const float*)d_in[29];
  const float* fc2_w = (const float*)d_in[30];
  const float* fc2_b = (const float*)d_in[31];
  float* out = (float*)d_out;

  // workspace (float slots)
  float* ws   = (float*)d_ws;
  float* feat = ws;                       // 65536
  float* xf   = feat + 65536;             // 262144
  float* xr   = xf   + 262144;            // 262144
  float* xzF  = xr   + 262144;            // 1048576
  float* xzR  = xzF  + 1048576;           // 1048576
  float* xcF  = xzR  + 1048576;           // 524288
  float* xcR  = xcF  + 524288;            // 524288
  float* dbF  = xcR  + 524288;            // 49152
  float* dbR  = dbF  + 49152;             // 49152
  unsigned short* yoF = (unsigned short*)(dbR + 49152);     // 524288 sh
  unsigned short* yoR = yoF + 524288;
  unsigned short* X1  = yoR + 524288;                        // 33554432 sh
  unsigned short* Wbp = X1 + 33554432;                       // 18432 sh
  unsigned short* Wip = Wbp + 18432;                         // 2097152 sh
  unsigned short* Wop = Wip + 2097152;                       // 1048576 sh
  unsigned short* Wxp = Wop + 1048576;                       // 196608 sh
  unsigned short* xcbF = Wxp + 196608;                       // 524288 sh
  unsigned short* xcbR = xcbF + 524288;                      // 524288 sh
  unsigned short* Wb1  = xcbR + 524288;                      // 1024 sh

  // 1. packs + CNN
  pack_w2<<<dim3(10), 256, 0, stream>>>(c2w, Wbp, c1w, Wb1);
  pack_mamba<<<dim3(1632), 256, 0, stream>>>(Wf[1], Wb_[1], Wf[9], Wb_[9], Wf[4], Wb_[4],
                                             Wip, Wop, Wxp);
  conv1_mfma<<<dim3(TOK), 256, 0, stream>>>(video, Wb1, c1b, X1);
  conv2_k<<<dim3(TOK), 256, (size_t)(X_LDS_BYTES + 1024), stream>>>(X1, Wbp, c2b, feat);

  // 2. cnn fc (writes xf+xr directly) + audio fill (independent)
  fcgemm_k<<<dim3(16, 4), 256, 0, stream>>>(feat, fcw, fcb, xf, xr);
  audio_k<<<dim3((BATCH*FRAMES*NM + 255)/256), 256, 0, stream>>>(audio, xf, xr);

  // 3. bi-Mamba (5 kernels per layer)
  for (int l = 0; l < NLAYER; ++l) {
    const float* nwF  = Wf[0] + l*DD;              const float* nwR  = Wb_[0] + l*DD;
    const float* cwF_ = Wf[2] + l*EDIM*4;          const float* cwR_ = Wb_[2] + l*EDIM*4;
    const float* cbF_ = Wf[3] + l*EDIM;            const float* cbR_ = Wb_[3] + l*EDIM;
    const float* dwF  = Wf[5] + l*EDIM*DTRANK;     const float* dwR  = Wb_[5] + l*EDIM*DTRANK;
    const float* dtbF = Wf[6] + l*EDIM;            const float* dtbR = Wb_[6] + l*EDIM;
    const float* AlF  = Wf[7] + l*EDIM*NSTATE;     const float* AlR  = Wb_[7] + l*EDIM*NSTATE;
    const float* DpF  = Wf[8] + l*EDIM;            const float* DpR  = Wb_[8] + l*EDIM;

    inproj_mfma3<<<dim3(64, 4, 2), 256, 0, stream>>>(xf, xr, nwF, nwR, Wip, l, xzF, xzR);
    convsilu2_k<<<dim3(256, 1, 2), 256, 0, stream>>>(xzF, xzR, cwF_, cwR_, cbF_, cbR_,
                                                     xcF, xcR, xcbF, xcbR);
    xproj_mfma<<<dim3(64, 1, 2), 64, 0, stream>>>(xcbF, xcbR, Wxp, l, dbF, dbR);
    scan4_k<<<dim3(256, 1, 2), 256, 0, stream>>>(xzF, xzR, xcF, xcR, dbF, dbR, dwF, dwR,
                                                 dtbF, dtbR, AlF, AlR, DpF, DpR, yoF, yoR);
    outproj_mfma<<<dim3(32, 4, 2), 256, 0, stream>>>(yoF, yoR, Wop, l, xf, xr);
  }

  // 4. head
  head_k<<<dim3(BATCH), 256, 0, stream>>>(xf, xr, fc_w, fc_b, fc2_w, fc2_b, out);
}